// Round 1
// baseline (4991.336 us; speedup 1.0000x reference)
//
#include <hip/hip_runtime.h>
#include <hip/hip_bf16.h>
#include <stdint.h>

#define B_    8
#define N_    256
#define CTX_  196
#define IMGD_ 1024
#define DIM_  512
#define DEPTH_ 6
#define DIN_  1024
#define DTR_  32
#define DST_  16
#define HEADS_ 8
#define HD_   64

// ---------------- elementwise / small kernels ----------------

__global__ void dyt_kernel(const float* __restrict__ img, const float* __restrict__ alpha_p,
                           const float* __restrict__ gamma, const float* __restrict__ beta,
                           float* __restrict__ out, int total) {
    int i = blockIdx.x * 256 + threadIdx.x;
    if (i >= total) return;
    float a = alpha_p[0];
    int c = i & (IMGD_ - 1);
    out[i] = gamma[c] * tanhf(a * img[i]) + beta[c];
}

__global__ void pool_kernel(const float* __restrict__ imgf, float* __restrict__ pooled) {
    int i = blockIdx.x * 256 + threadIdx.x;
    if (i >= B_ * DIM_) return;
    int b = i >> 9, c = i & (DIM_ - 1);
    const float* p = imgf + (size_t)b * CTX_ * DIM_ + c;
    float s = 0.f;
    for (int t = 0; t < CTX_; ++t) s += p[t * DIM_];
    pooled[i] = s * (1.f / CTX_);
}

__global__ void gate1_kernel(const float* __restrict__ pooled, const float* __restrict__ W,
                             const float* __restrict__ bias, float* __restrict__ g1) {
    int i = blockIdx.x * 256 + threadIdx.x;
    if (i >= B_ * 128) return;
    int b = i >> 7, j = i & 127;
    const float* p = pooled + b * DIM_;
    float s = bias[j];
    for (int c = 0; c < DIM_; ++c) s += p[c] * W[c * 128 + j];
    g1[i] = 0.5f * s * (1.f + erff(s * 0.70710678118654752f));
}

__global__ void gate2_kernel(const float* __restrict__ g1, const float* __restrict__ W,
                             const float* __restrict__ bias, float* __restrict__ gate) {
    int i = blockIdx.x * 256 + threadIdx.x;
    if (i >= B_ * DIM_) return;
    int b = i >> 9, c = i & (DIM_ - 1);
    const float* p = g1 + b * 128;
    float s = bias[c];
    for (int j = 0; j < 128; ++j) s += p[j] * W[j * DIM_ + c];
    gate[i] = 1.f / (1.f + __expf(-s));
}

__global__ void scale_kernel(float* __restrict__ imgf, const float* __restrict__ gate) {
    int i = blockIdx.x * 256 + threadIdx.x;
    if (i >= B_ * CTX_ * DIM_) return;
    int c = i & (DIM_ - 1);
    int b = i / (CTX_ * DIM_);
    imgf[i] *= gate[b * DIM_ + c];
}

__global__ void embed_kernel(const int* __restrict__ text, const float* __restrict__ temb,
                             const float* __restrict__ pemb, float* __restrict__ x) {
    int i = blockIdx.x * 256 + threadIdx.x;
    if (i >= B_ * N_ * DIM_) return;
    int c = i & (DIM_ - 1);
    int row = i >> 9;
    int n = row & (N_ - 1);
    int tok = text[row];
    x[i] = temb[(size_t)tok * DIM_ + c] + pemb[(size_t)n * DIM_ + c];
}

// wave-per-row layernorm, row = 512 floats
__global__ void ln_kernel(const float* __restrict__ x, const float* __restrict__ g,
                          const float* __restrict__ b, float* __restrict__ o, int rows) {
    int row = blockIdx.x * 4 + (threadIdx.x >> 6);
    if (row >= rows) return;
    int lane = threadIdx.x & 63;
    const float* xr = x + (size_t)row * DIM_ + lane * 8;
    float4 v0 = ((const float4*)xr)[0];
    float4 v1 = ((const float4*)xr)[1];
    float r[8] = {v0.x, v0.y, v0.z, v0.w, v1.x, v1.y, v1.z, v1.w};
    float sum = 0.f, sq = 0.f;
    #pragma unroll
    for (int j = 0; j < 8; ++j) { sum += r[j]; sq += r[j] * r[j]; }
    #pragma unroll
    for (int m = 1; m < 64; m <<= 1) { sum += __shfl_xor(sum, m); sq += __shfl_xor(sq, m); }
    float mean = sum * (1.f / DIM_);
    float var  = sq * (1.f / DIM_) - mean * mean;
    float inv  = rsqrtf(fmaxf(var, 0.f) + 1e-5f);
    const float* gp = g + lane * 8;
    const float* bp = b + lane * 8;
    float* op = o + (size_t)row * DIM_ + lane * 8;
    float4 o0, o1;
    o0.x = (r[0]-mean)*inv*gp[0]+bp[0]; o0.y = (r[1]-mean)*inv*gp[1]+bp[1];
    o0.z = (r[2]-mean)*inv*gp[2]+bp[2]; o0.w = (r[3]-mean)*inv*gp[3]+bp[3];
    o1.x = (r[4]-mean)*inv*gp[4]+bp[4]; o1.y = (r[5]-mean)*inv*gp[5]+bp[5];
    o1.z = (r[6]-mean)*inv*gp[6]+bp[6]; o1.w = (r[7]-mean)*inv*gp[7]+bp[7];
    ((float4*)op)[0] = o0; ((float4*)op)[1] = o1;
}

// causal depthwise conv (4 taps) + SiLU; xi = xz[..., :1024]
__global__ void conv_silu_kernel(const float* __restrict__ xz, const float* __restrict__ cw,
                                 const float* __restrict__ cb, float* __restrict__ xc) {
    int i = blockIdx.x * 256 + threadIdx.x;
    if (i >= B_ * N_ * DIN_) return;
    int d = i & (DIN_ - 1);
    int row = i >> 10;
    int n = row & (N_ - 1);
    int rowb = row - n;
    float acc = cb[d];
    #pragma unroll
    for (int k = 0; k < 4; ++k) {
        int m = n - 3 + k;
        if (m >= 0) acc += xz[(size_t)(rowb + m) * (2 * DIN_) + d] * cw[d * 4 + k];
    }
    xc[i] = acc / (1.f + __expf(-acc));
}

// selective scan: thread per (b, d, s); 16-lane shuffle reduce for y
__global__ __launch_bounds__(256) void scan_kernel(
    const float* __restrict__ dtp, const float* __restrict__ xc,
    const float* __restrict__ dbl, const float* __restrict__ xz,
    const float* __restrict__ A_log, const float* __restrict__ Dsk,
    float* __restrict__ yb) {
    int t = blockIdx.x * 256 + threadIdx.x;   // < B_*DIN_*16 = 131072
    int s = t & 15;
    int d = (t >> 4) & (DIN_ - 1);
    int b = t >> 14;
    float As = -__expf(A_log[t & 16383]);     // A_log[d*16+s]
    float Dv = Dsk[d];
    float h = 0.f;
    int base = b * N_;
    for (int n = 0; n < N_; ++n) {
        int row = base + n;
        float dtraw = dtp[(size_t)row * DIN_ + d];
        float dt = dtraw > 20.f ? dtraw : log1pf(__expf(dtraw));
        float xcv = xc[(size_t)row * DIN_ + d];
        float Bv = dbl[row * 64 + 32 + s];
        float Cv = dbl[row * 64 + 48 + s];
        float dA = __expf(dt * As);
        h = h * dA + dt * Bv * xcv;
        float p = h * Cv;
        p += __shfl_xor(p, 1);
        p += __shfl_xor(p, 2);
        p += __shfl_xor(p, 4);
        p += __shfl_xor(p, 8);
        if (s == 0) {
            float z = xz[(size_t)row * (2 * DIN_) + DIN_ + d];
            float y = (p + xcv * Dv) * (z / (1.f + __expf(-z)));
            yb[(size_t)row * DIN_ + d] = y;
        }
    }
}

// wave-per-row softmax over CTX_=196
__global__ void softmax_kernel(float* __restrict__ att, int rows) {
    int row = blockIdx.x * 4 + (threadIdx.x >> 6);
    if (row >= rows) return;
    int lane = threadIdx.x & 63;
    float* ar = att + (size_t)row * CTX_;
    float v[4];
    float mx = -1e30f;
    #pragma unroll
    for (int j = 0; j < 4; ++j) {
        int idx = lane + j * 64;
        v[j] = idx < CTX_ ? ar[idx] : -1e30f;
        mx = fmaxf(mx, v[j]);
    }
    #pragma unroll
    for (int m = 1; m < 64; m <<= 1) mx = fmaxf(mx, __shfl_xor(mx, m));
    float sm = 0.f;
    #pragma unroll
    for (int j = 0; j < 4; ++j) {
        int idx = lane + j * 64;
        v[j] = idx < CTX_ ? __expf(v[j] - mx) : 0.f;
        sm += v[j];
    }
    #pragma unroll
    for (int m = 1; m < 64; m <<= 1) sm += __shfl_xor(sm, m);
    float inv = 1.f / sm;
    #pragma unroll
    for (int j = 0; j < 4; ++j) {
        int idx = lane + j * 64;
        if (idx < CTX_) ar[idx] = v[j] * inv;
    }
}

// ---------------- generic fp32 GEMM ----------------
// C[b1,b2][m,n] = alpha * sum_k A[m,k]*B[k,n](or B[n,k] if TB) + bias[n] (+ res)
#define TM_ 64
#define TN_ 64
#define TK_ 16

template <bool TB, bool RES>
__global__ __launch_bounds__(256) void gemm_k(
    const float* __restrict__ A, const float* __restrict__ B,
    const float* __restrict__ bias, const float* res, float* C,
    int M, int N, int K, int lda, int ldb, int ldc,
    long long aO1, long long aO2, long long bO1, long long bO2,
    long long cO1, long long cO2, int subBatch, float alpha) {
    int z = blockIdx.z;
    int b1 = z / subBatch, b2 = z % subBatch;
    A += b1 * aO1 + b2 * aO2;
    B += b1 * bO1 + b2 * bO2;
    long long cbase = b1 * cO1 + b2 * cO2;

    __shared__ float As[TK_][TM_ + 4];
    __shared__ float Bs[TK_][TN_ + 4];
    int tid = threadIdx.x;
    int row0 = blockIdx.y * TM_;
    int col0 = blockIdx.x * TN_;
    int tm = (tid / 16) * 4, tn = (tid % 16) * 4;
    float acc[4][4] = {};
    int nk = (K + TK_ - 1) / TK_;

    for (int kt = 0; kt < nk; ++kt) {
        int k0 = kt * TK_;
        {   // A tile: 64 rows x 16 k
            int m = tid >> 2, kq = (tid & 3) * 4;
            int gm = row0 + m;
            float4 v = {0, 0, 0, 0};
            if (gm < M) {
                const float* p = A + (size_t)gm * lda + k0 + kq;
                if (k0 + kq + 3 < K) v = *(const float4*)p;
                else {
                    float tmp[4] = {0, 0, 0, 0};
                    for (int j = 0; j < 4; ++j) if (k0 + kq + j < K) tmp[j] = p[j];
                    v = {tmp[0], tmp[1], tmp[2], tmp[3]};
                }
            }
            As[kq + 0][m] = v.x; As[kq + 1][m] = v.y; As[kq + 2][m] = v.z; As[kq + 3][m] = v.w;
        }
        if (!TB) {  // B tile: 16 k x 64 n, B row-major K x N
            int kk = tid >> 4, nq = (tid & 15) * 4;
            int gk = k0 + kk;
            float4 v = {0, 0, 0, 0};
            if (gk < K) {
                const float* p = B + (size_t)gk * ldb + col0 + nq;
                if (col0 + nq + 3 < N) v = *(const float4*)p;
                else {
                    float tmp[4] = {0, 0, 0, 0};
                    for (int j = 0; j < 4; ++j) if (col0 + nq + j < N) tmp[j] = p[j];
                    v = {tmp[0], tmp[1], tmp[2], tmp[3]};
                }
            }
            Bs[kk][nq + 0] = v.x; Bs[kk][nq + 1] = v.y; Bs[kk][nq + 2] = v.z; Bs[kk][nq + 3] = v.w;
        } else {    // B is N x K row-major: Bs[k][n] = B[n*ldb + k]
            int nn = tid >> 2, kq = (tid & 3) * 4;
            int gn = col0 + nn;
            float4 v = {0, 0, 0, 0};
            if (gn < N) {
                const float* p = B + (size_t)gn * ldb + k0 + kq;
                if (k0 + kq + 3 < K) v = *(const float4*)p;
                else {
                    float tmp[4] = {0, 0, 0, 0};
                    for (int j = 0; j < 4; ++j) if (k0 + kq + j < K) tmp[j] = p[j];
                    v = {tmp[0], tmp[1], tmp[2], tmp[3]};
                }
            }
            Bs[kq + 0][nn] = v.x; Bs[kq + 1][nn] = v.y; Bs[kq + 2][nn] = v.z; Bs[kq + 3][nn] = v.w;
        }
        __syncthreads();
        #pragma unroll
        for (int kk = 0; kk < TK_; ++kk) {
            float4 a4 = *(const float4*)&As[kk][tm];
            float4 b4 = *(const float4*)&Bs[kk][tn];
            float a0[4] = {a4.x, a4.y, a4.z, a4.w};
            float b0[4] = {b4.x, b4.y, b4.z, b4.w};
            #pragma unroll
            for (int i = 0; i < 4; ++i)
                #pragma unroll
                for (int j = 0; j < 4; ++j)
                    acc[i][j] += a0[i] * b0[j];
        }
        __syncthreads();
    }
    for (int i = 0; i < 4; ++i) {
        int gm = row0 + tm + i;
        if (gm >= M) continue;
        for (int j = 0; j < 4; ++j) {
            int gn = col0 + tn + j;
            if (gn >= N) continue;
            float v = acc[i][j] * alpha;
            if (bias) v += bias[gn];
            long long idx = cbase + (long long)gm * ldc + gn;
            if (RES) v += res[idx];
            C[idx] = v;
        }
    }
}

// ---------------- host side ----------------

static inline void gemm(bool tb, bool resf,
                        const float* A, const float* B, const float* bias, const float* res, float* C,
                        int M, int N, int K, int lda, int ldb, int ldc,
                        long long aO1, long long aO2, long long bO1, long long bO2,
                        long long cO1, long long cO2, int batches, int subBatch, float alpha,
                        hipStream_t s) {
    dim3 g((N + TN_ - 1) / TN_, (M + TM_ - 1) / TM_, batches), blk(256);
    if (!tb && !resf)      gemm_k<false, false><<<g, blk, 0, s>>>(A, B, bias, res, C, M, N, K, lda, ldb, ldc, aO1, aO2, bO1, bO2, cO1, cO2, subBatch, alpha);
    else if (tb && !resf)  gemm_k<true,  false><<<g, blk, 0, s>>>(A, B, bias, res, C, M, N, K, lda, ldb, ldc, aO1, aO2, bO1, bO2, cO1, cO2, subBatch, alpha);
    else if (!tb && resf)  gemm_k<false, true ><<<g, blk, 0, s>>>(A, B, bias, res, C, M, N, K, lda, ldb, ldc, aO1, aO2, bO1, bO2, cO1, cO2, subBatch, alpha);
    else                   gemm_k<true,  true ><<<g, blk, 0, s>>>(A, B, bias, res, C, M, N, K, lda, ldb, ldc, aO1, aO2, bO1, bO2, cO1, cO2, subBatch, alpha);
}

extern "C" void kernel_launch(void* const* d_in, const int* in_sizes, int n_in,
                              void* d_out, int out_size, void* d_ws, size_t ws_size,
                              hipStream_t stream) {
    const int*   text   = (const int*)d_in[0];
    const float* images = (const float*)d_in[1];
    const float* alphap = (const float*)d_in[2];
    const float* dgam   = (const float*)d_in[3];
    const float* dbeta  = (const float*)d_in[4];
    const float* imgW   = (const float*)d_in[5];
    const float* imgb   = (const float*)d_in[6];
    const float* g1W    = (const float*)d_in[7];
    const float* g1b    = (const float*)d_in[8];
    const float* g2W    = (const float*)d_in[9];
    const float* g2b    = (const float*)d_in[10];
    const float* temb   = (const float*)d_in[11];
    const float* pemb   = (const float*)d_in[12];
    const float* ln1g   = (const float*)d_in[13];
    const float* ln1b   = (const float*)d_in[14];
    const float* inW    = (const float*)d_in[15];
    const float* convW  = (const float*)d_in[16];
    const float* convb  = (const float*)d_in[17];
    const float* xpW    = (const float*)d_in[18];
    const float* dtW    = (const float*)d_in[19];
    const float* dtb    = (const float*)d_in[20];
    const float* Alog   = (const float*)d_in[21];
    const float* Dsk    = (const float*)d_in[22];
    const float* outW   = (const float*)d_in[23];
    const float* ln2g   = (const float*)d_in[24];
    const float* ln2b   = (const float*)d_in[25];
    const float* ainW   = (const float*)d_in[26];
    const float* ainb   = (const float*)d_in[27];
    const float* aoutW  = (const float*)d_in[28];
    const float* aoutb  = (const float*)d_in[29];
    const float* fng    = (const float*)d_in[30];
    const float* fnb    = (const float*)d_in[31];
    const float* lgW    = (const float*)d_in[32];
    const float* lgb    = (const float*)d_in[33];
    float* out = (float*)d_out;

    float* w = (float*)d_ws;
    float* imgd   = w; w += (size_t)B_ * CTX_ * IMGD_;   // 1605632
    float* imgf   = w; w += (size_t)B_ * CTX_ * DIM_;    // 802816
    float* pooled = w; w += B_ * DIM_;
    float* g1     = w; w += B_ * 128;
    float* gate   = w; w += B_ * DIM_;
    float* x      = w; w += (size_t)B_ * N_ * DIM_;      // 1048576
    float* xn     = w; w += (size_t)B_ * N_ * DIM_;
    float* xz     = w; w += (size_t)B_ * N_ * 2 * DIN_;  // 4194304
    float* xc     = w; w += (size_t)B_ * N_ * DIN_;      // 2097152
    float* dblb   = w; w += (size_t)B_ * N_ * 64;        // 131072
    float* dtp    = w; w += (size_t)B_ * N_ * DIN_;
    float* yb     = w; w += (size_t)B_ * N_ * DIN_;
    float* q      = w; w += (size_t)B_ * N_ * DIM_;
    float* kb     = w; w += (size_t)B_ * CTX_ * DIM_;
    float* vb     = w; w += (size_t)B_ * CTX_ * DIM_;
    float* att    = w; w += (size_t)B_ * HEADS_ * N_ * CTX_; // 3211264
    float* ob     = w; w += (size_t)B_ * N_ * DIM_;

    const int TOKENS = B_ * N_;       // 2048
    const int IMGT   = B_ * CTX_;     // 1568

    // image path
    {
        int total = B_ * CTX_ * IMGD_;
        dyt_kernel<<<(total + 255) / 256, 256, 0, stream>>>(images, alphap, dgam, dbeta, imgd, total);
        gemm(false, false, imgd, imgW, imgb, nullptr, imgf,
             IMGT, DIM_, IMGD_, IMGD_, DIM_, DIM_, 0, 0, 0, 0, 0, 0, 1, 1, 1.f, stream);
        pool_kernel<<<(B_ * DIM_ + 255) / 256, 256, 0, stream>>>(imgf, pooled);
        gate1_kernel<<<(B_ * 128 + 255) / 256, 256, 0, stream>>>(pooled, g1W, g1b, g1);
        gate2_kernel<<<(B_ * DIM_ + 255) / 256, 256, 0, stream>>>(g1, g2W, g2b, gate);
        scale_kernel<<<(B_ * CTX_ * DIM_ + 255) / 256, 256, 0, stream>>>(imgf, gate);
    }
    // embedding
    embed_kernel<<<(TOKENS * DIM_ + 255) / 256, 256, 0, stream>>>(text, temb, pemb, x);

    for (int l = 0; l < DEPTH_; ++l) {
        const float* W_in  = inW  + (size_t)l * DIM_ * 2 * DIN_;
        const float* cw    = convW + (size_t)l * DIN_ * 4;
        const float* cb    = convb + (size_t)l * DIN_;
        const float* xpw   = xpW  + (size_t)l * DIN_ * 64;
        const float* dtw   = dtW  + (size_t)l * DTR_ * DIN_;
        const float* dtbi  = dtb  + (size_t)l * DIN_;
        const float* alog  = Alog + (size_t)l * DIN_ * DST_;
        const float* dsk   = Dsk  + (size_t)l * DIN_;
        const float* ow    = outW + (size_t)l * DIN_ * DIM_;
        const float* aw    = ainW + (size_t)l * 3 * DIM_ * DIM_;
        const float* ab    = ainb + (size_t)l * 3 * DIM_;
        const float* aow   = aoutW + (size_t)l * DIM_ * DIM_;
        const float* aob   = aoutb + (size_t)l * DIM_;

        // mamba block
        ln_kernel<<<TOKENS / 4, 256, 0, stream>>>(x, ln1g + l * DIM_, ln1b + l * DIM_, xn, TOKENS);
        gemm(false, false, xn, W_in, nullptr, nullptr, xz,
             TOKENS, 2 * DIN_, DIM_, DIM_, 2 * DIN_, 2 * DIN_, 0, 0, 0, 0, 0, 0, 1, 1, 1.f, stream);
        conv_silu_kernel<<<(TOKENS * DIN_ + 255) / 256, 256, 0, stream>>>(xz, cw, cb, xc);
        gemm(false, false, xc, xpw, nullptr, nullptr, dblb,
             TOKENS, 64, DIN_, DIN_, 64, 64, 0, 0, 0, 0, 0, 0, 1, 1, 1.f, stream);
        gemm(false, false, dblb, dtw, dtbi, nullptr, dtp,
             TOKENS, DIN_, DTR_, 64, DIN_, DIN_, 0, 0, 0, 0, 0, 0, 1, 1, 1.f, stream);
        scan_kernel<<<(B_ * DIN_ * DST_) / 256, 256, 0, stream>>>(dtp, xc, dblb, xz, alog, dsk, yb);
        gemm(false, true, yb, ow, nullptr, x, x,
             TOKENS, DIM_, DIN_, DIN_, DIM_, DIM_, 0, 0, 0, 0, 0, 0, 1, 1, 1.f, stream);

        // cross-attention block
        ln_kernel<<<TOKENS / 4, 256, 0, stream>>>(x, ln2g + l * DIM_, ln2b + l * DIM_, xn, TOKENS);
        gemm(true, false, xn, aw, ab, nullptr, q,
             TOKENS, DIM_, DIM_, DIM_, DIM_, DIM_, 0, 0, 0, 0, 0, 0, 1, 1, 1.f, stream);
        gemm(true, false, imgf, aw + (size_t)DIM_ * DIM_, ab + DIM_, nullptr, kb,
             IMGT, DIM_, DIM_, DIM_, DIM_, DIM_, 0, 0, 0, 0, 0, 0, 1, 1, 1.f, stream);
        gemm(true, false, imgf, aw + (size_t)2 * DIM_ * DIM_, ab + 2 * DIM_, nullptr, vb,
             IMGT, DIM_, DIM_, DIM_, DIM_, DIM_, 0, 0, 0, 0, 0, 0, 1, 1, 1.f, stream);
        // scores: att[b,h,q,t] = 0.125 * q . k
        gemm(true, false, q, kb, nullptr, nullptr, att,
             N_, CTX_, HD_, DIM_, DIM_, CTX_,
             (long long)N_ * DIM_, HD_,
             (long long)CTX_ * DIM_, HD_,
             (long long)HEADS_ * N_ * CTX_, (long long)N_ * CTX_,
             B_ * HEADS_, HEADS_, 0.125f, stream);
        softmax_kernel<<<(B_ * HEADS_ * N_) / 4, 256, 0, stream>>>(att, B_ * HEADS_ * N_);
        // PV: ob[b,q,h*64+hd] = att @ v
        gemm(false, false, att, vb, nullptr, nullptr, ob,
             N_, HD_, CTX_, CTX_, DIM_, DIM_,
             (long long)HEADS_ * N_ * CTX_, (long long)N_ * CTX_,
             (long long)CTX_ * DIM_, HD_,
             (long long)N_ * DIM_, HD_,
             B_ * HEADS_, HEADS_, 1.f, stream);
        gemm(true, true, ob, aow, aob, x, x,
             TOKENS, DIM_, DIM_, DIM_, DIM_, DIM_, 0, 0, 0, 0, 0, 0, 1, 1, 1.f, stream);
    }

    // final LN + logits
    ln_kernel<<<TOKENS / 4, 256, 0, stream>>>(x, fng, fnb, xn, TOKENS);
    gemm(false, false, xn, lgW, lgb, nullptr, out,
         TOKENS, 10000, DIM_, DIM_, 10000, 10000, 0, 0, 0, 0, 0, 0, 1, 1, 1.f, stream);
}

// Round 2
// 3627.358 us; speedup vs baseline: 1.3760x; 1.3760x over previous
//
#include <hip/hip_runtime.h>
#include <hip/hip_bf16.h>
#include <stdint.h>

#define B_    8
#define N_    256
#define CTX_  196
#define IMGD_ 1024
#define DIM_  512
#define DEPTH_ 6
#define DIN_  1024
#define DTR_  32
#define DST_  16
#define HEADS_ 8
#define HD_   64
#define NCHUNK_ 8
#define CLEN_   32   // N_/NCHUNK_

// ---------------- elementwise / small kernels ----------------

__global__ void dyt_kernel(const float* __restrict__ img, const float* __restrict__ alpha_p,
                           const float* __restrict__ gamma, const float* __restrict__ beta,
                           float* __restrict__ out, int total) {
    int i = blockIdx.x * 256 + threadIdx.x;
    if (i >= total) return;
    float a = alpha_p[0];
    int c = i & (IMGD_ - 1);
    out[i] = gamma[c] * tanhf(a * img[i]) + beta[c];
}

__global__ void pool_kernel(const float* __restrict__ imgf, float* __restrict__ pooled) {
    int i = blockIdx.x * 256 + threadIdx.x;
    if (i >= B_ * DIM_) return;
    int b = i >> 9, c = i & (DIM_ - 1);
    const float* p = imgf + (size_t)b * CTX_ * DIM_ + c;
    float s = 0.f;
    for (int t = 0; t < CTX_; ++t) s += p[t * DIM_];
    pooled[i] = s * (1.f / CTX_);
}

__global__ void gate1_kernel(const float* __restrict__ pooled, const float* __restrict__ W,
                             const float* __restrict__ bias, float* __restrict__ g1) {
    int i = blockIdx.x * 256 + threadIdx.x;
    if (i >= B_ * 128) return;
    int b = i >> 7, j = i & 127;
    const float* p = pooled + b * DIM_;
    float s = bias[j];
    for (int c = 0; c < DIM_; ++c) s += p[c] * W[c * 128 + j];
    g1[i] = 0.5f * s * (1.f + erff(s * 0.70710678118654752f));
}

__global__ void gate2_kernel(const float* __restrict__ g1, const float* __restrict__ W,
                             const float* __restrict__ bias, float* __restrict__ gate) {
    int i = blockIdx.x * 256 + threadIdx.x;
    if (i >= B_ * DIM_) return;
    int b = i >> 9, c = i & (DIM_ - 1);
    const float* p = g1 + b * 128;
    float s = bias[c];
    for (int j = 0; j < 128; ++j) s += p[j] * W[j * DIM_ + c];
    gate[i] = 1.f / (1.f + __expf(-s));
}

__global__ void scale_kernel(float* __restrict__ imgf, const float* __restrict__ gate) {
    int i = blockIdx.x * 256 + threadIdx.x;
    if (i >= B_ * CTX_ * DIM_) return;
    int c = i & (DIM_ - 1);
    int b = i / (CTX_ * DIM_);
    imgf[i] *= gate[b * DIM_ + c];
}

__global__ void embed_kernel(const int* __restrict__ text, const float* __restrict__ temb,
                             const float* __restrict__ pemb, float* __restrict__ x) {
    int i = blockIdx.x * 256 + threadIdx.x;
    if (i >= B_ * N_ * DIM_) return;
    int c = i & (DIM_ - 1);
    int row = i >> 9;
    int n = row & (N_ - 1);
    int tok = text[row];
    x[i] = temb[(size_t)tok * DIM_ + c] + pemb[(size_t)n * DIM_ + c];
}

// wave-per-row layernorm, row = 512 floats
__global__ void ln_kernel(const float* __restrict__ x, const float* __restrict__ g,
                          const float* __restrict__ b, float* __restrict__ o, int rows) {
    int row = blockIdx.x * 4 + (threadIdx.x >> 6);
    if (row >= rows) return;
    int lane = threadIdx.x & 63;
    const float* xr = x + (size_t)row * DIM_ + lane * 8;
    float4 v0 = ((const float4*)xr)[0];
    float4 v1 = ((const float4*)xr)[1];
    float r[8] = {v0.x, v0.y, v0.z, v0.w, v1.x, v1.y, v1.z, v1.w};
    float sum = 0.f, sq = 0.f;
    #pragma unroll
    for (int j = 0; j < 8; ++j) { sum += r[j]; sq += r[j] * r[j]; }
    #pragma unroll
    for (int m = 1; m < 64; m <<= 1) { sum += __shfl_xor(sum, m); sq += __shfl_xor(sq, m); }
    float mean = sum * (1.f / DIM_);
    float var  = sq * (1.f / DIM_) - mean * mean;
    float inv  = rsqrtf(fmaxf(var, 0.f) + 1e-5f);
    const float* gp = g + lane * 8;
    const float* bp = b + lane * 8;
    float* op = o + (size_t)row * DIM_ + lane * 8;
    float4 o0, o1;
    o0.x = (r[0]-mean)*inv*gp[0]+bp[0]; o0.y = (r[1]-mean)*inv*gp[1]+bp[1];
    o0.z = (r[2]-mean)*inv*gp[2]+bp[2]; o0.w = (r[3]-mean)*inv*gp[3]+bp[3];
    o1.x = (r[4]-mean)*inv*gp[4]+bp[4]; o1.y = (r[5]-mean)*inv*gp[5]+bp[5];
    o1.z = (r[6]-mean)*inv*gp[6]+bp[6]; o1.w = (r[7]-mean)*inv*gp[7]+bp[7];
    ((float4*)op)[0] = o0; ((float4*)op)[1] = o1;
}

// causal depthwise conv (4 taps) + SiLU; xi = xz[..., :1024]
__global__ void conv_silu_kernel(const float* __restrict__ xz, const float* __restrict__ cw,
                                 const float* __restrict__ cb, float* __restrict__ xc) {
    int i = blockIdx.x * 256 + threadIdx.x;
    if (i >= B_ * N_ * DIN_) return;
    int d = i & (DIN_ - 1);
    int row = i >> 10;
    int n = row & (N_ - 1);
    int rowb = row - n;
    float acc = cb[d];
    #pragma unroll
    for (int k = 0; k < 4; ++k) {
        int m = n - 3 + k;
        if (m >= 0) acc += xz[(size_t)(rowb + m) * (2 * DIN_) + d] * cw[d * 4 + k];
    }
    xc[i] = acc / (1.f + __expf(-acc));
}

// dt = softplus(dtp) (overwrite dtp); u = dt * xc
__global__ void dt_prep_kernel(float* __restrict__ dtp, const float* __restrict__ xc,
                               float* __restrict__ u) {
    int i = blockIdx.x * 256 + threadIdx.x;
    if (i >= B_ * N_ * DIN_) return;
    float v = dtp[i];
    float e = __expf(-fabsf(v));
    float dt = fmaxf(v, 0.f) + __logf(1.f + e);
    dtp[i] = dt;
    u[i] = dt * xc[i];
}

// ---------------- chunked selective scan ----------------
// thread id bits: s(4) | d(10) | c(3) | b(3); (b,c) select a 32-step chunk
// scan1: compute per-chunk affine summary h_out = a*h_in + bacc
__global__ __launch_bounds__(256) void scan1_kernel(
    const float* __restrict__ dtp, const float* __restrict__ u,
    const float* __restrict__ dbl, const float* __restrict__ A_log,
    float* __restrict__ chunkA, float* __restrict__ chunkB) {
    int t = blockIdx.x * 256 + threadIdx.x;     // < 1048576
    int s = t & 15;
    int d = (t >> 4) & (DIN_ - 1);
    int c = (t >> 14) & (NCHUNK_ - 1);
    int b = t >> 17;
    float As = -__expf(A_log[(d << 4) | s]);
    float a = 1.f, hb = 0.f;
    int row0 = b * N_ + c * CLEN_;
    for (int n = 0; n < CLEN_; ++n) {
        int row = row0 + n;
        float dt = dtp[(size_t)row * DIN_ + d];
        float uu = u[(size_t)row * DIN_ + d];
        float Bv = dbl[row * 64 + 32 + s];
        float dA = __expf(dt * As);
        hb = hb * dA + uu * Bv;
        a *= dA;
    }
    chunkA[t] = a;
    chunkB[t] = hb;
}

// scan2: compose prior chunk summaries for h_init, replay chunk, emit y
__global__ __launch_bounds__(256) void scan2_kernel(
    const float* __restrict__ dtp, const float* __restrict__ u,
    const float* __restrict__ dbl, const float* __restrict__ xc,
    const float* __restrict__ xz, const float* __restrict__ A_log,
    const float* __restrict__ Dsk,
    const float* __restrict__ chunkA, const float* __restrict__ chunkB,
    float* __restrict__ yb) {
    int t = blockIdx.x * 256 + threadIdx.x;
    int s = t & 15;
    int d = (t >> 4) & (DIN_ - 1);
    int c = (t >> 14) & (NCHUNK_ - 1);
    int b = t >> 17;
    float h = 0.f;
    int base = (b << 17) | (d << 4) | s;
    for (int j = 0; j < c; ++j) {
        int idx = base | (j << 14);
        h = h * chunkA[idx] + chunkB[idx];
    }
    float As = -__expf(A_log[(d << 4) | s]);
    float Dv = Dsk[d];
    int row0 = b * N_ + c * CLEN_;
    for (int n = 0; n < CLEN_; ++n) {
        int row = row0 + n;
        float dt = dtp[(size_t)row * DIN_ + d];
        float uu = u[(size_t)row * DIN_ + d];
        float Bv = dbl[row * 64 + 32 + s];
        float Cv = dbl[row * 64 + 48 + s];
        float dA = __expf(dt * As);
        h = h * dA + uu * Bv;
        float p = h * Cv;
        p += __shfl_xor(p, 1);
        p += __shfl_xor(p, 2);
        p += __shfl_xor(p, 4);
        p += __shfl_xor(p, 8);
        if (s == 0) {
            float z = xz[(size_t)row * (2 * DIN_) + DIN_ + d];
            float xcv = xc[(size_t)row * DIN_ + d];
            float y = (p + xcv * Dv) * (z / (1.f + __expf(-z)));
            yb[(size_t)row * DIN_ + d] = y;
        }
    }
}

// wave-per-row softmax over CTX_=196
__global__ void softmax_kernel(float* __restrict__ att, int rows) {
    int row = blockIdx.x * 4 + (threadIdx.x >> 6);
    if (row >= rows) return;
    int lane = threadIdx.x & 63;
    float* ar = att + (size_t)row * CTX_;
    float v[4];
    float mx = -1e30f;
    #pragma unroll
    for (int j = 0; j < 4; ++j) {
        int idx = lane + j * 64;
        v[j] = idx < CTX_ ? ar[idx] : -1e30f;
        mx = fmaxf(mx, v[j]);
    }
    #pragma unroll
    for (int m = 1; m < 64; m <<= 1) mx = fmaxf(mx, __shfl_xor(mx, m));
    float sm = 0.f;
    #pragma unroll
    for (int j = 0; j < 4; ++j) {
        int idx = lane + j * 64;
        v[j] = idx < CTX_ ? __expf(v[j] - mx) : 0.f;
        sm += v[j];
    }
    #pragma unroll
    for (int m = 1; m < 64; m <<= 1) sm += __shfl_xor(sm, m);
    float inv = 1.f / sm;
    #pragma unroll
    for (int j = 0; j < 4; ++j) {
        int idx = lane + j * 64;
        if (idx < CTX_) ar[idx] = v[j] * inv;
    }
}

// ---------------- generic fp32 GEMM ----------------
#define TM_ 64
#define TN_ 64
#define TK_ 16

template <bool TB, bool RES>
__global__ __launch_bounds__(256) void gemm_k(
    const float* __restrict__ A, const float* __restrict__ B,
    const float* __restrict__ bias, const float* res, float* C,
    int M, int N, int K, int lda, int ldb, int ldc,
    long long aO1, long long aO2, long long bO1, long long bO2,
    long long cO1, long long cO2, int subBatch, float alpha) {
    int z = blockIdx.z;
    int b1 = z / subBatch, b2 = z % subBatch;
    A += b1 * aO1 + b2 * aO2;
    B += b1 * bO1 + b2 * bO2;
    long long cbase = b1 * cO1 + b2 * cO2;

    __shared__ float As[TK_][TM_ + 4];
    __shared__ float Bs[TK_][TN_ + 4];
    int tid = threadIdx.x;
    int row0 = blockIdx.y * TM_;
    int col0 = blockIdx.x * TN_;
    int tm = (tid / 16) * 4, tn = (tid % 16) * 4;
    float acc[4][4] = {};
    int nk = (K + TK_ - 1) / TK_;

    for (int kt = 0; kt < nk; ++kt) {
        int k0 = kt * TK_;
        {
            int m = tid >> 2, kq = (tid & 3) * 4;
            int gm = row0 + m;
            float4 v = {0, 0, 0, 0};
            if (gm < M) {
                const float* p = A + (size_t)gm * lda + k0 + kq;
                if (k0 + kq + 3 < K) v = *(const float4*)p;
                else {
                    float tmp[4] = {0, 0, 0, 0};
                    for (int j = 0; j < 4; ++j) if (k0 + kq + j < K) tmp[j] = p[j];
                    v = {tmp[0], tmp[1], tmp[2], tmp[3]};
                }
            }
            As[kq + 0][m] = v.x; As[kq + 1][m] = v.y; As[kq + 2][m] = v.z; As[kq + 3][m] = v.w;
        }
        if (!TB) {
            int kk = tid >> 4, nq = (tid & 15) * 4;
            int gk = k0 + kk;
            float4 v = {0, 0, 0, 0};
            if (gk < K) {
                const float* p = B + (size_t)gk * ldb + col0 + nq;
                if (col0 + nq + 3 < N) v = *(const float4*)p;
                else {
                    float tmp[4] = {0, 0, 0, 0};
                    for (int j = 0; j < 4; ++j) if (col0 + nq + j < N) tmp[j] = p[j];
                    v = {tmp[0], tmp[1], tmp[2], tmp[3]};
                }
            }
            Bs[kk][nq + 0] = v.x; Bs[kk][nq + 1] = v.y; Bs[kk][nq + 2] = v.z; Bs[kk][nq + 3] = v.w;
        } else {
            int nn = tid >> 2, kq = (tid & 3) * 4;
            int gn = col0 + nn;
            float4 v = {0, 0, 0, 0};
            if (gn < N) {
                const float* p = B + (size_t)gn * ldb + k0 + kq;
                if (k0 + kq + 3 < K) v = *(const float4*)p;
                else {
                    float tmp[4] = {0, 0, 0, 0};
                    for (int j = 0; j < 4; ++j) if (k0 + kq + j < K) tmp[j] = p[j];
                    v = {tmp[0], tmp[1], tmp[2], tmp[3]};
                }
            }
            Bs[kq + 0][nn] = v.x; Bs[kq + 1][nn] = v.y; Bs[kq + 2][nn] = v.z; Bs[kq + 3][nn] = v.w;
        }
        __syncthreads();
        #pragma unroll
        for (int kk = 0; kk < TK_; ++kk) {
            float4 a4 = *(const float4*)&As[kk][tm];
            float4 b4 = *(const float4*)&Bs[kk][tn];
            float a0[4] = {a4.x, a4.y, a4.z, a4.w};
            float b0[4] = {b4.x, b4.y, b4.z, b4.w};
            #pragma unroll
            for (int i = 0; i < 4; ++i)
                #pragma unroll
                for (int j = 0; j < 4; ++j)
                    acc[i][j] += a0[i] * b0[j];
        }
        __syncthreads();
    }
    for (int i = 0; i < 4; ++i) {
        int gm = row0 + tm + i;
        if (gm >= M) continue;
        for (int j = 0; j < 4; ++j) {
            int gn = col0 + tn + j;
            if (gn >= N) continue;
            float v = acc[i][j] * alpha;
            if (bias) v += bias[gn];
            long long idx = cbase + (long long)gm * ldc + gn;
            if (RES) v += res[idx];
            C[idx] = v;
        }
    }
}

// ---------------- host side ----------------

static inline void gemm(bool tb, bool resf,
                        const float* A, const float* B, const float* bias, const float* res, float* C,
                        int M, int N, int K, int lda, int ldb, int ldc,
                        long long aO1, long long aO2, long long bO1, long long bO2,
                        long long cO1, long long cO2, int batches, int subBatch, float alpha,
                        hipStream_t s) {
    dim3 g((N + TN_ - 1) / TN_, (M + TM_ - 1) / TM_, batches), blk(256);
    if (!tb && !resf)      gemm_k<false, false><<<g, blk, 0, s>>>(A, B, bias, res, C, M, N, K, lda, ldb, ldc, aO1, aO2, bO1, bO2, cO1, cO2, subBatch, alpha);
    else if (tb && !resf)  gemm_k<true,  false><<<g, blk, 0, s>>>(A, B, bias, res, C, M, N, K, lda, ldb, ldc, aO1, aO2, bO1, bO2, cO1, cO2, subBatch, alpha);
    else if (!tb && resf)  gemm_k<false, true ><<<g, blk, 0, s>>>(A, B, bias, res, C, M, N, K, lda, ldb, ldc, aO1, aO2, bO1, bO2, cO1, cO2, subBatch, alpha);
    else                   gemm_k<true,  true ><<<g, blk, 0, s>>>(A, B, bias, res, C, M, N, K, lda, ldb, ldc, aO1, aO2, bO1, bO2, cO1, cO2, subBatch, alpha);
}

extern "C" void kernel_launch(void* const* d_in, const int* in_sizes, int n_in,
                              void* d_out, int out_size, void* d_ws, size_t ws_size,
                              hipStream_t stream) {
    const int*   text   = (const int*)d_in[0];
    const float* images = (const float*)d_in[1];
    const float* alphap = (const float*)d_in[2];
    const float* dgam   = (const float*)d_in[3];
    const float* dbeta  = (const float*)d_in[4];
    const float* imgW   = (const float*)d_in[5];
    const float* imgb   = (const float*)d_in[6];
    const float* g1W    = (const float*)d_in[7];
    const float* g1b    = (const float*)d_in[8];
    const float* g2W    = (const float*)d_in[9];
    const float* g2b    = (const float*)d_in[10];
    const float* temb   = (const float*)d_in[11];
    const float* pemb   = (const float*)d_in[12];
    const float* ln1g   = (const float*)d_in[13];
    const float* ln1b   = (const float*)d_in[14];
    const float* inW    = (const float*)d_in[15];
    const float* convW  = (const float*)d_in[16];
    const float* convb  = (const float*)d_in[17];
    const float* xpW    = (const float*)d_in[18];
    const float* dtW    = (const float*)d_in[19];
    const float* dtb    = (const float*)d_in[20];
    const float* Alog   = (const float*)d_in[21];
    const float* Dsk    = (const float*)d_in[22];
    const float* outW   = (const float*)d_in[23];
    const float* ln2g   = (const float*)d_in[24];
    const float* ln2b   = (const float*)d_in[25];
    const float* ainW   = (const float*)d_in[26];
    const float* ainb   = (const float*)d_in[27];
    const float* aoutW  = (const float*)d_in[28];
    const float* aoutb  = (const float*)d_in[29];
    const float* fng    = (const float*)d_in[30];
    const float* fnb    = (const float*)d_in[31];
    const float* lgW    = (const float*)d_in[32];
    const float* lgb    = (const float*)d_in[33];
    float* out = (float*)d_out;

    float* w = (float*)d_ws;
    float* imgd   = w; w += (size_t)B_ * CTX_ * IMGD_;
    float* imgf   = w; w += (size_t)B_ * CTX_ * DIM_;
    float* pooled = w; w += B_ * DIM_;
    float* g1     = w; w += B_ * 128;
    float* gate   = w; w += B_ * DIM_;
    float* x      = w; w += (size_t)B_ * N_ * DIM_;
    float* xn     = w; w += (size_t)B_ * N_ * DIM_;
    float* xz     = w; w += (size_t)B_ * N_ * 2 * DIN_;
    float* xc     = w; w += (size_t)B_ * N_ * DIN_;
    float* dblb   = w; w += (size_t)B_ * N_ * 64;
    float* dtp    = w; w += (size_t)B_ * N_ * DIN_;
    float* yb     = w; w += (size_t)B_ * N_ * DIN_;
    float* q      = w; w += (size_t)B_ * N_ * DIM_;
    float* kb     = w; w += (size_t)B_ * CTX_ * DIM_;
    float* vb     = w; w += (size_t)B_ * CTX_ * DIM_;
    float* att    = w; w += (size_t)B_ * HEADS_ * N_ * CTX_;
    float* ob     = w; w += (size_t)B_ * N_ * DIM_;

    // scan scratch aliased onto attention buffers (attention is written
    // AFTER the scan inside each layer; no overlap in live ranges)
    float* ubuf   = att;   // needs B_*N_*DIN_  = 2M  <= 3.2M  OK
    float* chunkA = ob;    // needs 1M  <= 1M  OK
    float* chunkB = q;     // needs 1M  <= 1M  OK

    const int TOKENS = B_ * N_;       // 2048
    const int IMGT   = B_ * CTX_;     // 1568
    const int SCANT  = B_ * DIN_ * DST_ * NCHUNK_;  // 1048576

    // image path
    {
        int total = B_ * CTX_ * IMGD_;
        dyt_kernel<<<(total + 255) / 256, 256, 0, stream>>>(images, alphap, dgam, dbeta, imgd, total);
        gemm(false, false, imgd, imgW, imgb, nullptr, imgf,
             IMGT, DIM_, IMGD_, IMGD_, DIM_, DIM_, 0, 0, 0, 0, 0, 0, 1, 1, 1.f, stream);
        pool_kernel<<<(B_ * DIM_ + 255) / 256, 256, 0, stream>>>(imgf, pooled);
        gate1_kernel<<<(B_ * 128 + 255) / 256, 256, 0, stream>>>(pooled, g1W, g1b, g1);
        gate2_kernel<<<(B_ * DIM_ + 255) / 256, 256, 0, stream>>>(g1, g2W, g2b, gate);
        scale_kernel<<<(B_ * CTX_ * DIM_ + 255) / 256, 256, 0, stream>>>(imgf, gate);
    }
    // embedding
    embed_kernel<<<(TOKENS * DIM_ + 255) / 256, 256, 0, stream>>>(text, temb, pemb, x);

    for (int l = 0; l < DEPTH_; ++l) {
        const float* W_in  = inW  + (size_t)l * DIM_ * 2 * DIN_;
        const float* cw    = convW + (size_t)l * DIN_ * 4;
        const float* cb    = convb + (size_t)l * DIN_;
        const float* xpw   = xpW  + (size_t)l * DIN_ * 64;
        const float* dtw   = dtW  + (size_t)l * DTR_ * DIN_;
        const float* dtbi  = dtb  + (size_t)l * DIN_;
        const float* alog  = Alog + (size_t)l * DIN_ * DST_;
        const float* dsk   = Dsk  + (size_t)l * DIN_;
        const float* ow    = outW + (size_t)l * DIN_ * DIM_;
        const float* aw    = ainW + (size_t)l * 3 * DIM_ * DIM_;
        const float* ab    = ainb + (size_t)l * 3 * DIM_;
        const float* aow   = aoutW + (size_t)l * DIM_ * DIM_;
        const float* aob   = aoutb + (size_t)l * DIM_;

        // mamba block
        ln_kernel<<<TOKENS / 4, 256, 0, stream>>>(x, ln1g + l * DIM_, ln1b + l * DIM_, xn, TOKENS);
        gemm(false, false, xn, W_in, nullptr, nullptr, xz,
             TOKENS, 2 * DIN_, DIM_, DIM_, 2 * DIN_, 2 * DIN_, 0, 0, 0, 0, 0, 0, 1, 1, 1.f, stream);
        conv_silu_kernel<<<(TOKENS * DIN_ + 255) / 256, 256, 0, stream>>>(xz, cw, cb, xc);
        gemm(false, false, xc, xpw, nullptr, nullptr, dblb,
             TOKENS, 64, DIN_, DIN_, 64, 64, 0, 0, 0, 0, 0, 0, 1, 1, 1.f, stream);
        gemm(false, false, dblb, dtw, dtbi, nullptr, dtp,
             TOKENS, DIN_, DTR_, 64, DIN_, DIN_, 0, 0, 0, 0, 0, 0, 1, 1, 1.f, stream);
        dt_prep_kernel<<<(TOKENS * DIN_ + 255) / 256, 256, 0, stream>>>(dtp, xc, ubuf);
        scan1_kernel<<<SCANT / 256, 256, 0, stream>>>(dtp, ubuf, dblb, alog, chunkA, chunkB);
        scan2_kernel<<<SCANT / 256, 256, 0, stream>>>(dtp, ubuf, dblb, xc, xz, alog, dsk,
                                                      chunkA, chunkB, yb);
        gemm(false, true, yb, ow, nullptr, x, x,
             TOKENS, DIM_, DIN_, DIN_, DIM_, DIM_, 0, 0, 0, 0, 0, 0, 1, 1, 1.f, stream);

        // cross-attention block
        ln_kernel<<<TOKENS / 4, 256, 0, stream>>>(x, ln2g + l * DIM_, ln2b + l * DIM_, xn, TOKENS);
        gemm(true, false, xn, aw, ab, nullptr, q,
             TOKENS, DIM_, DIM_, DIM_, DIM_, DIM_, 0, 0, 0, 0, 0, 0, 1, 1, 1.f, stream);
        gemm(true, false, imgf, aw + (size_t)DIM_ * DIM_, ab + DIM_, nullptr, kb,
             IMGT, DIM_, DIM_, DIM_, DIM_, DIM_, 0, 0, 0, 0, 0, 0, 1, 1, 1.f, stream);
        gemm(true, false, imgf, aw + (size_t)2 * DIM_ * DIM_, ab + 2 * DIM_, nullptr, vb,
             IMGT, DIM_, DIM_, DIM_, DIM_, DIM_, 0, 0, 0, 0, 0, 0, 1, 1, 1.f, stream);
        gemm(true, false, q, kb, nullptr, nullptr, att,
             N_, CTX_, HD_, DIM_, DIM_, CTX_,
             (long long)N_ * DIM_, HD_,
             (long long)CTX_ * DIM_, HD_,
             (long long)HEADS_ * N_ * CTX_, (long long)N_ * CTX_,
             B_ * HEADS_, HEADS_, 0.125f, stream);
        softmax_kernel<<<(B_ * HEADS_ * N_) / 4, 256, 0, stream>>>(att, B_ * HEADS_ * N_);
        gemm(false, false, att, vb, nullptr, nullptr, ob,
             N_, HD_, CTX_, CTX_, DIM_, DIM_,
             (long long)HEADS_ * N_ * CTX_, (long long)N_ * CTX_,
             (long long)CTX_ * DIM_, HD_,
             (long long)N_ * DIM_, HD_,
             B_ * HEADS_, HEADS_, 1.f, stream);
        gemm(true, true, ob, aow, aob, x, x,
             TOKENS, DIM_, DIM_, DIM_, DIM_, DIM_, 0, 0, 0, 0, 0, 0, 1, 1, 1.f, stream);
    }

    // final LN + logits
    ln_kernel<<<TOKENS / 4, 256, 0, stream>>>(x, fng, fnb, xn, TOKENS);
    gemm(false, false, xn, lgW, lgb, nullptr, out,
         TOKENS, 10000, DIM_, DIM_, 10000, 10000, 0, 0, 0, 0, 0, 0, 1, 1, 1.f, stream);
}

// Round 3
// 3437.342 us; speedup vs baseline: 1.4521x; 1.0553x over previous
//
#include <hip/hip_runtime.h>
#include <hip/hip_bf16.h>
#include <stdint.h>

#define B_    8
#define N_    256
#define CTX_  196
#define IMGD_ 1024
#define DIM_  512
#define DEPTH_ 6
#define DIN_  1024
#define DTR_  32
#define DST_  16
#define HEADS_ 8
#define HD_   64
#define NCHUNK_ 8
#define CLEN_   32   // N_/NCHUNK_

typedef __bf16 bf16x8 __attribute__((ext_vector_type(8)));
typedef __bf16 bf16x4 __attribute__((ext_vector_type(4)));
typedef float  f32x4  __attribute__((ext_vector_type(4)));

// ---------------- elementwise / small kernels ----------------

__global__ void dyt_kernel(const float* __restrict__ img, const float* __restrict__ alpha_p,
                           const float* __restrict__ gamma, const float* __restrict__ beta,
                           float* __restrict__ out, int total) {
    int i = blockIdx.x * 256 + threadIdx.x;
    if (i >= total) return;
    float a = alpha_p[0];
    int c = i & (IMGD_ - 1);
    out[i] = gamma[c] * tanhf(a * img[i]) + beta[c];
}

__global__ void pool_kernel(const float* __restrict__ imgf, float* __restrict__ pooled) {
    int i = blockIdx.x * 256 + threadIdx.x;
    if (i >= B_ * DIM_) return;
    int b = i >> 9, c = i & (DIM_ - 1);
    const float* p = imgf + (size_t)b * CTX_ * DIM_ + c;
    float s = 0.f;
    for (int t = 0; t < CTX_; ++t) s += p[t * DIM_];
    pooled[i] = s * (1.f / CTX_);
}

__global__ void gate1_kernel(const float* __restrict__ pooled, const float* __restrict__ W,
                             const float* __restrict__ bias, float* __restrict__ g1) {
    int i = blockIdx.x * 256 + threadIdx.x;
    if (i >= B_ * 128) return;
    int b = i >> 7, j = i & 127;
    const float* p = pooled + b * DIM_;
    float s = bias[j];
    for (int c = 0; c < DIM_; ++c) s += p[c] * W[c * 128 + j];
    g1[i] = 0.5f * s * (1.f + erff(s * 0.70710678118654752f));
}

__global__ void gate2_kernel(const float* __restrict__ g1, const float* __restrict__ W,
                             const float* __restrict__ bias, float* __restrict__ gate) {
    int i = blockIdx.x * 256 + threadIdx.x;
    if (i >= B_ * DIM_) return;
    int b = i >> 9, c = i & (DIM_ - 1);
    const float* p = g1 + b * 128;
    float s = bias[c];
    for (int j = 0; j < 128; ++j) s += p[j] * W[j * DIM_ + c];
    gate[i] = 1.f / (1.f + __expf(-s));
}

__global__ void scale_kernel(float* __restrict__ imgf, const float* __restrict__ gate) {
    int i = blockIdx.x * 256 + threadIdx.x;
    if (i >= B_ * CTX_ * DIM_) return;
    int c = i & (DIM_ - 1);
    int b = i / (CTX_ * DIM_);
    imgf[i] *= gate[b * DIM_ + c];
}

__global__ void embed_kernel(const int* __restrict__ text, const float* __restrict__ temb,
                             const float* __restrict__ pemb, float* __restrict__ x) {
    int i = blockIdx.x * 256 + threadIdx.x;
    if (i >= B_ * N_ * DIM_) return;
    int c = i & (DIM_ - 1);
    int row = i >> 9;
    int n = row & (N_ - 1);
    int tok = text[row];
    x[i] = temb[(size_t)tok * DIM_ + c] + pemb[(size_t)n * DIM_ + c];
}

// wave-per-row layernorm, row = 512 floats
__global__ void ln_kernel(const float* __restrict__ x, const float* __restrict__ g,
                          const float* __restrict__ b, float* __restrict__ o, int rows) {
    int row = blockIdx.x * 4 + (threadIdx.x >> 6);
    if (row >= rows) return;
    int lane = threadIdx.x & 63;
    const float* xr = x + (size_t)row * DIM_ + lane * 8;
    float4 v0 = ((const float4*)xr)[0];
    float4 v1 = ((const float4*)xr)[1];
    float r[8] = {v0.x, v0.y, v0.z, v0.w, v1.x, v1.y, v1.z, v1.w};
    float sum = 0.f, sq = 0.f;
    #pragma unroll
    for (int j = 0; j < 8; ++j) { sum += r[j]; sq += r[j] * r[j]; }
    #pragma unroll
    for (int m = 1; m < 64; m <<= 1) { sum += __shfl_xor(sum, m); sq += __shfl_xor(sq, m); }
    float mean = sum * (1.f / DIM_);
    float var  = sq * (1.f / DIM_) - mean * mean;
    float inv  = rsqrtf(fmaxf(var, 0.f) + 1e-5f);
    const float* gp = g + lane * 8;
    const float* bp = b + lane * 8;
    float* op = o + (size_t)row * DIM_ + lane * 8;
    float4 o0, o1;
    o0.x = (r[0]-mean)*inv*gp[0]+bp[0]; o0.y = (r[1]-mean)*inv*gp[1]+bp[1];
    o0.z = (r[2]-mean)*inv*gp[2]+bp[2]; o0.w = (r[3]-mean)*inv*gp[3]+bp[3];
    o1.x = (r[4]-mean)*inv*gp[4]+bp[4]; o1.y = (r[5]-mean)*inv*gp[5]+bp[5];
    o1.z = (r[6]-mean)*inv*gp[6]+bp[6]; o1.w = (r[7]-mean)*inv*gp[7]+bp[7];
    ((float4*)op)[0] = o0; ((float4*)op)[1] = o1;
}

// causal depthwise conv (4 taps) + SiLU
__global__ void conv_silu_kernel(const float* __restrict__ xz, const float* __restrict__ cw,
                                 const float* __restrict__ cb, float* __restrict__ xc) {
    int i = blockIdx.x * 256 + threadIdx.x;
    if (i >= B_ * N_ * DIN_) return;
    int d = i & (DIN_ - 1);
    int row = i >> 10;
    int n = row & (N_ - 1);
    int rowb = row - n;
    float acc = cb[d];
    #pragma unroll
    for (int k = 0; k < 4; ++k) {
        int m = n - 3 + k;
        if (m >= 0) acc += xz[(size_t)(rowb + m) * (2 * DIN_) + d] * cw[d * 4 + k];
    }
    xc[i] = acc / (1.f + __expf(-acc));
}

// dt = softplus(dtp) (overwrite dtp); u = dt * xc
__global__ void dt_prep_kernel(float* __restrict__ dtp, const float* __restrict__ xc,
                               float* __restrict__ u) {
    int i = blockIdx.x * 256 + threadIdx.x;
    if (i >= B_ * N_ * DIN_) return;
    float v = dtp[i];
    float e = __expf(-fabsf(v));
    float dt = fmaxf(v, 0.f) + __logf(1.f + e);
    dtp[i] = dt;
    u[i] = dt * xc[i];
}

// ---------------- chunked selective scan ----------------
__global__ __launch_bounds__(256) void scan1_kernel(
    const float* __restrict__ dtp, const float* __restrict__ u,
    const float* __restrict__ dbl, const float* __restrict__ A_log,
    float* __restrict__ chunkA, float* __restrict__ chunkB) {
    int t = blockIdx.x * 256 + threadIdx.x;
    int s = t & 15;
    int d = (t >> 4) & (DIN_ - 1);
    int c = (t >> 14) & (NCHUNK_ - 1);
    int b = t >> 17;
    float As = -__expf(A_log[(d << 4) | s]);
    float a = 1.f, hb = 0.f;
    int row0 = b * N_ + c * CLEN_;
    for (int n = 0; n < CLEN_; ++n) {
        int row = row0 + n;
        float dt = dtp[(size_t)row * DIN_ + d];
        float uu = u[(size_t)row * DIN_ + d];
        float Bv = dbl[row * 64 + 32 + s];
        float dA = __expf(dt * As);
        hb = hb * dA + uu * Bv;
        a *= dA;
    }
    chunkA[t] = a;
    chunkB[t] = hb;
}

__global__ __launch_bounds__(256) void scan2_kernel(
    const float* __restrict__ dtp, const float* __restrict__ u,
    const float* __restrict__ dbl, const float* __restrict__ xc,
    const float* __restrict__ xz, const float* __restrict__ A_log,
    const float* __restrict__ Dsk,
    const float* __restrict__ chunkA, const float* __restrict__ chunkB,
    float* __restrict__ yb) {
    int t = blockIdx.x * 256 + threadIdx.x;
    int s = t & 15;
    int d = (t >> 4) & (DIN_ - 1);
    int c = (t >> 14) & (NCHUNK_ - 1);
    int b = t >> 17;
    float h = 0.f;
    int base = (b << 17) | (d << 4) | s;
    for (int j = 0; j < c; ++j) {
        int idx = base | (j << 14);
        h = h * chunkA[idx] + chunkB[idx];
    }
    float As = -__expf(A_log[(d << 4) | s]);
    float Dv = Dsk[d];
    int row0 = b * N_ + c * CLEN_;
    for (int n = 0; n < CLEN_; ++n) {
        int row = row0 + n;
        float dt = dtp[(size_t)row * DIN_ + d];
        float uu = u[(size_t)row * DIN_ + d];
        float Bv = dbl[row * 64 + 32 + s];
        float Cv = dbl[row * 64 + 48 + s];
        float dA = __expf(dt * As);
        h = h * dA + uu * Bv;
        float p = h * Cv;
        p += __shfl_xor(p, 1);
        p += __shfl_xor(p, 2);
        p += __shfl_xor(p, 4);
        p += __shfl_xor(p, 8);
        if (s == 0) {
            float z = xz[(size_t)row * (2 * DIN_) + DIN_ + d];
            float xcv = xc[(size_t)row * DIN_ + d];
            float y = (p + xcv * Dv) * (z / (1.f + __expf(-z)));
            yb[(size_t)row * DIN_ + d] = y;
        }
    }
}

// wave-per-row softmax over CTX_=196
__global__ void softmax_kernel(float* __restrict__ att, int rows) {
    int row = blockIdx.x * 4 + (threadIdx.x >> 6);
    if (row >= rows) return;
    int lane = threadIdx.x & 63;
    float* ar = att + (size_t)row * CTX_;
    float v[4];
    float mx = -1e30f;
    #pragma unroll
    for (int j = 0; j < 4; ++j) {
        int idx = lane + j * 64;
        v[j] = idx < CTX_ ? ar[idx] : -1e30f;
        mx = fmaxf(mx, v[j]);
    }
    #pragma unroll
    for (int m = 1; m < 64; m <<= 1) mx = fmaxf(mx, __shfl_xor(mx, m));
    float sm = 0.f;
    #pragma unroll
    for (int j = 0; j < 4; ++j) {
        int idx = lane + j * 64;
        v[j] = idx < CTX_ ? __expf(v[j] - mx) : 0.f;
        sm += v[j];
    }
    #pragma unroll
    for (int m = 1; m < 64; m <<= 1) sm += __shfl_xor(sm, m);
    float inv = 1.f / sm;
    #pragma unroll
    for (int j = 0; j < 4; ++j) {
        int idx = lane + j * 64;
        if (idx < CTX_) ar[idx] = v[j] * inv;
    }
}

// ---------------- weight prep: fp32 -> bf16 ----------------

// straight convert (weights already [N][K] row-major)
__global__ void conv_bf16_kernel(const float* __restrict__ src, __bf16* __restrict__ dst, int count) {
    int i = (blockIdx.x * 256 + threadIdx.x) * 4;
    if (i >= count) return;
    float4 v = *(const float4*)(src + i);
    bf16x4 p = {(__bf16)v.x, (__bf16)v.y, (__bf16)v.z, (__bf16)v.w};
    *(bf16x4*)(dst + i) = p;
}

// transpose+convert: src [K][N] fp32 (batched by z) -> dst [N][K] bf16
__global__ void tconv_kernel(const float* __restrict__ src, __bf16* __restrict__ dst,
                             int K, int N) {
    __shared__ float tile[32][33];
    int n0 = blockIdx.x * 32, k0 = blockIdx.y * 32;
    src += (size_t)blockIdx.z * K * N;
    dst += (size_t)blockIdx.z * K * N;
    int tx = threadIdx.x & 31, ty = threadIdx.x >> 5;
    #pragma unroll
    for (int i = 0; i < 32; i += 8) {
        int k = k0 + ty + i, n = n0 + tx;
        tile[ty + i][tx] = (k < K && n < N) ? src[(size_t)k * N + n] : 0.f;
    }
    __syncthreads();
    #pragma unroll
    for (int i = 0; i < 32; i += 8) {
        int n = n0 + ty + i, k = k0 + tx;
        if (n < N && k < K) dst[(size_t)n * K + k] = (__bf16)tile[tx][ty + i];
    }
}

// ---------------- bf16 MFMA GEMM ----------------
// C[m][n] = sum_k A[m][k] * Bw[n][k] (+bias[n]) (+res[m][n])
// A fp32 (converted to bf16 during staging), Bw bf16 [N][K] row-major.
#define BM_ 128
#define BN_ 128
#define BK_ 32
#define LDP_ 40   // padded LDS row length in bf16 (80 B -> 2-way banks, free)

__global__ __launch_bounds__(256) void mgemm_k(
    const float* __restrict__ A, const __bf16* __restrict__ Bw,
    const float* __restrict__ bias, const float* __restrict__ res,
    float* __restrict__ C, int M, int N, int K, int lda, int ldc) {
    __shared__ __align__(16) __bf16 As[BM_ * LDP_];
    __shared__ __align__(16) __bf16 Bs[BN_ * LDP_];
    int tid = threadIdx.x;
    int row0 = blockIdx.y * BM_, col0 = blockIdx.x * BN_;
    int wave = tid >> 6, lane = tid & 63;
    int wm = (wave >> 1) * 64, wn = (wave & 1) * 64;
    int fr = lane & 15, fk = lane >> 4;
    f32x4 acc[4][4] = {};

    for (int k0 = 0; k0 < K; k0 += BK_) {
        // stage A: 128 x 32 fp32 -> bf16
        #pragma unroll
        for (int i = 0; i < 4; ++i) {
            int idx = i * 256 + tid;
            int r = idx >> 3, k4 = (idx & 7) * 4;
            int gm = row0 + r;
            float4 v = {0.f, 0.f, 0.f, 0.f};
            if (gm < M) v = *(const float4*)(A + (size_t)gm * lda + k0 + k4);
            bf16x4 p = {(__bf16)v.x, (__bf16)v.y, (__bf16)v.z, (__bf16)v.w};
            *(bf16x4*)&As[r * LDP_ + k4] = p;
        }
        // stage B: 128 n-rows x 32 k (bf16, already [N][K])
        #pragma unroll
        for (int i = 0; i < 2; ++i) {
            int idx = i * 256 + tid;
            int n = idx >> 2, kc = (idx & 3) * 8;
            int gn = col0 + n;
            uint4 u = {0u, 0u, 0u, 0u};
            if (gn < N) u = *(const uint4*)(Bw + (size_t)gn * K + k0 + kc);
            *(uint4*)&Bs[n * LDP_ + kc] = u;
        }
        __syncthreads();
        bf16x8 af[4], bg[4];
        #pragma unroll
        for (int mf = 0; mf < 4; ++mf)
            af[mf] = *(const bf16x8*)&As[(wm + mf * 16 + fr) * LDP_ + fk * 8];
        #pragma unroll
        for (int nf = 0; nf < 4; ++nf)
            bg[nf] = *(const bf16x8*)&Bs[(wn + nf * 16 + fr) * LDP_ + fk * 8];
        #pragma unroll
        for (int mf = 0; mf < 4; ++mf)
            #pragma unroll
            for (int nf = 0; nf < 4; ++nf)
                acc[mf][nf] = __builtin_amdgcn_mfma_f32_16x16x32_bf16(af[mf], bg[nf], acc[mf][nf], 0, 0, 0);
        __syncthreads();
    }
    // epilogue: D[(lane>>4)*4+e][lane&15] per 16x16 frag
    #pragma unroll
    for (int mf = 0; mf < 4; ++mf) {
        #pragma unroll
        for (int nf = 0; nf < 4; ++nf) {
            int gn = col0 + wn + nf * 16 + fr;
            if (gn >= N) continue;
            float bb = bias ? bias[gn] : 0.f;
            #pragma unroll
            for (int e = 0; e < 4; ++e) {
                int gm = row0 + wm + mf * 16 + fk * 4 + e;
                if (gm >= M) continue;
                size_t idx = (size_t)gm * ldc + gn;
                float v = acc[mf][nf][e] + bb;
                if (res) v += res[idx];
                C[idx] = v;
            }
        }
    }
}

static inline void mgemm(const float* A, const __bf16* Bw, const float* bias,
                         const float* res, float* C, int M, int N, int K,
                         int lda, int ldc, hipStream_t s) {
    dim3 g((N + BN_ - 1) / BN_, (M + BM_ - 1) / BM_);
    mgemm_k<<<g, 256, 0, s>>>(A, Bw, bias, res, C, M, N, K, lda, ldc);
}

// ---------------- generic fp32 GEMM (small/batched shapes) ----------------
#define TM_ 64
#define TN_ 64
#define TK_ 16

template <bool TB, bool RES>
__global__ __launch_bounds__(256) void gemm_k(
    const float* __restrict__ A, const float* __restrict__ B,
    const float* __restrict__ bias, const float* res, float* C,
    int M, int N, int K, int lda, int ldb, int ldc,
    long long aO1, long long aO2, long long bO1, long long bO2,
    long long cO1, long long cO2, int subBatch, float alpha) {
    int z = blockIdx.z;
    int b1 = z / subBatch, b2 = z % subBatch;
    A += b1 * aO1 + b2 * aO2;
    B += b1 * bO1 + b2 * bO2;
    long long cbase = b1 * cO1 + b2 * cO2;

    __shared__ float As[TK_][TM_ + 4];
    __shared__ float Bs[TK_][TN_ + 4];
    int tid = threadIdx.x;
    int row0 = blockIdx.y * TM_;
    int col0 = blockIdx.x * TN_;
    int tm = (tid / 16) * 4, tn = (tid % 16) * 4;
    float acc[4][4] = {};
    int nk = (K + TK_ - 1) / TK_;

    for (int kt = 0; kt < nk; ++kt) {
        int k0 = kt * TK_;
        {
            int m = tid >> 2, kq = (tid & 3) * 4;
            int gm = row0 + m;
            float4 v = {0, 0, 0, 0};
            if (gm < M) {
                const float* p = A + (size_t)gm * lda + k0 + kq;
                if (k0 + kq + 3 < K) v = *(const float4*)p;
                else {
                    float tmp[4] = {0, 0, 0, 0};
                    for (int j = 0; j < 4; ++j) if (k0 + kq + j < K) tmp[j] = p[j];
                    v = {tmp[0], tmp[1], tmp[2], tmp[3]};
                }
            }
            As[kq + 0][m] = v.x; As[kq + 1][m] = v.y; As[kq + 2][m] = v.z; As[kq + 3][m] = v.w;
        }
        if (!TB) {
            int kk = tid >> 4, nq = (tid & 15) * 4;
            int gk = k0 + kk;
            float4 v = {0, 0, 0, 0};
            if (gk < K) {
                const float* p = B + (size_t)gk * ldb + col0 + nq;
                if (col0 + nq + 3 < N) v = *(const float4*)p;
                else {
                    float tmp[4] = {0, 0, 0, 0};
                    for (int j = 0; j < 4; ++j) if (col0 + nq + j < N) tmp[j] = p[j];
                    v = {tmp[0], tmp[1], tmp[2], tmp[3]};
                }
            }
            Bs[kk][nq + 0] = v.x; Bs[kk][nq + 1] = v.y; Bs[kk][nq + 2] = v.z; Bs[kk][nq + 3] = v.w;
        } else {
            int nn = tid >> 2, kq = (tid & 3) * 4;
            int gn = col0 + nn;
            float4 v = {0, 0, 0, 0};
            if (gn < N) {
                const float* p = B + (size_t)gn * ldb + k0 + kq;
                if (k0 + kq + 3 < K) v = *(const float4*)p;
                else {
                    float tmp[4] = {0, 0, 0, 0};
                    for (int j = 0; j < 4; ++j) if (k0 + kq + j < K) tmp[j] = p[j];
                    v = {tmp[0], tmp[1], tmp[2], tmp[3]};
                }
            }
            Bs[kq + 0][nn] = v.x; Bs[kq + 1][nn] = v.y; Bs[kq + 2][nn] = v.z; Bs[kq + 3][nn] = v.w;
        }
        __syncthreads();
        #pragma unroll
        for (int kk = 0; kk < TK_; ++kk) {
            float4 a4 = *(const float4*)&As[kk][tm];
            float4 b4 = *(const float4*)&Bs[kk][tn];
            float a0[4] = {a4.x, a4.y, a4.z, a4.w};
            float b0[4] = {b4.x, b4.y, b4.z, b4.w};
            #pragma unroll
            for (int i = 0; i < 4; ++i)
                #pragma unroll
                for (int j = 0; j < 4; ++j)
                    acc[i][j] += a0[i] * b0[j];
        }
        __syncthreads();
    }
    for (int i = 0; i < 4; ++i) {
        int gm = row0 + tm + i;
        if (gm >= M) continue;
        for (int j = 0; j < 4; ++j) {
            int gn = col0 + tn + j;
            if (gn >= N) continue;
            float v = acc[i][j] * alpha;
            if (bias) v += bias[gn];
            long long idx = cbase + (long long)gm * ldc + gn;
            if (RES) v += res[idx];
            C[idx] = v;
        }
    }
}

static inline void gemm(bool tb, bool resf,
                        const float* A, const float* B, const float* bias, const float* res, float* C,
                        int M, int N, int K, int lda, int ldb, int ldc,
                        long long aO1, long long aO2, long long bO1, long long bO2,
                        long long cO1, long long cO2, int batches, int subBatch, float alpha,
                        hipStream_t s) {
    dim3 g((N + TN_ - 1) / TN_, (M + TM_ - 1) / TM_, batches), blk(256);
    if (!tb && !resf)      gemm_k<false, false><<<g, blk, 0, s>>>(A, B, bias, res, C, M, N, K, lda, ldb, ldc, aO1, aO2, bO1, bO2, cO1, cO2, subBatch, alpha);
    else if (tb && !resf)  gemm_k<true,  false><<<g, blk, 0, s>>>(A, B, bias, res, C, M, N, K, lda, ldb, ldc, aO1, aO2, bO1, bO2, cO1, cO2, subBatch, alpha);
    else if (!tb && resf)  gemm_k<false, true ><<<g, blk, 0, s>>>(A, B, bias, res, C, M, N, K, lda, ldb, ldc, aO1, aO2, bO1, bO2, cO1, cO2, subBatch, alpha);
    else                   gemm_k<true,  true ><<<g, blk, 0, s>>>(A, B, bias, res, C, M, N, K, lda, ldb, ldc, aO1, aO2, bO1, bO2, cO1, cO2, subBatch, alpha);
}

// ---------------- host side ----------------

extern "C" void kernel_launch(void* const* d_in, const int* in_sizes, int n_in,
                              void* d_out, int out_size, void* d_ws, size_t ws_size,
                              hipStream_t stream) {
    const int*   text   = (const int*)d_in[0];
    const float* images = (const float*)d_in[1];
    const float* alphap = (const float*)d_in[2];
    const float* dgam   = (const float*)d_in[3];
    const float* dbeta  = (const float*)d_in[4];
    const float* imgW   = (const float*)d_in[5];
    const float* imgb   = (const float*)d_in[6];
    const float* g1W    = (const float*)d_in[7];
    const float* g1b    = (const float*)d_in[8];
    const float* g2W    = (const float*)d_in[9];
    const float* g2b    = (const float*)d_in[10];
    const float* temb   = (const float*)d_in[11];
    const float* pemb   = (const float*)d_in[12];
    const float* ln1g   = (const float*)d_in[13];
    const float* ln1b   = (const float*)d_in[14];
    const float* inW    = (const float*)d_in[15];
    const float* convW  = (const float*)d_in[16];
    const float* convb  = (const float*)d_in[17];
    const float* xpW    = (const float*)d_in[18];
    const float* dtW    = (const float*)d_in[19];
    const float* dtb    = (const float*)d_in[20];
    const float* Alog   = (const float*)d_in[21];
    const float* Dsk    = (const float*)d_in[22];
    const float* outW   = (const float*)d_in[23];
    const float* ln2g   = (const float*)d_in[24];
    const float* ln2b   = (const float*)d_in[25];
    const float* ainW   = (const float*)d_in[26];
    const float* ainb   = (const float*)d_in[27];
    const float* aoutW  = (const float*)d_in[28];
    const float* aoutb  = (const float*)d_in[29];
    const float* fng    = (const float*)d_in[30];
    const float* fnb    = (const float*)d_in[31];
    const float* lgW    = (const float*)d_in[32];
    const float* lgb    = (const float*)d_in[33];
    float* out = (float*)d_out;

    float* w = (float*)d_ws;
    float* imgd   = w; w += (size_t)B_ * CTX_ * IMGD_;
    float* imgf   = w; w += (size_t)B_ * CTX_ * DIM_;
    float* pooled = w; w += B_ * DIM_;
    float* g1     = w; w += B_ * 128;
    float* gate   = w; w += B_ * DIM_;
    float* x      = w; w += (size_t)B_ * N_ * DIM_;
    float* xn     = w; w += (size_t)B_ * N_ * DIM_;
    float* xz     = w; w += (size_t)B_ * N_ * 2 * DIN_;
    float* xc     = w; w += (size_t)B_ * N_ * DIN_;
    float* dblb   = w; w += (size_t)B_ * N_ * 64;
    float* dtp    = w; w += (size_t)B_ * N_ * DIN_;
    float* yb     = w; w += (size_t)B_ * N_ * DIN_;
    float* q      = w; w += (size_t)B_ * N_ * DIM_;
    float* kb     = w; w += (size_t)B_ * CTX_ * DIM_;
    float* vb     = w; w += (size_t)B_ * CTX_ * DIM_;
    float* att    = w; w += (size_t)B_ * HEADS_ * N_ * CTX_;
    float* ob     = w; w += (size_t)B_ * N_ * DIM_;
    // bf16 weight regions (allocated in float units, cast to __bf16*)
    __bf16* inpT  = (__bf16*)w; w += (size_t)DEPTH_ * 2 * DIN_ * DIM_ / 2;    // 6x[2048][512]
    __bf16* outpT = (__bf16*)w; w += (size_t)DEPTH_ * DIM_ * DIN_ / 2;        // 6x[512][1024]
    __bf16* ainB  = (__bf16*)w; w += (size_t)DEPTH_ * 3 * DIM_ * DIM_ / 2;    // 6x[1536][512]
    __bf16* aoutB = (__bf16*)w; w += (size_t)DEPTH_ * DIM_ * DIM_ / 2;        // 6x[512][512]
    __bf16* imgWT = (__bf16*)w; w += (size_t)DIM_ * IMGD_ / 2;                // [512][1024]
    // logits bf16 [10000][512] aliased onto att (dead after layer loop; 2.56M fl <= 3.21M fl)
    __bf16* lgT = (__bf16*)att;

    // scan scratch aliased onto attention buffers
    float* ubuf   = att;   // B_*N_*DIN_ = 2M fl <= 3.21M
    float* chunkA = ob;    // 1M fl
    float* chunkB = q;     // 1M fl

    const int TOKENS = B_ * N_;       // 2048
    const int IMGT   = B_ * CTX_;     // 1568
    const int SCANT  = B_ * DIN_ * DST_ * NCHUNK_;  // 1048576

    // ---- weight prep (bf16) ----
    tconv_kernel<<<dim3(2 * DIN_ / 32, DIM_ / 32, DEPTH_), 256, 0, stream>>>(inW,  inpT,  DIM_, 2 * DIN_);
    tconv_kernel<<<dim3(DIM_ / 32, DIN_ / 32, DEPTH_),     256, 0, stream>>>(outW, outpT, DIN_, DIM_);
    tconv_kernel<<<dim3(DIM_ / 32, IMGD_ / 32, 1),         256, 0, stream>>>(imgW, imgWT, IMGD_, DIM_);
    conv_bf16_kernel<<<(DEPTH_ * 3 * DIM_ * DIM_ / 4 + 255) / 256, 256, 0, stream>>>(ainW,  ainB,  DEPTH_ * 3 * DIM_ * DIM_);
    conv_bf16_kernel<<<(DEPTH_ * DIM_ * DIM_ / 4 + 255) / 256, 256, 0, stream>>>(aoutW, aoutB, DEPTH_ * DIM_ * DIM_);

    // ---- image path ----
    {
        int total = B_ * CTX_ * IMGD_;
        dyt_kernel<<<(total + 255) / 256, 256, 0, stream>>>(images, alphap, dgam, dbeta, imgd, total);
        mgemm(imgd, imgWT, imgb, nullptr, imgf, IMGT, DIM_, IMGD_, IMGD_, DIM_, stream);
        pool_kernel<<<(B_ * DIM_ + 255) / 256, 256, 0, stream>>>(imgf, pooled);
        gate1_kernel<<<(B_ * 128 + 255) / 256, 256, 0, stream>>>(pooled, g1W, g1b, g1);
        gate2_kernel<<<(B_ * DIM_ + 255) / 256, 256, 0, stream>>>(g1, g2W, g2b, gate);
        scale_kernel<<<(B_ * CTX_ * DIM_ + 255) / 256, 256, 0, stream>>>(imgf, gate);
    }
    // embedding
    embed_kernel<<<(TOKENS * DIM_ + 255) / 256, 256, 0, stream>>>(text, temb, pemb, x);

    for (int l = 0; l < DEPTH_; ++l) {
        const __bf16* inpT_l  = inpT  + (size_t)l * 2 * DIN_ * DIM_;
        const __bf16* outpT_l = outpT + (size_t)l * DIM_ * DIN_;
        const __bf16* ainB_l  = ainB  + (size_t)l * 3 * DIM_ * DIM_;
        const __bf16* aoutB_l = aoutB + (size_t)l * DIM_ * DIM_;
        const float* cw    = convW + (size_t)l * DIN_ * 4;
        const float* cb    = convb + (size_t)l * DIN_;
        const float* xpw   = xpW  + (size_t)l * DIN_ * 64;
        const float* dtw   = dtW  + (size_t)l * DTR_ * DIN_;
        const float* dtbi  = dtb  + (size_t)l * DIN_;
        const float* alog  = Alog + (size_t)l * DIN_ * DST_;
        const float* dsk   = Dsk  + (size_t)l * DIN_;
        const float* ab    = ainb + (size_t)l * 3 * DIM_;
        const float* aob   = aoutb + (size_t)l * DIM_;

        // mamba block
        ln_kernel<<<TOKENS / 4, 256, 0, stream>>>(x, ln1g + l * DIM_, ln1b + l * DIM_, xn, TOKENS);
        mgemm(xn, inpT_l, nullptr, nullptr, xz, TOKENS, 2 * DIN_, DIM_, DIM_, 2 * DIN_, stream);
        conv_silu_kernel<<<(TOKENS * DIN_ + 255) / 256, 256, 0, stream>>>(xz, cw, cb, xc);
        gemm(false, false, xc, xpw, nullptr, nullptr, dblb,
             TOKENS, 64, DIN_, DIN_, 64, 64, 0, 0, 0, 0, 0, 0, 1, 1, 1.f, stream);
        gemm(false, false, dblb, dtw, dtbi, nullptr, dtp,
             TOKENS, DIN_, DTR_, 64, DIN_, DIN_, 0, 0, 0, 0, 0, 0, 1, 1, 1.f, stream);
        dt_prep_kernel<<<(TOKENS * DIN_ + 255) / 256, 256, 0, stream>>>(dtp, xc, ubuf);
        scan1_kernel<<<SCANT / 256, 256, 0, stream>>>(dtp, ubuf, dblb, alog, chunkA, chunkB);
        scan2_kernel<<<SCANT / 256, 256, 0, stream>>>(dtp, ubuf, dblb, xc, xz, alog, dsk,
                                                      chunkA, chunkB, yb);
        mgemm(yb, outpT_l, nullptr, x, x, TOKENS, DIM_, DIN_, DIN_, DIM_, stream);

        // cross-attention block
        ln_kernel<<<TOKENS / 4, 256, 0, stream>>>(x, ln2g + l * DIM_, ln2b + l * DIM_, xn, TOKENS);
        mgemm(xn,   ainB_l,                     ab,            nullptr, q,  TOKENS, DIM_, DIM_, DIM_, DIM_, stream);
        mgemm(imgf, ainB_l + (size_t)DIM_ * DIM_,     ab + DIM_,     nullptr, kb, IMGT,  DIM_, DIM_, DIM_, DIM_, stream);
        mgemm(imgf, ainB_l + (size_t)2 * DIM_ * DIM_, ab + 2 * DIM_, nullptr, vb, IMGT,  DIM_, DIM_, DIM_, DIM_, stream);
        gemm(true, false, q, kb, nullptr, nullptr, att,
             N_, CTX_, HD_, DIM_, DIM_, CTX_,
             (long long)N_ * DIM_, HD_,
             (long long)CTX_ * DIM_, HD_,
             (long long)HEADS_ * N_ * CTX_, (long long)N_ * CTX_,
             B_ * HEADS_, HEADS_, 0.125f, stream);
        softmax_kernel<<<(B_ * HEADS_ * N_) / 4, 256, 0, stream>>>(att, B_ * HEADS_ * N_);
        gemm(false, false, att, vb, nullptr, nullptr, ob,
             N_, HD_, CTX_, CTX_, DIM_, DIM_,
             (long long)HEADS_ * N_ * CTX_, (long long)N_ * CTX_,
             (long long)CTX_ * DIM_, HD_,
             (long long)N_ * DIM_, HD_,
             B_ * HEADS_, HEADS_, 1.f, stream);
        mgemm(ob, aoutB_l, aob, x, x, TOKENS, DIM_, DIM_, DIM_, DIM_, stream);
    }

    // final LN + logits (lgT aliases att, which is dead now)
    tconv_kernel<<<dim3((10000 + 31) / 32, DIM_ / 32, 1), 256, 0, stream>>>(lgW, lgT, DIM_, 10000);
    ln_kernel<<<TOKENS / 4, 256, 0, stream>>>(x, fng, fnb, xn, TOKENS);
    mgemm(xn, lgT, lgb, nullptr, out, TOKENS, 10000, DIM_, DIM_, 10000, stream);
}

// Round 4
// 1728.764 us; speedup vs baseline: 2.8872x; 1.9883x over previous
//
#include <hip/hip_runtime.h>
#include <hip/hip_bf16.h>
#include <stdint.h>

#define B_    8
#define N_    256
#define CTX_  196
#define IMGD_ 1024
#define DIM_  512
#define DEPTH_ 6
#define DIN_  1024
#define DTR_  32
#define DST_  16
#define HEADS_ 8
#define HD_   64
#define NCHUNK_ 8
#define CLEN_   32   // N_/NCHUNK_

typedef __bf16 bf16x8 __attribute__((ext_vector_type(8)));
typedef __bf16 bf16x4 __attribute__((ext_vector_type(4)));
typedef float  f32x4  __attribute__((ext_vector_type(4)));

// ---------------- elementwise / small kernels ----------------

__global__ void dyt_kernel(const float* __restrict__ img, const float* __restrict__ alpha_p,
                           const float* __restrict__ gamma, const float* __restrict__ beta,
                           __bf16* __restrict__ out, int total) {
    int i = blockIdx.x * 256 + threadIdx.x;
    if (i >= total) return;
    float a = alpha_p[0];
    int c = i & (IMGD_ - 1);
    out[i] = (__bf16)(gamma[c] * tanhf(a * img[i]) + beta[c]);
}

__global__ void pool_kernel(const float* __restrict__ imgf, float* __restrict__ pooled) {
    int i = blockIdx.x * 256 + threadIdx.x;
    if (i >= B_ * DIM_) return;
    int b = i >> 9, c = i & (DIM_ - 1);
    const float* p = imgf + (size_t)b * CTX_ * DIM_ + c;
    float s = 0.f;
    for (int t = 0; t < CTX_; ++t) s += p[t * DIM_];
    pooled[i] = s * (1.f / CTX_);
}

__global__ void gate1_kernel(const float* __restrict__ pooled, const float* __restrict__ W,
                             const float* __restrict__ bias, float* __restrict__ g1) {
    int i = blockIdx.x * 256 + threadIdx.x;
    if (i >= B_ * 128) return;
    int b = i >> 7, j = i & 127;
    const float* p = pooled + b * DIM_;
    float s = bias[j];
    for (int c = 0; c < DIM_; ++c) s += p[c] * W[c * 128 + j];
    g1[i] = 0.5f * s * (1.f + erff(s * 0.70710678118654752f));
}

__global__ void gate2_kernel(const float* __restrict__ g1, const float* __restrict__ W,
                             const float* __restrict__ bias, float* __restrict__ gate) {
    int i = blockIdx.x * 256 + threadIdx.x;
    if (i >= B_ * DIM_) return;
    int b = i >> 9, c = i & (DIM_ - 1);
    const float* p = g1 + b * 128;
    float s = bias[c];
    for (int j = 0; j < 128; ++j) s += p[j] * W[j * DIM_ + c];
    gate[i] = 1.f / (1.f + __expf(-s));
}

// reads unscaled imgf (fp32), writes gated bf16 kv-input
__global__ void scale_kernel(const float* __restrict__ imgf, const float* __restrict__ gate,
                             __bf16* __restrict__ imgfb) {
    int i = blockIdx.x * 256 + threadIdx.x;
    if (i >= B_ * CTX_ * DIM_) return;
    int c = i & (DIM_ - 1);
    int b = i / (CTX_ * DIM_);
    imgfb[i] = (__bf16)(imgf[i] * gate[b * DIM_ + c]);
}

__global__ void embed_kernel(const int* __restrict__ text, const float* __restrict__ temb,
                             const float* __restrict__ pemb, float* __restrict__ x) {
    int i = blockIdx.x * 256 + threadIdx.x;
    if (i >= B_ * N_ * DIM_) return;
    int c = i & (DIM_ - 1);
    int row = i >> 9;
    int n = row & (N_ - 1);
    int tok = text[row];
    x[i] = temb[(size_t)tok * DIM_ + c] + pemb[(size_t)n * DIM_ + c];
}

// wave-per-row layernorm, row = 512 floats, bf16 output (feeds MFMA GEMMs)
__global__ void ln_kernel(const float* __restrict__ x, const float* __restrict__ g,
                          const float* __restrict__ b, __bf16* __restrict__ o, int rows) {
    int row = blockIdx.x * 4 + (threadIdx.x >> 6);
    if (row >= rows) return;
    int lane = threadIdx.x & 63;
    const float* xr = x + (size_t)row * DIM_ + lane * 8;
    float4 v0 = ((const float4*)xr)[0];
    float4 v1 = ((const float4*)xr)[1];
    float r[8] = {v0.x, v0.y, v0.z, v0.w, v1.x, v1.y, v1.z, v1.w};
    float sum = 0.f, sq = 0.f;
    #pragma unroll
    for (int j = 0; j < 8; ++j) { sum += r[j]; sq += r[j] * r[j]; }
    #pragma unroll
    for (int m = 1; m < 64; m <<= 1) { sum += __shfl_xor(sum, m); sq += __shfl_xor(sq, m); }
    float mean = sum * (1.f / DIM_);
    float var  = sq * (1.f / DIM_) - mean * mean;
    float inv  = rsqrtf(fmaxf(var, 0.f) + 1e-5f);
    const float* gp = g + lane * 8;
    const float* bp = b + lane * 8;
    __bf16* op = o + (size_t)row * DIM_ + lane * 8;
    bf16x8 ov;
    #pragma unroll
    for (int j = 0; j < 8; ++j) ov[j] = (__bf16)((r[j] - mean) * inv * gp[j] + bp[j]);
    *(bf16x8*)op = ov;
}

// causal depthwise conv (4 taps) + SiLU; fp32 (for scan) + bf16 (for xproj GEMM)
__global__ void conv_silu_kernel(const float* __restrict__ xz, const float* __restrict__ cw,
                                 const float* __restrict__ cb, float* __restrict__ xc,
                                 __bf16* __restrict__ xcb) {
    int i = blockIdx.x * 256 + threadIdx.x;
    if (i >= B_ * N_ * DIN_) return;
    int d = i & (DIN_ - 1);
    int row = i >> 10;
    int n = row & (N_ - 1);
    int rowb = row - n;
    float acc = cb[d];
    #pragma unroll
    for (int k = 0; k < 4; ++k) {
        int m = n - 3 + k;
        if (m >= 0) acc += xz[(size_t)(rowb + m) * (2 * DIN_) + d] * cw[d * 4 + k];
    }
    float s = acc / (1.f + __expf(-acc));
    xc[i] = s;
    xcb[i] = (__bf16)s;
}

// dt = softplus(dtp) (overwrite dtp); u = dt * xc
__global__ void dt_prep_kernel(float* __restrict__ dtp, const float* __restrict__ xc,
                               float* __restrict__ u) {
    int i = blockIdx.x * 256 + threadIdx.x;
    if (i >= B_ * N_ * DIN_) return;
    float v = dtp[i];
    float e = __expf(-fabsf(v));
    float dt = fmaxf(v, 0.f) + __logf(1.f + e);
    dtp[i] = dt;
    u[i] = dt * xc[i];
}

__global__ void cvt_bf16_kernel(const float* __restrict__ src, __bf16* __restrict__ dst, int count) {
    int i = (blockIdx.x * 256 + threadIdx.x) * 4;
    if (i >= count) return;
    float4 v = *(const float4*)(src + i);
    bf16x4 p = {(__bf16)v.x, (__bf16)v.y, (__bf16)v.z, (__bf16)v.w};
    *(bf16x4*)(dst + i) = p;
}

// ---------------- chunked selective scan ----------------
__global__ __launch_bounds__(256) void scan1_kernel(
    const float* __restrict__ dtp, const float* __restrict__ u,
    const float* __restrict__ dbl, const float* __restrict__ A_log,
    float* __restrict__ chunkA, float* __restrict__ chunkB) {
    int t = blockIdx.x * 256 + threadIdx.x;
    int s = t & 15;
    int d = (t >> 4) & (DIN_ - 1);
    int c = (t >> 14) & (NCHUNK_ - 1);
    int b = t >> 17;
    float As = -__expf(A_log[(d << 4) | s]);
    float a = 1.f, hb = 0.f;
    int row0 = b * N_ + c * CLEN_;
    for (int n = 0; n < CLEN_; ++n) {
        int row = row0 + n;
        float dt = dtp[(size_t)row * DIN_ + d];
        float uu = u[(size_t)row * DIN_ + d];
        float Bv = dbl[row * 64 + 32 + s];
        float dA = __expf(dt * As);
        hb = hb * dA + uu * Bv;
        a *= dA;
    }
    chunkA[t] = a;
    chunkB[t] = hb;
}

__global__ __launch_bounds__(256) void scan2_kernel(
    const float* __restrict__ dtp, const float* __restrict__ u,
    const float* __restrict__ dbl, const float* __restrict__ xc,
    const float* __restrict__ xz, const float* __restrict__ A_log,
    const float* __restrict__ Dsk,
    const float* __restrict__ chunkA, const float* __restrict__ chunkB,
    __bf16* __restrict__ yb) {
    int t = blockIdx.x * 256 + threadIdx.x;
    int s = t & 15;
    int d = (t >> 4) & (DIN_ - 1);
    int c = (t >> 14) & (NCHUNK_ - 1);
    int b = t >> 17;
    float h = 0.f;
    int base = (b << 17) | (d << 4) | s;
    for (int j = 0; j < c; ++j) {
        int idx = base | (j << 14);
        h = h * chunkA[idx] + chunkB[idx];
    }
    float As = -__expf(A_log[(d << 4) | s]);
    float Dv = Dsk[d];
    int row0 = b * N_ + c * CLEN_;
    for (int n = 0; n < CLEN_; ++n) {
        int row = row0 + n;
        float dt = dtp[(size_t)row * DIN_ + d];
        float uu = u[(size_t)row * DIN_ + d];
        float Bv = dbl[row * 64 + 32 + s];
        float Cv = dbl[row * 64 + 48 + s];
        float dA = __expf(dt * As);
        h = h * dA + uu * Bv;
        float p = h * Cv;
        p += __shfl_xor(p, 1);
        p += __shfl_xor(p, 2);
        p += __shfl_xor(p, 4);
        p += __shfl_xor(p, 8);
        if (s == 0) {
            float z = xz[(size_t)row * (2 * DIN_) + DIN_ + d];
            float xcv = xc[(size_t)row * DIN_ + d];
            float y = (p + xcv * Dv) * (z / (1.f + __expf(-z)));
            yb[(size_t)row * DIN_ + d] = (__bf16)y;
        }
    }
}

// wave-per-row softmax over CTX_=196
__global__ void softmax_kernel(float* __restrict__ att, int rows) {
    int row = blockIdx.x * 4 + (threadIdx.x >> 6);
    if (row >= rows) return;
    int lane = threadIdx.x & 63;
    float* ar = att + (size_t)row * CTX_;
    float v[4];
    float mx = -1e30f;
    #pragma unroll
    for (int j = 0; j < 4; ++j) {
        int idx = lane + j * 64;
        v[j] = idx < CTX_ ? ar[idx] : -1e30f;
        mx = fmaxf(mx, v[j]);
    }
    #pragma unroll
    for (int m = 1; m < 64; m <<= 1) mx = fmaxf(mx, __shfl_xor(mx, m));
    float sm = 0.f;
    #pragma unroll
    for (int j = 0; j < 4; ++j) {
        int idx = lane + j * 64;
        v[j] = idx < CTX_ ? __expf(v[j] - mx) : 0.f;
        sm += v[j];
    }
    #pragma unroll
    for (int m = 1; m < 64; m <<= 1) sm += __shfl_xor(sm, m);
    float inv = 1.f / sm;
    #pragma unroll
    for (int j = 0; j < 4; ++j) {
        int idx = lane + j * 64;
        if (idx < CTX_) ar[idx] = v[j] * inv;
    }
}

// ---------------- weight prep: fp32 -> bf16 ----------------

// transpose+convert: src [K][N] fp32 (batched by z) -> dst [N][K] bf16
__global__ void tconv_kernel(const float* __restrict__ src, __bf16* __restrict__ dst,
                             int K, int N) {
    __shared__ float tile[32][33];
    int n0 = blockIdx.x * 32, k0 = blockIdx.y * 32;
    src += (size_t)blockIdx.z * K * N;
    dst += (size_t)blockIdx.z * K * N;
    int tx = threadIdx.x & 31, ty = threadIdx.x >> 5;
    #pragma unroll
    for (int i = 0; i < 32; i += 8) {
        int k = k0 + ty + i, n = n0 + tx;
        tile[ty + i][tx] = (k < K && n < N) ? src[(size_t)k * N + n] : 0.f;
    }
    __syncthreads();
    #pragma unroll
    for (int i = 0; i < 32; i += 8) {
        int n = n0 + ty + i, k = k0 + tx;
        if (n < N && k < K) dst[(size_t)n * K + k] = (__bf16)tile[tx][ty + i];
    }
}

// ---------------- bf16 MFMA GEMM v2 (double-buffered, issue-early) ----------------
// C[m][n] = sum_k A[m][k] * Bw[n][k] (+bias[n]) (+res)
// A bf16 [M][lda], Bw bf16 [N][K]. 4 waves in 2x2; wave tile (BM/2)x(BN/2).
#define LDP_ 40   // padded LDS row (bf16): 80 B stride -> 2-way bank starts (free)

template <int BM, int BN>
__global__ __launch_bounds__(256) void mgemm_k(
    const __bf16* __restrict__ A, const __bf16* __restrict__ Bw,
    const float* __restrict__ bias, const float* __restrict__ res,
    float* __restrict__ C, int M, int N, int K, int lda, int ldc) {
    constexpr int RA = BM / 64, RB = BN / 64;   // uint4 staging rounds
    constexpr int FM = BM / 32, FN = BN / 32;   // 16x16 frags per wave
    __shared__ __align__(16) __bf16 As[2][BM * LDP_];
    __shared__ __align__(16) __bf16 Bs[2][BN * LDP_];
    int tid = threadIdx.x;
    int ntx = gridDim.x;
    int nwg = ntx * gridDim.y;
    int bid = blockIdx.y * ntx + blockIdx.x;
    if ((nwg & 7) == 0) bid = (bid & 7) * (nwg >> 3) + (bid >> 3);  // XCD swizzle
    int row0 = (bid / ntx) * BM, col0 = (bid % ntx) * BN;
    int wave = tid >> 6, lane = tid & 63;
    int wm = (wave >> 1) * (BM / 2), wn = (wave & 1) * (BN / 2);
    int fr = lane & 15, fk = lane >> 4;
    f32x4 acc[FM][FN] = {};
    uint4 aR[RA], bR[RB];

    auto loadT = [&](int k0) {
        #pragma unroll
        for (int i = 0; i < RA; ++i) {
            int idx = i * 256 + tid;
            int r = idx >> 2, c = (idx & 3) * 8;
            int gm = row0 + r;
            uint4 v = {0u, 0u, 0u, 0u};
            if (gm < M) v = *(const uint4*)(A + (size_t)gm * lda + k0 + c);
            aR[i] = v;
        }
        #pragma unroll
        for (int i = 0; i < RB; ++i) {
            int idx = i * 256 + tid;
            int r = idx >> 2, c = (idx & 3) * 8;
            int gn = col0 + r;
            uint4 v = {0u, 0u, 0u, 0u};
            if (gn < N) v = *(const uint4*)(Bw + (size_t)gn * K + k0 + c);
            bR[i] = v;
        }
    };
    auto writeT = [&](int buf) {
        #pragma unroll
        for (int i = 0; i < RA; ++i) {
            int idx = i * 256 + tid;
            int r = idx >> 2, c = (idx & 3) * 8;
            *(uint4*)&As[buf][r * LDP_ + c] = aR[i];
        }
        #pragma unroll
        for (int i = 0; i < RB; ++i) {
            int idx = i * 256 + tid;
            int r = idx >> 2, c = (idx & 3) * 8;
            *(uint4*)&Bs[buf][r * LDP_ + c] = bR[i];
        }
    };

    loadT(0);
    writeT(0);
    __syncthreads();
    int NK = K >> 5;
    for (int kt = 0; kt < NK; ++kt) {
        int cur = kt & 1;
        if (kt + 1 < NK) loadT((kt + 1) << 5);   // issue next tile early
        bf16x8 af[FM], bg[FN];
        #pragma unroll
        for (int mf = 0; mf < FM; ++mf)
            af[mf] = *(const bf16x8*)&As[cur][(wm + mf * 16 + fr) * LDP_ + fk * 8];
        #pragma unroll
        for (int nf = 0; nf < FN; ++nf)
            bg[nf] = *(const bf16x8*)&Bs[cur][(wn + nf * 16 + fr) * LDP_ + fk * 8];
        #pragma unroll
        for (int mf = 0; mf < FM; ++mf)
            #pragma unroll
            for (int nf = 0; nf < FN; ++nf)
                acc[mf][nf] = __builtin_amdgcn_mfma_f32_16x16x32_bf16(af[mf], bg[nf], acc[mf][nf], 0, 0, 0);
        if (kt + 1 < NK) {
            writeT(cur ^ 1);
            __syncthreads();
        }
    }
    // epilogue: D row = wm+mf*16+fk*4+e, col = wn+nf*16+fr
    #pragma unroll
    for (int mf = 0; mf < FM; ++mf) {
        #pragma unroll
        for (int nf = 0; nf < FN; ++nf) {
            int gn = col0 + wn + nf * 16 + fr;
            if (gn >= N) continue;
            float bb = bias ? bias[gn] : 0.f;
            #pragma unroll
            for (int e = 0; e < 4; ++e) {
                int gm = row0 + wm + mf * 16 + fk * 4 + e;
                if (gm >= M) continue;
                size_t idx = (size_t)gm * ldc + gn;
                float v = acc[mf][nf][e] + bb;
                if (res) v += res[idx];
                C[idx] = v;
            }
        }
    }
}

template <int BM, int BN>
static inline void mgemm(const __bf16* A, const __bf16* Bw, const float* bias,
                         const float* res, float* C, int M, int N, int K,
                         int lda, int ldc, hipStream_t s) {
    dim3 g((N + BN - 1) / BN, (M + BM - 1) / BM);
    mgemm_k<BM, BN><<<g, 256, 0, s>>>(A, Bw, bias, res, C, M, N, K, lda, ldc);
}

// ---------------- generic fp32 GEMM (small/batched shapes) ----------------
#define TM_ 64
#define TN_ 64
#define TK_ 16

template <bool TB, bool RES>
__global__ __launch_bounds__(256) void gemm_k(
    const float* __restrict__ A, const float* __restrict__ B,
    const float* __restrict__ bias, const float* res, float* C,
    int M, int N, int K, int lda, int ldb, int ldc,
    long long aO1, long long aO2, long long bO1, long long bO2,
    long long cO1, long long cO2, int subBatch, float alpha) {
    int z = blockIdx.z;
    int b1 = z / subBatch, b2 = z % subBatch;
    A += b1 * aO1 + b2 * aO2;
    B += b1 * bO1 + b2 * bO2;
    long long cbase = b1 * cO1 + b2 * cO2;

    __shared__ float As[TK_][TM_ + 4];
    __shared__ float Bs[TK_][TN_ + 4];
    int tid = threadIdx.x;
    int row0 = blockIdx.y * TM_;
    int col0 = blockIdx.x * TN_;
    int tm = (tid / 16) * 4, tn = (tid % 16) * 4;
    float acc[4][4] = {};
    int nk = (K + TK_ - 1) / TK_;

    for (int kt = 0; kt < nk; ++kt) {
        int k0 = kt * TK_;
        {
            int m = tid >> 2, kq = (tid & 3) * 4;
            int gm = row0 + m;
            float4 v = {0, 0, 0, 0};
            if (gm < M) {
                const float* p = A + (size_t)gm * lda + k0 + kq;
                if (k0 + kq + 3 < K) v = *(const float4*)p;
                else {
                    float tmp[4] = {0, 0, 0, 0};
                    for (int j = 0; j < 4; ++j) if (k0 + kq + j < K) tmp[j] = p[j];
                    v = {tmp[0], tmp[1], tmp[2], tmp[3]};
                }
            }
            As[kq + 0][m] = v.x; As[kq + 1][m] = v.y; As[kq + 2][m] = v.z; As[kq + 3][m] = v.w;
        }
        if (!TB) {
            int kk = tid >> 4, nq = (tid & 15) * 4;
            int gk = k0 + kk;
            float4 v = {0, 0, 0, 0};
            if (gk < K) {
                const float* p = B + (size_t)gk * ldb + col0 + nq;
                if (col0 + nq + 3 < N) v = *(const float4*)p;
                else {
                    float tmp[4] = {0, 0, 0, 0};
                    for (int j = 0; j < 4; ++j) if (col0 + nq + j < N) tmp[j] = p[j];
                    v = {tmp[0], tmp[1], tmp[2], tmp[3]};
                }
            }
            Bs[kk][nq + 0] = v.x; Bs[kk][nq + 1] = v.y; Bs[kk][nq + 2] = v.z; Bs[kk][nq + 3] = v.w;
        } else {
            int nn = tid >> 2, kq = (tid & 3) * 4;
            int gn = col0 + nn;
            float4 v = {0, 0, 0, 0};
            if (gn < N) {
                const float* p = B + (size_t)gn * ldb + k0 + kq;
                if (k0 + kq + 3 < K) v = *(const float4*)p;
                else {
                    float tmp[4] = {0, 0, 0, 0};
                    for (int j = 0; j < 4; ++j) if (k0 + kq + j < K) tmp[j] = p[j];
                    v = {tmp[0], tmp[1], tmp[2], tmp[3]};
                }
            }
            Bs[kq + 0][nn] = v.x; Bs[kq + 1][nn] = v.y; Bs[kq + 2][nn] = v.z; Bs[kq + 3][nn] = v.w;
        }
        __syncthreads();
        #pragma unroll
        for (int kk = 0; kk < TK_; ++kk) {
            float4 a4 = *(const float4*)&As[kk][tm];
            float4 b4 = *(const float4*)&Bs[kk][tn];
            float a0[4] = {a4.x, a4.y, a4.z, a4.w};
            float b0[4] = {b4.x, b4.y, b4.z, b4.w};
            #pragma unroll
            for (int i = 0; i < 4; ++i)
                #pragma unroll
                for (int j = 0; j < 4; ++j)
                    acc[i][j] += a0[i] * b0[j];
        }
        __syncthreads();
    }
    for (int i = 0; i < 4; ++i) {
        int gm = row0 + tm + i;
        if (gm >= M) continue;
        for (int j = 0; j < 4; ++j) {
            int gn = col0 + tn + j;
            if (gn >= N) continue;
            float v = acc[i][j] * alpha;
            if (bias) v += bias[gn];
            long long idx = cbase + (long long)gm * ldc + gn;
            if (RES) v += res[idx];
            C[idx] = v;
        }
    }
}

static inline void gemm(bool tb, bool resf,
                        const float* A, const float* B, const float* bias, const float* res, float* C,
                        int M, int N, int K, int lda, int ldb, int ldc,
                        long long aO1, long long aO2, long long bO1, long long bO2,
                        long long cO1, long long cO2, int batches, int subBatch, float alpha,
                        hipStream_t s) {
    dim3 g((N + TN_ - 1) / TN_, (M + TM_ - 1) / TM_, batches), blk(256);
    if (!tb && !resf)      gemm_k<false, false><<<g, blk, 0, s>>>(A, B, bias, res, C, M, N, K, lda, ldb, ldc, aO1, aO2, bO1, bO2, cO1, cO2, subBatch, alpha);
    else if (tb && !resf)  gemm_k<true,  false><<<g, blk, 0, s>>>(A, B, bias, res, C, M, N, K, lda, ldb, ldc, aO1, aO2, bO1, bO2, cO1, cO2, subBatch, alpha);
    else if (!tb && resf)  gemm_k<false, true ><<<g, blk, 0, s>>>(A, B, bias, res, C, M, N, K, lda, ldb, ldc, aO1, aO2, bO1, bO2, cO1, cO2, subBatch, alpha);
    else                   gemm_k<true,  true ><<<g, blk, 0, s>>>(A, B, bias, res, C, M, N, K, lda, ldb, ldc, aO1, aO2, bO1, bO2, cO1, cO2, subBatch, alpha);
}

// ---------------- host side ----------------

extern "C" void kernel_launch(void* const* d_in, const int* in_sizes, int n_in,
                              void* d_out, int out_size, void* d_ws, size_t ws_size,
                              hipStream_t stream) {
    const int*   text   = (const int*)d_in[0];
    const float* images = (const float*)d_in[1];
    const float* alphap = (const float*)d_in[2];
    const float* dgam   = (const float*)d_in[3];
    const float* dbeta  = (const float*)d_in[4];
    const float* imgW   = (const float*)d_in[5];
    const float* imgb   = (const float*)d_in[6];
    const float* g1W    = (const float*)d_in[7];
    const float* g1b    = (const float*)d_in[8];
    const float* g2W    = (const float*)d_in[9];
    const float* g2b    = (const float*)d_in[10];
    const float* temb   = (const float*)d_in[11];
    const float* pemb   = (const float*)d_in[12];
    const float* ln1g   = (const float*)d_in[13];
    const float* ln1b   = (const float*)d_in[14];
    const float* inW    = (const float*)d_in[15];
    const float* convW  = (const float*)d_in[16];
    const float* convb  = (const float*)d_in[17];
    const float* xpW    = (const float*)d_in[18];
    const float* dtW    = (const float*)d_in[19];
    const float* dtb    = (const float*)d_in[20];
    const float* Alog   = (const float*)d_in[21];
    const float* Dsk    = (const float*)d_in[22];
    const float* outW   = (const float*)d_in[23];
    const float* ln2g   = (const float*)d_in[24];
    const float* ln2b   = (const float*)d_in[25];
    const float* ainW   = (const float*)d_in[26];
    const float* ainb   = (const float*)d_in[27];
    const float* aoutW  = (const float*)d_in[28];
    const float* aoutb  = (const float*)d_in[29];
    const float* fng    = (const float*)d_in[30];
    const float* fnb    = (const float*)d_in[31];
    const float* lgW    = (const float*)d_in[32];
    const float* lgb    = (const float*)d_in[33];
    float* out = (float*)d_out;

    float* w = (float*)d_ws;
    float* imgd   = w; w += (size_t)B_ * CTX_ * IMGD_;   // used as bf16 (dyt out)
    float* imgf   = w; w += (size_t)B_ * CTX_ * DIM_;    // fp32 (pool input)
    float* pooled = w; w += B_ * DIM_;
    float* g1     = w; w += B_ * 128;
    float* gate   = w; w += B_ * DIM_;
    float* x      = w; w += (size_t)B_ * N_ * DIM_;
    float* xn     = w; w += (size_t)B_ * N_ * DIM_;      // used as bf16 (ln out)
    float* xz     = w; w += (size_t)B_ * N_ * 2 * DIN_;
    float* xc     = w; w += (size_t)B_ * N_ * DIN_;
    float* dblb   = w; w += (size_t)B_ * N_ * 64;
    float* dtp    = w; w += (size_t)B_ * N_ * DIN_;
    float* yb     = w; w += (size_t)B_ * N_ * DIN_;      // used as bf16 (scan out)
    float* q      = w; w += (size_t)B_ * N_ * DIM_;
    float* kb     = w; w += (size_t)B_ * CTX_ * DIM_;
    float* vb     = w; w += (size_t)B_ * CTX_ * DIM_;
    float* att    = w; w += (size_t)B_ * HEADS_ * N_ * CTX_;
    float* ob     = w; w += (size_t)B_ * N_ * DIM_;
    // bf16 activation side-buffers
    __bf16* xcb   = (__bf16*)w; w += (size_t)B_ * N_ * DIN_ / 2;      // conv out bf16
    __bf16* imgfb = (__bf16*)w; w += (size_t)B_ * CTX_ * DIM_ / 2;    // gated kv input bf16
    __bf16* obb   = (__bf16*)w; w += (size_t)B_ * N_ * DIM_ / 2;      // attn PV out bf16
    // bf16 weights
    __bf16* inpT  = (__bf16*)w; w += (size_t)DEPTH_ * 2 * DIN_ * DIM_ / 2;
    __bf16* outpT = (__bf16*)w; w += (size_t)DEPTH_ * DIM_ * DIN_ / 2;
    __bf16* ainB  = (__bf16*)w; w += (size_t)DEPTH_ * 3 * DIM_ * DIM_ / 2;
    __bf16* aoutB = (__bf16*)w; w += (size_t)DEPTH_ * DIM_ * DIM_ / 2;
    __bf16* imgWT = (__bf16*)w; w += (size_t)DIM_ * IMGD_ / 2;
    __bf16* xpWT  = (__bf16*)w; w += (size_t)DEPTH_ * 64 * DIN_ / 2;
    // logits bf16 [10000][512] aliased onto att (dead after layer loop)
    __bf16* lgT = (__bf16*)att;
    __bf16* imgdb = (__bf16*)imgd;
    __bf16* xnb   = (__bf16*)xn;
    __bf16* ybb   = (__bf16*)yb;

    // scan scratch aliased onto attention buffers
    float* ubuf   = att;   // B_*N_*DIN_ = 2M fl <= 3.21M
    float* chunkA = ob;    // 1M fl
    float* chunkB = q;     // 1M fl

    const int TOKENS = B_ * N_;       // 2048
    const int IMGT   = B_ * CTX_;     // 1568
    const int SCANT  = B_ * DIN_ * DST_ * NCHUNK_;  // 1048576

    // ---- weight prep (bf16) ----
    tconv_kernel<<<dim3(2 * DIN_ / 32, DIM_ / 32, DEPTH_), 256, 0, stream>>>(inW,  inpT,  DIM_, 2 * DIN_);
    tconv_kernel<<<dim3(DIM_ / 32, DIN_ / 32, DEPTH_),     256, 0, stream>>>(outW, outpT, DIN_, DIM_);
    tconv_kernel<<<dim3(DIM_ / 32, IMGD_ / 32, 1),         256, 0, stream>>>(imgW, imgWT, IMGD_, DIM_);
    tconv_kernel<<<dim3(64 / 32, DIN_ / 32, DEPTH_),       256, 0, stream>>>(xpW,  xpWT,  DIN_, 64);
    cvt_bf16_kernel<<<(DEPTH_ * 3 * DIM_ * DIM_ / 4 + 255) / 256, 256, 0, stream>>>(ainW,  ainB,  DEPTH_ * 3 * DIM_ * DIM_);
    cvt_bf16_kernel<<<(DEPTH_ * DIM_ * DIM_ / 4 + 255) / 256, 256, 0, stream>>>(aoutW, aoutB, DEPTH_ * DIM_ * DIM_);

    // ---- image path ----
    {
        int total = B_ * CTX_ * IMGD_;
        dyt_kernel<<<(total + 255) / 256, 256, 0, stream>>>(images, alphap, dgam, dbeta, imgdb, total);
        mgemm<64, 64>(imgdb, imgWT, imgb, nullptr, imgf, IMGT, DIM_, IMGD_, IMGD_, DIM_, stream);
        pool_kernel<<<(B_ * DIM_ + 255) / 256, 256, 0, stream>>>(imgf, pooled);
        gate1_kernel<<<(B_ * 128 + 255) / 256, 256, 0, stream>>>(pooled, g1W, g1b, g1);
        gate2_kernel<<<(B_ * DIM_ + 255) / 256, 256, 0, stream>>>(g1, g2W, g2b, gate);
        scale_kernel<<<(B_ * CTX_ * DIM_ + 255) / 256, 256, 0, stream>>>(imgf, gate, imgfb);
    }
    // embedding
    embed_kernel<<<(TOKENS * DIM_ + 255) / 256, 256, 0, stream>>>(text, temb, pemb, x);

    for (int l = 0; l < DEPTH_; ++l) {
        const __bf16* inpT_l  = inpT  + (size_t)l * 2 * DIN_ * DIM_;
        const __bf16* outpT_l = outpT + (size_t)l * DIM_ * DIN_;
        const __bf16* ainB_l  = ainB  + (size_t)l * 3 * DIM_ * DIM_;
        const __bf16* aoutB_l = aoutB + (size_t)l * DIM_ * DIM_;
        const __bf16* xpWT_l  = xpWT  + (size_t)l * 64 * DIN_;
        const float* cw    = convW + (size_t)l * DIN_ * 4;
        const float* cb    = convb + (size_t)l * DIN_;
        const float* dtw   = dtW  + (size_t)l * DTR_ * DIN_;
        const float* dtbi  = dtb  + (size_t)l * DIN_;
        const float* alog  = Alog + (size_t)l * DIN_ * DST_;
        const float* dsk   = Dsk  + (size_t)l * DIN_;
        const float* ab    = ainb + (size_t)l * 3 * DIM_;
        const float* aob   = aoutb + (size_t)l * DIM_;

        // mamba block
        ln_kernel<<<TOKENS / 4, 256, 0, stream>>>(x, ln1g + l * DIM_, ln1b + l * DIM_, xnb, TOKENS);
        mgemm<128, 128>(xnb, inpT_l, nullptr, nullptr, xz, TOKENS, 2 * DIN_, DIM_, DIM_, 2 * DIN_, stream);
        conv_silu_kernel<<<(TOKENS * DIN_ + 255) / 256, 256, 0, stream>>>(xz, cw, cb, xc, xcb);
        mgemm<64, 64>(xcb, xpWT_l, nullptr, nullptr, dblb, TOKENS, 64, DIN_, DIN_, 64, stream);
        gemm(false, false, dblb, dtw, dtbi, nullptr, dtp,
             TOKENS, DIN_, DTR_, 64, DIN_, DIN_, 0, 0, 0, 0, 0, 0, 1, 1, 1.f, stream);
        dt_prep_kernel<<<(TOKENS * DIN_ + 255) / 256, 256, 0, stream>>>(dtp, xc, ubuf);
        scan1_kernel<<<SCANT / 256, 256, 0, stream>>>(dtp, ubuf, dblb, alog, chunkA, chunkB);
        scan2_kernel<<<SCANT / 256, 256, 0, stream>>>(dtp, ubuf, dblb, xc, xz, alog, dsk,
                                                      chunkA, chunkB, ybb);
        mgemm<64, 64>(ybb, outpT_l, nullptr, x, x, TOKENS, DIM_, DIN_, DIN_, DIM_, stream);

        // cross-attention block
        ln_kernel<<<TOKENS / 4, 256, 0, stream>>>(x, ln2g + l * DIM_, ln2b + l * DIM_, xnb, TOKENS);
        mgemm<64, 64>(xnb,   ainB_l,                           ab,            nullptr, q,  TOKENS, DIM_, DIM_, DIM_, DIM_, stream);
        mgemm<64, 64>(imgfb, ainB_l + (size_t)DIM_ * DIM_,     ab + DIM_,     nullptr, kb, IMGT,  DIM_, DIM_, DIM_, DIM_, stream);
        mgemm<64, 64>(imgfb, ainB_l + (size_t)2 * DIM_ * DIM_, ab + 2 * DIM_, nullptr, vb, IMGT,  DIM_, DIM_, DIM_, DIM_, stream);
        gemm(true, false, q, kb, nullptr, nullptr, att,
             N_, CTX_, HD_, DIM_, DIM_, CTX_,
             (long long)N_ * DIM_, HD_,
             (long long)CTX_ * DIM_, HD_,
             (long long)HEADS_ * N_ * CTX_, (long long)N_ * CTX_,
             B_ * HEADS_, HEADS_, 0.125f, stream);
        softmax_kernel<<<(B_ * HEADS_ * N_) / 4, 256, 0, stream>>>(att, B_ * HEADS_ * N_);
        gemm(false, false, att, vb, nullptr, nullptr, ob,
             N_, HD_, CTX_, CTX_, DIM_, DIM_,
             (long long)HEADS_ * N_ * CTX_, (long long)N_ * CTX_,
             (long long)CTX_ * DIM_, HD_,
             (long long)N_ * DIM_, HD_,
             B_ * HEADS_, HEADS_, 1.f, stream);
        cvt_bf16_kernel<<<(TOKENS * DIM_ / 4 + 255) / 256, 256, 0, stream>>>(ob, obb, TOKENS * DIM_);
        mgemm<64, 64>(obb, aoutB_l, aob, x, x, TOKENS, DIM_, DIM_, DIM_, DIM_, stream);
    }

    // final LN + logits (lgT aliases att, which is dead now)
    tconv_kernel<<<dim3((10000 + 31) / 32, DIM_ / 32, 1), 256, 0, stream>>>(lgW, lgT, DIM_, 10000);
    ln_kernel<<<TOKENS / 4, 256, 0, stream>>>(x, fng, fnb, xnb, TOKENS);
    mgemm<128, 128>(xnb, lgT, lgb, nullptr, out, TOKENS, 10000, DIM_, DIM_, 10000, stream);
}

// Round 5
// 1498.026 us; speedup vs baseline: 3.3319x; 1.1540x over previous
//
#include <hip/hip_runtime.h>
#include <hip/hip_bf16.h>
#include <stdint.h>

#define B_    8
#define N_    256
#define CTX_  196
#define CTXP_ 224   // ctx padded to multiple of 32 for PV K-loop
#define IMGD_ 1024
#define DIM_  512
#define DEPTH_ 6
#define DIN_  1024
#define DTR_  32
#define DST_  16
#define HEADS_ 8
#define HD_   64
#define NCHUNK_ 8
#define CLEN_   32   // N_/NCHUNK_

typedef __bf16 bf16x8 __attribute__((ext_vector_type(8)));
typedef __bf16 bf16x4 __attribute__((ext_vector_type(4)));
typedef float  f32x4  __attribute__((ext_vector_type(4)));

// 16-lane sum via DPP butterfly (xor1/2/4/8 equivalents); all 16 lanes get total
__device__ __forceinline__ float dpp_red16(float v) {
    int y;
    y = __builtin_amdgcn_update_dpp(0, __float_as_int(v), 0xB1, 0xF, 0xF, true);  // quad_perm [1,0,3,2]
    v += __int_as_float(y);
    y = __builtin_amdgcn_update_dpp(0, __float_as_int(v), 0x4E, 0xF, 0xF, true);  // quad_perm [2,3,0,1]
    v += __int_as_float(y);
    y = __builtin_amdgcn_update_dpp(0, __float_as_int(v), 0x141, 0xF, 0xF, true); // row_half_mirror
    v += __int_as_float(y);
    y = __builtin_amdgcn_update_dpp(0, __float_as_int(v), 0x140, 0xF, 0xF, true); // row_mirror
    v += __int_as_float(y);
    return v;
}

// ---------------- elementwise / small kernels ----------------

__global__ void dyt_kernel(const float* __restrict__ img, const float* __restrict__ alpha_p,
                           const float* __restrict__ gamma, const float* __restrict__ beta,
                           __bf16* __restrict__ out, int total) {
    int i = blockIdx.x * 256 + threadIdx.x;
    if (i >= total) return;
    float a = alpha_p[0];
    int c = i & (IMGD_ - 1);
    out[i] = (__bf16)(gamma[c] * tanhf(a * img[i]) + beta[c]);
}

__global__ void pool_kernel(const float* __restrict__ imgf, float* __restrict__ pooled) {
    int i = blockIdx.x * 256 + threadIdx.x;
    if (i >= B_ * DIM_) return;
    int b = i >> 9, c = i & (DIM_ - 1);
    const float* p = imgf + (size_t)b * CTX_ * DIM_ + c;
    float s = 0.f;
    for (int t = 0; t < CTX_; ++t) s += p[t * DIM_];
    pooled[i] = s * (1.f / CTX_);
}

__global__ void gate1_kernel(const float* __restrict__ pooled, const float* __restrict__ W,
                             const float* __restrict__ bias, float* __restrict__ g1) {
    int i = blockIdx.x * 256 + threadIdx.x;
    if (i >= B_ * 128) return;
    int b = i >> 7, j = i & 127;
    const float* p = pooled + b * DIM_;
    float s = bias[j];
    for (int c = 0; c < DIM_; ++c) s += p[c] * W[c * 128 + j];
    g1[i] = 0.5f * s * (1.f + erff(s * 0.70710678118654752f));
}

__global__ void gate2_kernel(const float* __restrict__ g1, const float* __restrict__ W,
                             const float* __restrict__ bias, float* __restrict__ gate) {
    int i = blockIdx.x * 256 + threadIdx.x;
    if (i >= B_ * DIM_) return;
    int b = i >> 9, c = i & (DIM_ - 1);
    const float* p = g1 + b * 128;
    float s = bias[c];
    for (int j = 0; j < 128; ++j) s += p[j] * W[j * DIM_ + c];
    gate[i] = 1.f / (1.f + __expf(-s));
}

__global__ void scale_kernel(const float* __restrict__ imgf, const float* __restrict__ gate,
                             __bf16* __restrict__ imgfb) {
    int i = blockIdx.x * 256 + threadIdx.x;
    if (i >= B_ * CTX_ * DIM_) return;
    int c = i & (DIM_ - 1);
    int b = i / (CTX_ * DIM_);
    imgfb[i] = (__bf16)(imgf[i] * gate[b * DIM_ + c]);
}

__global__ void embed_kernel(const int* __restrict__ text, const float* __restrict__ temb,
                             const float* __restrict__ pemb, float* __restrict__ x) {
    int i = blockIdx.x * 256 + threadIdx.x;
    if (i >= B_ * N_ * DIM_) return;
    int c = i & (DIM_ - 1);
    int row = i >> 9;
    int n = row & (N_ - 1);
    int tok = text[row];
    x[i] = temb[(size_t)tok * DIM_ + c] + pemb[(size_t)n * DIM_ + c];
}

// wave-per-row layernorm, row = 512 floats, bf16 output
__global__ void ln_kernel(const float* __restrict__ x, const float* __restrict__ g,
                          const float* __restrict__ b, __bf16* __restrict__ o, int rows) {
    int row = blockIdx.x * 4 + (threadIdx.x >> 6);
    if (row >= rows) return;
    int lane = threadIdx.x & 63;
    const float* xr = x + (size_t)row * DIM_ + lane * 8;
    float4 v0 = ((const float4*)xr)[0];
    float4 v1 = ((const float4*)xr)[1];
    float r[8] = {v0.x, v0.y, v0.z, v0.w, v1.x, v1.y, v1.z, v1.w};
    float sum = 0.f, sq = 0.f;
    #pragma unroll
    for (int j = 0; j < 8; ++j) { sum += r[j]; sq += r[j] * r[j]; }
    #pragma unroll
    for (int m = 1; m < 64; m <<= 1) { sum += __shfl_xor(sum, m); sq += __shfl_xor(sq, m); }
    float mean = sum * (1.f / DIM_);
    float var  = sq * (1.f / DIM_) - mean * mean;
    float inv  = rsqrtf(fmaxf(var, 0.f) + 1e-5f);
    const float* gp = g + lane * 8;
    const float* bp = b + lane * 8;
    __bf16* op = o + (size_t)row * DIM_ + lane * 8;
    bf16x8 ov;
    #pragma unroll
    for (int j = 0; j < 8; ++j) ov[j] = (__bf16)((r[j] - mean) * inv * gp[j] + bp[j]);
    *(bf16x8*)op = ov;
}

// causal depthwise conv (4 taps) + SiLU; fp32 (scan) + bf16 (xproj GEMM)
__global__ void conv_silu_kernel(const float* __restrict__ xz, const float* __restrict__ cw,
                                 const float* __restrict__ cb, float* __restrict__ xc,
                                 __bf16* __restrict__ xcb) {
    int i = blockIdx.x * 256 + threadIdx.x;
    if (i >= B_ * N_ * DIN_) return;
    int d = i & (DIN_ - 1);
    int row = i >> 10;
    int n = row & (N_ - 1);
    int rowb = row - n;
    float acc = cb[d];
    #pragma unroll
    for (int k = 0; k < 4; ++k) {
        int m = n - 3 + k;
        if (m >= 0) acc += xz[(size_t)(rowb + m) * (2 * DIN_) + d] * cw[d * 4 + k];
    }
    float s = acc / (1.f + __expf(-acc));
    xc[i] = s;
    xcb[i] = (__bf16)s;
}

// dt = softplus(dtp) (overwrite); u = dt * xc
__global__ void dt_prep_kernel(float* __restrict__ dtp, const float* __restrict__ xc,
                               float* __restrict__ u) {
    int i = blockIdx.x * 256 + threadIdx.x;
    if (i >= B_ * N_ * DIN_) return;
    float v = dtp[i];
    float e = __expf(-fabsf(v));
    float dt = fmaxf(v, 0.f) + __logf(1.f + e);
    dtp[i] = dt;
    u[i] = dt * xc[i];
}

__global__ void cvt_bf16_kernel(const float* __restrict__ src, __bf16* __restrict__ dst, int count) {
    int i = (blockIdx.x * 256 + threadIdx.x) * 4;
    if (i >= count) return;
    float4 v = *(const float4*)(src + i);
    bf16x4 p = {(__bf16)v.x, (__bf16)v.y, (__bf16)v.z, (__bf16)v.w};
    *(bf16x4*)(dst + i) = p;
}

// ---------------- chunked selective scan ----------------
__global__ __launch_bounds__(256) void scan1_kernel(
    const float* __restrict__ dtp, const float* __restrict__ u,
    const float* __restrict__ dbl, const float* __restrict__ A_log,
    float* __restrict__ chunkA, float* __restrict__ chunkB) {
    int t = blockIdx.x * 256 + threadIdx.x;
    int s = t & 15;
    int d = (t >> 4) & (DIN_ - 1);
    int c = (t >> 14) & (NCHUNK_ - 1);
    int b = t >> 17;
    float As = -__expf(A_log[(d << 4) | s]);
    float a = 1.f, hb = 0.f;
    int row0 = b * N_ + c * CLEN_;
    #pragma unroll 4
    for (int n = 0; n < CLEN_; ++n) {
        int row = row0 + n;
        float dt = dtp[(size_t)row * DIN_ + d];
        float uu = u[(size_t)row * DIN_ + d];
        float Bv = dbl[row * 64 + 32 + s];
        float dA = __expf(dt * As);
        hb = hb * dA + uu * Bv;
        a *= dA;
    }
    chunkA[t] = a;
    chunkB[t] = hb;
}

// scan2: compose prefix, replay chunk, DPP-reduce over s, store raw p-sum
__global__ __launch_bounds__(256) void scan2_kernel(
    const float* __restrict__ dtp, const float* __restrict__ u,
    const float* __restrict__ dbl, const float* __restrict__ A_log,
    const float* __restrict__ chunkA, const float* __restrict__ chunkB,
    float* __restrict__ psum) {
    int t = blockIdx.x * 256 + threadIdx.x;
    int s = t & 15;
    int d = (t >> 4) & (DIN_ - 1);
    int c = (t >> 14) & (NCHUNK_ - 1);
    int b = t >> 17;
    float h = 0.f;
    int base = (b << 17) | (d << 4) | s;
    for (int j = 0; j < c; ++j) {
        int idx = base | (j << 14);
        h = h * chunkA[idx] + chunkB[idx];
    }
    float As = -__expf(A_log[(d << 4) | s]);
    int row0 = b * N_ + c * CLEN_;
    #pragma unroll 4
    for (int n = 0; n < CLEN_; ++n) {
        int row = row0 + n;
        float dt = dtp[(size_t)row * DIN_ + d];
        float uu = u[(size_t)row * DIN_ + d];
        float Bv = dbl[row * 64 + 32 + s];
        float Cv = dbl[row * 64 + 48 + s];
        float dA = __expf(dt * As);
        h = h * dA + uu * Bv;
        float p = dpp_red16(h * Cv);
        if (s == 0) psum[(size_t)row * DIN_ + d] = p;
    }
}

// y = (psum + xc*D) * silu(z), bf16 out
__global__ void yfin_kernel(const float* __restrict__ psum, const float* __restrict__ xc,
                            const float* __restrict__ xz, const float* __restrict__ Dsk,
                            __bf16* __restrict__ ybb) {
    int i = blockIdx.x * 256 + threadIdx.x;
    if (i >= B_ * N_ * DIN_) return;
    int d = i & (DIN_ - 1);
    int row = i >> 10;
    float z = xz[(size_t)row * (2 * DIN_) + DIN_ + d];
    float y = (psum[i] + xc[i] * Dsk[d]) * (z / (1.f + __expf(-z)));
    ybb[i] = (__bf16)y;
}

// wave-per-row softmax over CTX_=196; writes bf16 padded to 224 (zeros in pad)
__global__ void softmax_kernel(const float* __restrict__ att, __bf16* __restrict__ attb, int rows) {
    int row = blockIdx.x * 4 + (threadIdx.x >> 6);
    if (row >= rows) return;
    int lane = threadIdx.x & 63;
    const float* ar = att + (size_t)row * CTX_;
    float v[4];
    float mx = -1e30f;
    #pragma unroll
    for (int j = 0; j < 4; ++j) {
        int idx = lane + j * 64;
        v[j] = idx < CTX_ ? ar[idx] : -1e30f;
        mx = fmaxf(mx, v[j]);
    }
    #pragma unroll
    for (int m = 1; m < 64; m <<= 1) mx = fmaxf(mx, __shfl_xor(mx, m));
    float sm = 0.f;
    #pragma unroll
    for (int j = 0; j < 4; ++j) {
        int idx = lane + j * 64;
        v[j] = idx < CTX_ ? __expf(v[j] - mx) : 0.f;
        sm += v[j];
    }
    #pragma unroll
    for (int m = 1; m < 64; m <<= 1) sm += __shfl_xor(sm, m);
    float inv = 1.f / sm;
    __bf16* ob = attb + (size_t)row * CTXP_;
    #pragma unroll
    for (int j = 0; j < 4; ++j) {
        int idx = lane + j * 64;
        if (idx < CTXP_) ob[idx] = (idx < CTX_) ? (__bf16)(v[j] * inv) : (__bf16)0.f;
    }
}

// ---------------- weight prep ----------------

__global__ void tconv_kernel(const float* __restrict__ src, __bf16* __restrict__ dst,
                             int K, int N) {
    __shared__ float tile[32][33];
    int n0 = blockIdx.x * 32, k0 = blockIdx.y * 32;
    src += (size_t)blockIdx.z * K * N;
    dst += (size_t)blockIdx.z * K * N;
    int tx = threadIdx.x & 31, ty = threadIdx.x >> 5;
    #pragma unroll
    for (int i = 0; i < 32; i += 8) {
        int k = k0 + ty + i, n = n0 + tx;
        tile[ty + i][tx] = (k < K && n < N) ? src[(size_t)k * N + n] : 0.f;
    }
    __syncthreads();
    #pragma unroll
    for (int i = 0; i < 32; i += 8) {
        int n = n0 + ty + i, k = k0 + tx;
        if (n < N && k < K) dst[(size_t)n * K + k] = (__bf16)tile[tx][ty + i];
    }
}

// ---------------- bf16 MFMA GEMM (double-buffered) ----------------
#define LDP_ 40

template <int BM, int BN, bool BOUT>
__global__ __launch_bounds__(256) void mgemm_k(
    const __bf16* __restrict__ A, const __bf16* __restrict__ Bw,
    const float* __restrict__ bias, const float* __restrict__ res,
    void* __restrict__ Cp, int M, int N, int K, int lda, int ldc) {
    constexpr int RA = BM / 64, RB = BN / 64;
    constexpr int FM = BM / 32, FN = BN / 32;
    __shared__ __align__(16) __bf16 As[2][BM * LDP_];
    __shared__ __align__(16) __bf16 Bs[2][BN * LDP_];
    int tid = threadIdx.x;
    int ntx = gridDim.x;
    int nwg = ntx * gridDim.y;
    int bid = blockIdx.y * ntx + blockIdx.x;
    if ((nwg & 7) == 0) bid = (bid & 7) * (nwg >> 3) + (bid >> 3);
    int row0 = (bid / ntx) * BM, col0 = (bid % ntx) * BN;
    int wave = tid >> 6, lane = tid & 63;
    int wm = (wave >> 1) * (BM / 2), wn = (wave & 1) * (BN / 2);
    int fr = lane & 15, fk = lane >> 4;
    f32x4 acc[FM][FN] = {};
    uint4 aR[RA], bR[RB];

    auto loadT = [&](int k0) {
        #pragma unroll
        for (int i = 0; i < RA; ++i) {
            int idx = i * 256 + tid;
            int r = idx >> 2, c = (idx & 3) * 8;
            int gm = row0 + r;
            uint4 v = {0u, 0u, 0u, 0u};
            if (gm < M) v = *(const uint4*)(A + (size_t)gm * lda + k0 + c);
            aR[i] = v;
        }
        #pragma unroll
        for (int i = 0; i < RB; ++i) {
            int idx = i * 256 + tid;
            int r = idx >> 2, c = (idx & 3) * 8;
            int gn = col0 + r;
            uint4 v = {0u, 0u, 0u, 0u};
            if (gn < N) v = *(const uint4*)(Bw + (size_t)gn * K + k0 + c);
            bR[i] = v;
        }
    };
    auto writeT = [&](int buf) {
        #pragma unroll
        for (int i = 0; i < RA; ++i) {
            int idx = i * 256 + tid;
            int r = idx >> 2, c = (idx & 3) * 8;
            *(uint4*)&As[buf][r * LDP_ + c] = aR[i];
        }
        #pragma unroll
        for (int i = 0; i < RB; ++i) {
            int idx = i * 256 + tid;
            int r = idx >> 2, c = (idx & 3) * 8;
            *(uint4*)&Bs[buf][r * LDP_ + c] = bR[i];
        }
    };

    loadT(0);
    writeT(0);
    __syncthreads();
    int NK = K >> 5;
    for (int kt = 0; kt < NK; ++kt) {
        int cur = kt & 1;
        if (kt + 1 < NK) loadT((kt + 1) << 5);
        bf16x8 af[FM], bg[FN];
        #pragma unroll
        for (int mf = 0; mf < FM; ++mf)
            af[mf] = *(const bf16x8*)&As[cur][(wm + mf * 16 + fr) * LDP_ + fk * 8];
        #pragma unroll
        for (int nf = 0; nf < FN; ++nf)
            bg[nf] = *(const bf16x8*)&Bs[cur][(wn + nf * 16 + fr) * LDP_ + fk * 8];
        #pragma unroll
        for (int mf = 0; mf < FM; ++mf)
            #pragma unroll
            for (int nf = 0; nf < FN; ++nf)
                acc[mf][nf] = __builtin_amdgcn_mfma_f32_16x16x32_bf16(af[mf], bg[nf], acc[mf][nf], 0, 0, 0);
        if (kt + 1 < NK) {
            writeT(cur ^ 1);
            __syncthreads();
        }
    }
    #pragma unroll
    for (int mf = 0; mf < FM; ++mf) {
        #pragma unroll
        for (int nf = 0; nf < FN; ++nf) {
            int gn = col0 + wn + nf * 16 + fr;
            if (gn >= N) continue;
            float bb = bias ? bias[gn] : 0.f;
            #pragma unroll
            for (int e = 0; e < 4; ++e) {
                int gm = row0 + wm + mf * 16 + fk * 4 + e;
                if (gm >= M) continue;
                size_t idx = (size_t)gm * ldc + gn;
                float v = acc[mf][nf][e] + bb;
                if constexpr (BOUT) {
                    ((__bf16*)Cp)[idx] = (__bf16)v;
                } else {
                    if (res) v += res[idx];
                    ((float*)Cp)[idx] = v;
                }
            }
        }
    }
}

template <int BM, int BN, bool BOUT = false>
static inline void mgemm(const __bf16* A, const __bf16* Bw, const float* bias,
                         const float* res, void* C, int M, int N, int K,
                         int lda, int ldc, hipStream_t s) {
    dim3 g((N + BN - 1) / BN, (M + BM - 1) / BM);
    mgemm_k<BM, BN, BOUT><<<g, 256, 0, s>>>(A, Bw, bias, res, C, M, N, K, lda, ldc);
}

// ---------------- batched attention MFMA kernels ----------------
// scores: att[z][256][196] = 0.125 * Q[z] . K[z]^T ; z = b*8+h
__global__ __launch_bounds__(256) void scores_k(
    const __bf16* __restrict__ qb, const __bf16* __restrict__ kbb,
    float* __restrict__ att) {
    int z = blockIdx.z, b = z >> 3, h = z & 7;
    const __bf16* Ab = qb + (size_t)b * N_ * DIM_ + h * HD_;
    const __bf16* Bb = kbb + (size_t)b * CTX_ * DIM_ + h * HD_;
    float* Cb = att + (size_t)z * N_ * CTX_;
    int row0 = blockIdx.y * 64, col0 = blockIdx.x * 64;
    __shared__ __align__(16) __bf16 As[64 * LDP_];
    __shared__ __align__(16) __bf16 Bs[64 * LDP_];
    int tid = threadIdx.x, wave = tid >> 6, lane = tid & 63;
    int wm = (wave >> 1) * 32, wn = (wave & 1) * 32;
    int fr = lane & 15, fk = lane >> 4;
    f32x4 acc[2][2] = {};
    int r = tid >> 2, c = (tid & 3) * 8;
    for (int k0 = 0; k0 < HD_; k0 += 32) {
        {
            uint4 v = {0u, 0u, 0u, 0u};
            if (row0 + r < N_) v = *(const uint4*)(Ab + (size_t)(row0 + r) * DIM_ + k0 + c);
            *(uint4*)&As[r * LDP_ + c] = v;
        }
        {
            uint4 v = {0u, 0u, 0u, 0u};
            if (col0 + r < CTX_) v = *(const uint4*)(Bb + (size_t)(col0 + r) * DIM_ + k0 + c);
            *(uint4*)&Bs[r * LDP_ + c] = v;
        }
        __syncthreads();
        bf16x8 af[2], bg[2];
        #pragma unroll
        for (int mf = 0; mf < 2; ++mf) af[mf] = *(const bf16x8*)&As[(wm + mf * 16 + fr) * LDP_ + fk * 8];
        #pragma unroll
        for (int nf = 0; nf < 2; ++nf) bg[nf] = *(const bf16x8*)&Bs[(wn + nf * 16 + fr) * LDP_ + fk * 8];
        #pragma unroll
        for (int mf = 0; mf < 2; ++mf)
            #pragma unroll
            for (int nf = 0; nf < 2; ++nf)
                acc[mf][nf] = __builtin_amdgcn_mfma_f32_16x16x32_bf16(af[mf], bg[nf], acc[mf][nf], 0, 0, 0);
        __syncthreads();
    }
    #pragma unroll
    for (int mf = 0; mf < 2; ++mf)
        #pragma unroll
        for (int nf = 0; nf < 2; ++nf) {
            int gn = col0 + wn + nf * 16 + fr;
            if (gn >= CTX_) continue;
            #pragma unroll
            for (int e = 0; e < 4; ++e) {
                int gm = row0 + wm + mf * 16 + fk * 4 + e;
                Cb[(size_t)gm * CTX_ + gn] = acc[mf][nf][e] * 0.125f;
            }
        }
}

// PV: obb[b][n][h*64+j] = attb[z][n][:] . V[z][:][j]   (K=224, zero-padded)
__global__ __launch_bounds__(256) void pv_k(
    const __bf16* __restrict__ attb, const __bf16* __restrict__ vbb,
    __bf16* __restrict__ obb) {
    int z = blockIdx.z, b = z >> 3, h = z & 7;
    const __bf16* Ab = attb + (size_t)z * N_ * CTXP_;
    const __bf16* Vb = vbb + (size_t)b * CTX_ * DIM_ + h * HD_;
    __bf16* Cb = obb + (size_t)b * N_ * DIM_ + h * HD_;
    int row0 = blockIdx.y * 64;
    __shared__ __align__(16) __bf16 As[64 * LDP_];
    __shared__ __align__(16) __bf16 Bs[64 * LDP_];
    int tid = threadIdx.x, wave = tid >> 6, lane = tid & 63;
    int wm = (wave >> 1) * 32, wn = (wave & 1) * 32;
    int fr = lane & 15, fk = lane >> 4;
    f32x4 acc[2][2] = {};
    int r = tid >> 2, c = (tid & 3) * 8;
    int kr = tid >> 3, c2 = (tid & 7) * 8;
    for (int k0 = 0; k0 < CTXP_; k0 += 32) {
        {   // A tile: 64 rows x 32 k from attb (lda=224)
            uint4 v = *(const uint4*)(Ab + (size_t)(row0 + r) * CTXP_ + k0 + c);
            *(uint4*)&As[r * LDP_ + c] = v;
        }
        {   // B tile transposed: Bs[n][k] = V[k0+kr][n]
            bf16x8 v = {};
            if (k0 + kr < CTX_) v = *(const bf16x8*)(Vb + (size_t)(k0 + kr) * DIM_ + c2);
            #pragma unroll
            for (int j = 0; j < 8; ++j) Bs[(c2 + j) * LDP_ + kr] = v[j];
        }
        __syncthreads();
        bf16x8 af[2], bg[2];
        #pragma unroll
        for (int mf = 0; mf < 2; ++mf) af[mf] = *(const bf16x8*)&As[(wm + mf * 16 + fr) * LDP_ + fk * 8];
        #pragma unroll
        for (int nf = 0; nf < 2; ++nf) bg[nf] = *(const bf16x8*)&Bs[(wn + nf * 16 + fr) * LDP_ + fk * 8];
        #pragma unroll
        for (int mf = 0; mf < 2; ++mf)
            #pragma unroll
            for (int nf = 0; nf < 2; ++nf)
                acc[mf][nf] = __builtin_amdgcn_mfma_f32_16x16x32_bf16(af[mf], bg[nf], acc[mf][nf], 0, 0, 0);
        __syncthreads();
    }
    #pragma unroll
    for (int mf = 0; mf < 2; ++mf)
        #pragma unroll
        for (int nf = 0; nf < 2; ++nf) {
            int gn = wn + nf * 16 + fr;
            #pragma unroll
            for (int e = 0; e < 4; ++e) {
                int gm = row0 + wm + mf * 16 + fk * 4 + e;
                Cb[(size_t)gm * DIM_ + gn] = (__bf16)acc[mf][nf][e];
            }
        }
}

// ---------------- generic fp32 GEMM (dt_proj only) ----------------
#define TM_ 64
#define TN_ 64
#define TK_ 16

__global__ __launch_bounds__(256) void gemm_k(
    const float* __restrict__ A, const float* __restrict__ B,
    const float* __restrict__ bias, float* C,
    int M, int N, int K, int lda, int ldb, int ldc) {
    __shared__ float As[TK_][TM_ + 4];
    __shared__ float Bs[TK_][TN_ + 4];
    int tid = threadIdx.x;
    int row0 = blockIdx.y * TM_;
    int col0 = blockIdx.x * TN_;
    int tm = (tid / 16) * 4, tn = (tid % 16) * 4;
    float acc[4][4] = {};
    int nk = (K + TK_ - 1) / TK_;
    for (int kt = 0; kt < nk; ++kt) {
        int k0 = kt * TK_;
        {
            int m = tid >> 2, kq = (tid & 3) * 4;
            int gm = row0 + m;
            float4 v = {0, 0, 0, 0};
            if (gm < M && k0 + kq + 3 < K) v = *(const float4*)(A + (size_t)gm * lda + k0 + kq);
            else if (gm < M) {
                float tmp[4] = {0, 0, 0, 0};
                for (int j = 0; j < 4; ++j) if (k0 + kq + j < K) tmp[j] = A[(size_t)gm * lda + k0 + kq + j];
                v = {tmp[0], tmp[1], tmp[2], tmp[3]};
            }
            As[kq + 0][m] = v.x; As[kq + 1][m] = v.y; As[kq + 2][m] = v.z; As[kq + 3][m] = v.w;
        }
        {
            int kk = tid >> 4, nq = (tid & 15) * 4;
            int gk = k0 + kk;
            float4 v = {0, 0, 0, 0};
            if (gk < K && col0 + nq + 3 < N) v = *(const float4*)(B + (size_t)gk * ldb + col0 + nq);
            Bs[kk][nq + 0] = v.x; Bs[kk][nq + 1] = v.y; Bs[kk][nq + 2] = v.z; Bs[kk][nq + 3] = v.w;
        }
        __syncthreads();
        #pragma unroll
        for (int kk = 0; kk < TK_; ++kk) {
            float4 a4 = *(const float4*)&As[kk][tm];
            float4 b4 = *(const float4*)&Bs[kk][tn];
            float a0[4] = {a4.x, a4.y, a4.z, a4.w};
            float b0[4] = {b4.x, b4.y, b4.z, b4.w};
            #pragma unroll
            for (int i = 0; i < 4; ++i)
                #pragma unroll
                for (int j = 0; j < 4; ++j)
                    acc[i][j] += a0[i] * b0[j];
        }
        __syncthreads();
    }
    for (int i = 0; i < 4; ++i) {
        int gm = row0 + tm + i;
        if (gm >= M) continue;
        for (int j = 0; j < 4; ++j) {
            int gn = col0 + tn + j;
            if (gn >= N) continue;
            float v = acc[i][j];
            if (bias) v += bias[gn];
            C[(size_t)gm * ldc + gn] = v;
        }
    }
}

// ---------------- host side ----------------

extern "C" void kernel_launch(void* const* d_in, const int* in_sizes, int n_in,
                              void* d_out, int out_size, void* d_ws, size_t ws_size,
                              hipStream_t stream) {
    const int*   text   = (const int*)d_in[0];
    const float* images = (const float*)d_in[1];
    const float* alphap = (const float*)d_in[2];
    const float* dgam   = (const float*)d_in[3];
    const float* dbeta  = (const float*)d_in[4];
    const float* imgW   = (const float*)d_in[5];
    const float* imgb   = (const float*)d_in[6];
    const float* g1W    = (const float*)d_in[7];
    const float* g1b    = (const float*)d_in[8];
    const float* g2W    = (const float*)d_in[9];
    const float* g2b    = (const float*)d_in[10];
    const float* temb   = (const float*)d_in[11];
    const float* pemb   = (const float*)d_in[12];
    const float* ln1g   = (const float*)d_in[13];
    const float* ln1b   = (const float*)d_in[14];
    const float* inW    = (const float*)d_in[15];
    const float* convW  = (const float*)d_in[16];
    const float* convb  = (const float*)d_in[17];
    const float* xpW    = (const float*)d_in[18];
    const float* dtW    = (const float*)d_in[19];
    const float* dtb    = (const float*)d_in[20];
    const float* Alog   = (const float*)d_in[21];
    const float* Dsk    = (const float*)d_in[22];
    const float* outW   = (const float*)d_in[23];
    const float* ln2g   = (const float*)d_in[24];
    const float* ln2b   = (const float*)d_in[25];
    const float* ainW   = (const float*)d_in[26];
    const float* ainb   = (const float*)d_in[27];
    const float* aoutW  = (const float*)d_in[28];
    const float* aoutb  = (const float*)d_in[29];
    const float* fng    = (const float*)d_in[30];
    const float* fnb    = (const float*)d_in[31];
    const float* lgW    = (const float*)d_in[32];
    const float* lgb    = (const float*)d_in[33];
    float* out = (float*)d_out;

    float* w = (float*)d_ws;
    float* imgd   = w; w += (size_t)B_ * CTX_ * IMGD_;   // bf16 dyt out (aliased)
    float* imgf   = w; w += (size_t)B_ * CTX_ * DIM_;
    float* pooled = w; w += B_ * DIM_;
    float* g1     = w; w += B_ * 128;
    float* gate   = w; w += B_ * DIM_;
    float* x      = w; w += (size_t)B_ * N_ * DIM_;
    float* xn     = w; w += (size_t)B_ * N_ * DIM_;      // bf16 ln out (aliased)
    float* xz     = w; w += (size_t)B_ * N_ * 2 * DIN_;
    float* xc     = w; w += (size_t)B_ * N_ * DIN_;
    float* dblb   = w; w += (size_t)B_ * N_ * 64;
    float* dtp    = w; w += (size_t)B_ * N_ * DIN_;
    float* psum   = w; w += (size_t)B_ * N_ * DIN_;
    float* q      = w; w += (size_t)B_ * N_ * DIM_;      // scan scratch chunkB
    float* ob     = w; w += (size_t)B_ * N_ * DIM_;      // scan scratch chunkA
    float* att    = w; w += (size_t)B_ * HEADS_ * N_ * CTX_;
    // bf16 buffers
    __bf16* xcb   = (__bf16*)w; w += (size_t)B_ * N_ * DIN_ / 2;
    __bf16* imgfb = (__bf16*)w; w += (size_t)B_ * CTX_ * DIM_ / 2;
    __bf16* ybb   = (__bf16*)w; w += (size_t)B_ * N_ * DIN_ / 2;
    __bf16* qb    = (__bf16*)w; w += (size_t)B_ * N_ * DIM_ / 2;
    __bf16* kbb   = (__bf16*)w; w += (size_t)B_ * CTX_ * DIM_ / 2;
    __bf16* vbb   = (__bf16*)w; w += (size_t)B_ * CTX_ * DIM_ / 2;
    __bf16* obb   = (__bf16*)w; w += (size_t)B_ * N_ * DIM_ / 2;
    __bf16* attb  = (__bf16*)w; w += (size_t)B_ * HEADS_ * N_ * CTXP_ / 2;
    // bf16 weights
    __bf16* inpT  = (__bf16*)w; w += (size_t)DEPTH_ * 2 * DIN_ * DIM_ / 2;
    __bf16* outpT = (__bf16*)w; w += (size_t)DEPTH_ * DIM_ * DIN_ / 2;
    __bf16* ainB  = (__bf16*)w; w += (size_t)DEPTH_ * 3 * DIM_ * DIM_ / 2;
    __bf16* aoutB = (__bf16*)w; w += (size_t)DEPTH_ * DIM_ * DIM_ / 2;
    __bf16* imgWT = (__bf16*)w; w += (size_t)DIM_ * IMGD_ / 2;
    __bf16* xpWT  = (__bf16*)w; w += (size_t)DEPTH_ * 64 * DIN_ / 2;
    __bf16* lgT   = (__bf16*)att;   // logits weight aliases att (dead after layers)
    __bf16* imgdb = (__bf16*)imgd;
    __bf16* xnb   = (__bf16*)xn;

    // scan scratch aliases
    float* ubuf   = att;   // u: 2M fl <= 3.21M; dead before scores written
    float* chunkA = ob;
    float* chunkB = q;

    const int TOKENS = B_ * N_;
    const int IMGT   = B_ * CTX_;
    const int SCANT  = B_ * DIN_ * DST_ * NCHUNK_;

    // ---- weight prep ----
    tconv_kernel<<<dim3(2 * DIN_ / 32, DIM_ / 32, DEPTH_), 256, 0, stream>>>(inW,  inpT,  DIM_, 2 * DIN_);
    tconv_kernel<<<dim3(DIM_ / 32, DIN_ / 32, DEPTH_),     256, 0, stream>>>(outW, outpT, DIN_, DIM_);
    tconv_kernel<<<dim3(DIM_ / 32, IMGD_ / 32, 1),         256, 0, stream>>>(imgW, imgWT, IMGD_, DIM_);
    tconv_kernel<<<dim3(64 / 32, DIN_ / 32, DEPTH_),       256, 0, stream>>>(xpW,  xpWT,  DIN_, 64);
    cvt_bf16_kernel<<<(DEPTH_ * 3 * DIM_ * DIM_ / 4 + 255) / 256, 256, 0, stream>>>(ainW,  ainB,  DEPTH_ * 3 * DIM_ * DIM_);
    cvt_bf16_kernel<<<(DEPTH_ * DIM_ * DIM_ / 4 + 255) / 256, 256, 0, stream>>>(aoutW, aoutB, DEPTH_ * DIM_ * DIM_);

    // ---- image path ----
    {
        int total = B_ * CTX_ * IMGD_;
        dyt_kernel<<<(total + 255) / 256, 256, 0, stream>>>(images, alphap, dgam, dbeta, imgdb, total);
        mgemm<64, 64>(imgdb, imgWT, imgb, nullptr, imgf, IMGT, DIM_, IMGD_, IMGD_, DIM_, stream);
        pool_kernel<<<(B_ * DIM_ + 255) / 256, 256, 0, stream>>>(imgf, pooled);
        gate1_kernel<<<(B_ * 128 + 255) / 256, 256, 0, stream>>>(pooled, g1W, g1b, g1);
        gate2_kernel<<<(B_ * DIM_ + 255) / 256, 256, 0, stream>>>(g1, g2W, g2b, gate);
        scale_kernel<<<(B_ * CTX_ * DIM_ + 255) / 256, 256, 0, stream>>>(imgf, gate, imgfb);
    }
    embed_kernel<<<(TOKENS * DIM_ + 255) / 256, 256, 0, stream>>>(text, temb, pemb, x);

    for (int l = 0; l < DEPTH_; ++l) {
        const __bf16* inpT_l  = inpT  + (size_t)l * 2 * DIN_ * DIM_;
        const __bf16* outpT_l = outpT + (size_t)l * DIM_ * DIN_;
        const __bf16* ainB_l  = ainB  + (size_t)l * 3 * DIM_ * DIM_;
        const __bf16* aoutB_l = aoutB + (size_t)l * DIM_ * DIM_;
        const __bf16* xpWT_l  = xpWT  + (size_t)l * 64 * DIN_;
        const float* cw    = convW + (size_t)l * DIN_ * 4;
        const float* cb    = convb + (size_t)l * DIN_;
        const float* dtw   = dtW  + (size_t)l * DTR_ * DIN_;
        const float* dtbi  = dtb  + (size_t)l * DIN_;
        const float* alog  = Alog + (size_t)l * DIN_ * DST_;
        const float* dsk   = Dsk  + (size_t)l * DIN_;
        const float* ab    = ainb + (size_t)l * 3 * DIM_;
        const float* aob   = aoutb + (size_t)l * DIM_;

        // mamba block
        ln_kernel<<<TOKENS / 4, 256, 0, stream>>>(x, ln1g + l * DIM_, ln1b + l * DIM_, xnb, TOKENS);
        mgemm<128, 128>(xnb, inpT_l, nullptr, nullptr, xz, TOKENS, 2 * DIN_, DIM_, DIM_, 2 * DIN_, stream);
        conv_silu_kernel<<<(TOKENS * DIN_ + 255) / 256, 256, 0, stream>>>(xz, cw, cb, xc, xcb);
        mgemm<64, 64>(xcb, xpWT_l, nullptr, nullptr, dblb, TOKENS, 64, DIN_, DIN_, 64, stream);
        gemm_k<<<dim3((DIN_ + TN_ - 1) / TN_, (TOKENS + TM_ - 1) / TM_), 256, 0, stream>>>(
            dblb, dtw, dtbi, dtp, TOKENS, DIN_, DTR_, 64, DIN_, DIN_);
        dt_prep_kernel<<<(TOKENS * DIN_ + 255) / 256, 256, 0, stream>>>(dtp, xc, ubuf);
        scan1_kernel<<<SCANT / 256, 256, 0, stream>>>(dtp, ubuf, dblb, alog, chunkA, chunkB);
        scan2_kernel<<<SCANT / 256, 256, 0, stream>>>(dtp, ubuf, dblb, alog, chunkA, chunkB, psum);
        yfin_kernel<<<(TOKENS * DIN_ + 255) / 256, 256, 0, stream>>>(psum, xc, xz, dsk, ybb);
        mgemm<64, 64>(ybb, outpT_l, nullptr, x, x, TOKENS, DIM_, DIN_, DIN_, DIM_, stream);

        // cross-attention block
        ln_kernel<<<TOKENS / 4, 256, 0, stream>>>(x, ln2g + l * DIM_, ln2b + l * DIM_, xnb, TOKENS);
        mgemm<64, 64, true>(xnb,   ainB_l,                           ab,            nullptr, qb,  TOKENS, DIM_, DIM_, DIM_, DIM_, stream);
        mgemm<64, 64, true>(imgfb, ainB_l + (size_t)DIM_ * DIM_,     ab + DIM_,     nullptr, kbb, IMGT,  DIM_, DIM_, DIM_, DIM_, stream);
        mgemm<64, 64, true>(imgfb, ainB_l + (size_t)2 * DIM_ * DIM_, ab + 2 * DIM_, nullptr, vbb, IMGT,  DIM_, DIM_, DIM_, DIM_, stream);
        scores_k<<<dim3(4, 4, B_ * HEADS_), 256, 0, stream>>>(qb, kbb, att);
        softmax_kernel<<<(B_ * HEADS_ * N_) / 4, 256, 0, stream>>>(att, attb, B_ * HEADS_ * N_);
        pv_k<<<dim3(1, 4, B_ * HEADS_), 256, 0, stream>>>(attb, vbb, obb);
        mgemm<64, 64>(obb, aoutB_l, aob, x, x, TOKENS, DIM_, DIM_, DIM_, DIM_, stream);
    }

    // final LN + logits
    tconv_kernel<<<dim3((10000 + 31) / 32, DIM_ / 32, 1), 256, 0, stream>>>(lgW, lgT, DIM_, 10000);
    ln_kernel<<<TOKENS / 4, 256, 0, stream>>>(x, fng, fnb, xnb, TOKENS);
    mgemm<128, 128>(xnb, lgT, lgb, nullptr, out, TOKENS, 10000, DIM_, DIM_, 10000, stream);
}

// Round 6
// 1491.896 us; speedup vs baseline: 3.3456x; 1.0041x over previous
//
#include <hip/hip_runtime.h>
#include <hip/hip_bf16.h>
#include <stdint.h>

#define B_    8
#define N_    256
#define CTX_  196
#define CTXP_ 224   // ctx padded to multiple of 32 for PV K-loop
#define IMGD_ 1024
#define DIM_  512
#define DEPTH_ 6
#define DIN_  1024
#define DTR_  32
#define DST_  16
#define HEADS_ 8
#define HD_   64
#define NCHUNK_ 16
#define CLEN_   16   // N_/NCHUNK_

typedef __bf16 bf16x8 __attribute__((ext_vector_type(8)));
typedef __bf16 bf16x4 __attribute__((ext_vector_type(4)));
typedef float  f32x4  __attribute__((ext_vector_type(4)));

// 16-lane sum via DPP butterfly; all 16 lanes get total
__device__ __forceinline__ float dpp_red16(float v) {
    int y;
    y = __builtin_amdgcn_update_dpp(0, __float_as_int(v), 0xB1, 0xF, 0xF, true);  // quad_perm [1,0,3,2]
    v += __int_as_float(y);
    y = __builtin_amdgcn_update_dpp(0, __float_as_int(v), 0x4E, 0xF, 0xF, true);  // quad_perm [2,3,0,1]
    v += __int_as_float(y);
    y = __builtin_amdgcn_update_dpp(0, __float_as_int(v), 0x141, 0xF, 0xF, true); // row_half_mirror
    v += __int_as_float(y);
    y = __builtin_amdgcn_update_dpp(0, __float_as_int(v), 0x140, 0xF, 0xF, true); // row_mirror
    v += __int_as_float(y);
    return v;
}

// ---------------- elementwise / small kernels ----------------

__global__ void dyt_kernel(const float* __restrict__ img, const float* __restrict__ alpha_p,
                           const float* __restrict__ gamma, const float* __restrict__ beta,
                           __bf16* __restrict__ out, int total) {
    int i = blockIdx.x * 256 + threadIdx.x;
    if (i >= total) return;
    float a = alpha_p[0];
    int c = i & (IMGD_ - 1);
    out[i] = (__bf16)(gamma[c] * tanhf(a * img[i]) + beta[c]);
}

__global__ void pool_kernel(const float* __restrict__ imgf, float* __restrict__ pooled) {
    int i = blockIdx.x * 256 + threadIdx.x;
    if (i >= B_ * DIM_) return;
    int b = i >> 9, c = i & (DIM_ - 1);
    const float* p = imgf + (size_t)b * CTX_ * DIM_ + c;
    float s = 0.f;
    for (int t = 0; t < CTX_; ++t) s += p[t * DIM_];
    pooled[i] = s * (1.f / CTX_);
}

__global__ void gate1_kernel(const float* __restrict__ pooled, const float* __restrict__ W,
                             const float* __restrict__ bias, float* __restrict__ g1) {
    int i = blockIdx.x * 256 + threadIdx.x;
    if (i >= B_ * 128) return;
    int b = i >> 7, j = i & 127;
    const float* p = pooled + b * DIM_;
    float s = bias[j];
    for (int c = 0; c < DIM_; ++c) s += p[c] * W[c * 128 + j];
    g1[i] = 0.5f * s * (1.f + erff(s * 0.70710678118654752f));
}

__global__ void gate2_kernel(const float* __restrict__ g1, const float* __restrict__ W,
                             const float* __restrict__ bias, float* __restrict__ gate) {
    int i = blockIdx.x * 256 + threadIdx.x;
    if (i >= B_ * DIM_) return;
    int b = i >> 9, c = i & (DIM_ - 1);
    const float* p = g1 + b * 128;
    float s = bias[c];
    for (int j = 0; j < 128; ++j) s += p[j] * W[j * DIM_ + c];
    gate[i] = 1.f / (1.f + __expf(-s));
}

__global__ void scale_kernel(const float* __restrict__ imgf, const float* __restrict__ gate,
                             __bf16* __restrict__ imgfb) {
    int i = blockIdx.x * 256 + threadIdx.x;
    if (i >= B_ * CTX_ * DIM_) return;
    int c = i & (DIM_ - 1);
    int b = i / (CTX_ * DIM_);
    imgfb[i] = (__bf16)(imgf[i] * gate[b * DIM_ + c]);
}

__global__ void embed_kernel(const int* __restrict__ text, const float* __restrict__ temb,
                             const float* __restrict__ pemb, float* __restrict__ x) {
    int i = blockIdx.x * 256 + threadIdx.x;
    if (i >= B_ * N_ * DIM_) return;
    int c = i & (DIM_ - 1);
    int row = i >> 9;
    int n = row & (N_ - 1);
    int tok = text[row];
    x[i] = temb[(size_t)tok * DIM_ + c] + pemb[(size_t)n * DIM_ + c];
}

// wave-per-row layernorm, row = 512 floats, bf16 output
__global__ void ln_kernel(const float* __restrict__ x, const float* __restrict__ g,
                          const float* __restrict__ b, __bf16* __restrict__ o, int rows) {
    int row = blockIdx.x * 4 + (threadIdx.x >> 6);
    if (row >= rows) return;
    int lane = threadIdx.x & 63;
    const float* xr = x + (size_t)row * DIM_ + lane * 8;
    float4 v0 = ((const float4*)xr)[0];
    float4 v1 = ((const float4*)xr)[1];
    float r[8] = {v0.x, v0.y, v0.z, v0.w, v1.x, v1.y, v1.z, v1.w};
    float sum = 0.f, sq = 0.f;
    #pragma unroll
    for (int j = 0; j < 8; ++j) { sum += r[j]; sq += r[j] * r[j]; }
    #pragma unroll
    for (int m = 1; m < 64; m <<= 1) { sum += __shfl_xor(sum, m); sq += __shfl_xor(sq, m); }
    float mean = sum * (1.f / DIM_);
    float var  = sq * (1.f / DIM_) - mean * mean;
    float inv  = rsqrtf(fmaxf(var, 0.f) + 1e-5f);
    const float* gp = g + lane * 8;
    const float* bp = b + lane * 8;
    __bf16* op = o + (size_t)row * DIM_ + lane * 8;
    bf16x8 ov;
    #pragma unroll
    for (int j = 0; j < 8; ++j) ov[j] = (__bf16)((r[j] - mean) * inv * gp[j] + bp[j]);
    *(bf16x8*)op = ov;
}

// causal depthwise conv (4 taps) + SiLU; float4-vectorized over d
__global__ void conv_silu_kernel(const float* __restrict__ xz, const float* __restrict__ cw,
                                 const float* __restrict__ cb, float* __restrict__ xc,
                                 __bf16* __restrict__ xcb) {
    int idx = blockIdx.x * 256 + threadIdx.x;
    if (idx >= B_ * N_ * DIN_ / 4) return;
    int i4 = idx * 4;
    int d = i4 & (DIN_ - 1);
    int row = i4 >> 10;
    int n = row & (N_ - 1);
    int rowb = row - n;
    float4 acc = *(const float4*)(cb + d);
    #pragma unroll
    for (int k = 0; k < 4; ++k) {
        int m = n - 3 + k;
        if (m >= 0) {
            float4 v = *(const float4*)(xz + (size_t)(rowb + m) * (2 * DIN_) + d);
            acc.x += v.x * cw[(d + 0) * 4 + k];
            acc.y += v.y * cw[(d + 1) * 4 + k];
            acc.z += v.z * cw[(d + 2) * 4 + k];
            acc.w += v.w * cw[(d + 3) * 4 + k];
        }
    }
    float4 s;
    s.x = acc.x / (1.f + __expf(-acc.x));
    s.y = acc.y / (1.f + __expf(-acc.y));
    s.z = acc.z / (1.f + __expf(-acc.z));
    s.w = acc.w / (1.f + __expf(-acc.w));
    *(float4*)(xc + i4) = s;
    bf16x4 p = {(__bf16)s.x, (__bf16)s.y, (__bf16)s.z, (__bf16)s.w};
    *(bf16x4*)(xcb + i4) = p;
}

// dt = softplus(dtp) (overwrite); u = dt * xc  (float4)
__global__ void dt_prep_kernel(float* __restrict__ dtp, const float* __restrict__ xc,
                               float* __restrict__ u) {
    int idx = blockIdx.x * 256 + threadIdx.x;
    if (idx >= B_ * N_ * DIN_ / 4) return;
    int i4 = idx * 4;
    float4 v = *(const float4*)(dtp + i4);
    float4 xcv = *(const float4*)(xc + i4);
    float4 dt, uu;
    dt.x = fmaxf(v.x, 0.f) + __logf(1.f + __expf(-fabsf(v.x)));
    dt.y = fmaxf(v.y, 0.f) + __logf(1.f + __expf(-fabsf(v.y)));
    dt.z = fmaxf(v.z, 0.f) + __logf(1.f + __expf(-fabsf(v.z)));
    dt.w = fmaxf(v.w, 0.f) + __logf(1.f + __expf(-fabsf(v.w)));
    uu.x = dt.x * xcv.x; uu.y = dt.y * xcv.y; uu.z = dt.z * xcv.z; uu.w = dt.w * xcv.w;
    *(float4*)(dtp + i4) = dt;
    *(float4*)(u + i4) = uu;
}

__global__ void cvt_bf16_kernel(const float* __restrict__ src, __bf16* __restrict__ dst, int count) {
    int i = (blockIdx.x * 256 + threadIdx.x) * 4;
    if (i >= count) return;
    float4 v = *(const float4*)(src + i);
    bf16x4 p = {(__bf16)v.x, (__bf16)v.y, (__bf16)v.z, (__bf16)v.w};
    *(bf16x4*)(dst + i) = p;
}

// ---------------- chunked selective scan ----------------
// t bits: s(4) | d(10) | c(4) | b(3)
__global__ __launch_bounds__(256) void scan1_kernel(
    const float* __restrict__ dtp, const float* __restrict__ u,
    const float* __restrict__ dbl, const float* __restrict__ A_log,
    float* __restrict__ chunkA, float* __restrict__ chunkB) {
    int t = blockIdx.x * 256 + threadIdx.x;
    int s = t & 15;
    int d = (t >> 4) & (DIN_ - 1);
    int c = (t >> 14) & (NCHUNK_ - 1);
    int b = t >> 18;
    float As = -__expf(A_log[(d << 4) | s]);
    float a = 1.f, hb = 0.f;
    int row0 = b * N_ + c * CLEN_;
    #pragma unroll 4
    for (int n = 0; n < CLEN_; ++n) {
        int row = row0 + n;
        float dt = dtp[(size_t)row * DIN_ + d];
        float uu = u[(size_t)row * DIN_ + d];
        float Bv = dbl[row * 64 + 32 + s];
        float dA = __expf(dt * As);
        hb = hb * dA + uu * Bv;
        a *= dA;
    }
    chunkA[t] = a;
    chunkB[t] = hb;
}

// scan2: compose prefix, replay chunk, DPP-reduce over s, store raw p-sum
__global__ __launch_bounds__(256) void scan2_kernel(
    const float* __restrict__ dtp, const float* __restrict__ u,
    const float* __restrict__ dbl, const float* __restrict__ A_log,
    const float* __restrict__ chunkA, const float* __restrict__ chunkB,
    float* __restrict__ psum) {
    int t = blockIdx.x * 256 + threadIdx.x;
    int s = t & 15;
    int d = (t >> 4) & (DIN_ - 1);
    int c = (t >> 14) & (NCHUNK_ - 1);
    int b = t >> 18;
    float h = 0.f;
    int base = (b << 18) | (d << 4) | s;
    for (int j = 0; j < c; ++j) {
        int idx = base | (j << 14);
        h = h * chunkA[idx] + chunkB[idx];
    }
    float As = -__expf(A_log[(d << 4) | s]);
    int row0 = b * N_ + c * CLEN_;
    #pragma unroll 4
    for (int n = 0; n < CLEN_; ++n) {
        int row = row0 + n;
        float dt = dtp[(size_t)row * DIN_ + d];
        float uu = u[(size_t)row * DIN_ + d];
        float Bv = dbl[row * 64 + 32 + s];
        float Cv = dbl[row * 64 + 48 + s];
        float dA = __expf(dt * As);
        h = h * dA + uu * Bv;
        float p = dpp_red16(h * Cv);
        if (s == 0) psum[(size_t)row * DIN_ + d] = p;
    }
}

// y = (psum + xc*D) * silu(z), bf16 out (float4)
__global__ void yfin_kernel(const float* __restrict__ psum, const float* __restrict__ xc,
                            const float* __restrict__ xz, const float* __restrict__ Dsk,
                            __bf16* __restrict__ ybb) {
    int idx = blockIdx.x * 256 + threadIdx.x;
    if (idx >= B_ * N_ * DIN_ / 4) return;
    int i4 = idx * 4;
    int d = i4 & (DIN_ - 1);
    int row = i4 >> 10;
    float4 z = *(const float4*)(xz + (size_t)row * (2 * DIN_) + DIN_ + d);
    float4 ps = *(const float4*)(psum + i4);
    float4 xcv = *(const float4*)(xc + i4);
    float4 Dv = *(const float4*)(Dsk + d);
    float4 y;
    y.x = (ps.x + xcv.x * Dv.x) * (z.x / (1.f + __expf(-z.x)));
    y.y = (ps.y + xcv.y * Dv.y) * (z.y / (1.f + __expf(-z.y)));
    y.z = (ps.z + xcv.z * Dv.z) * (z.z / (1.f + __expf(-z.z)));
    y.w = (ps.w + xcv.w * Dv.w) * (z.w / (1.f + __expf(-z.w)));
    bf16x4 p = {(__bf16)y.x, (__bf16)y.y, (__bf16)y.z, (__bf16)y.w};
    *(bf16x4*)(ybb + i4) = p;
}

// wave-per-row softmax over CTX_=196; writes bf16 padded to 224
__global__ void softmax_kernel(const float* __restrict__ att, __bf16* __restrict__ attb, int rows) {
    int row = blockIdx.x * 4 + (threadIdx.x >> 6);
    if (row >= rows) return;
    int lane = threadIdx.x & 63;
    const float* ar = att + (size_t)row * CTX_;
    float v[4];
    float mx = -1e30f;
    #pragma unroll
    for (int j = 0; j < 4; ++j) {
        int idx = lane + j * 64;
        v[j] = idx < CTX_ ? ar[idx] : -1e30f;
        mx = fmaxf(mx, v[j]);
    }
    #pragma unroll
    for (int m = 1; m < 64; m <<= 1) mx = fmaxf(mx, __shfl_xor(mx, m));
    float sm = 0.f;
    #pragma unroll
    for (int j = 0; j < 4; ++j) {
        int idx = lane + j * 64;
        v[j] = idx < CTX_ ? __expf(v[j] - mx) : 0.f;
        sm += v[j];
    }
    #pragma unroll
    for (int m = 1; m < 64; m <<= 1) sm += __shfl_xor(sm, m);
    float inv = 1.f / sm;
    __bf16* ob = attb + (size_t)row * CTXP_;
    #pragma unroll
    for (int j = 0; j < 4; ++j) {
        int idx = lane + j * 64;
        if (idx < CTXP_) ob[idx] = (idx < CTX_) ? (__bf16)(v[j] * inv) : (__bf16)0.f;
    }
}

// ---------------- weight prep ----------------

__global__ void tconv_kernel(const float* __restrict__ src, __bf16* __restrict__ dst,
                             int K, int N) {
    __shared__ float tile[32][33];
    int n0 = blockIdx.x * 32, k0 = blockIdx.y * 32;
    src += (size_t)blockIdx.z * K * N;
    dst += (size_t)blockIdx.z * K * N;
    int tx = threadIdx.x & 31, ty = threadIdx.x >> 5;
    #pragma unroll
    for (int i = 0; i < 32; i += 8) {
        int k = k0 + ty + i, n = n0 + tx;
        tile[ty + i][tx] = (k < K && n < N) ? src[(size_t)k * N + n] : 0.f;
    }
    __syncthreads();
    #pragma unroll
    for (int i = 0; i < 32; i += 8) {
        int n = n0 + ty + i, k = k0 + tx;
        if (n < N && k < K) dst[(size_t)n * K + k] = (__bf16)tile[tx][ty + i];
    }
}

// ---------------- bf16 MFMA GEMM (double-buffered, tile-templated) ----------------
#define LDP_ 40

template <int BM, int BN, bool BOUT>
__global__ __launch_bounds__(256) void mgemm_k(
    const __bf16* __restrict__ A, const __bf16* __restrict__ Bw,
    const float* __restrict__ bias, const float* __restrict__ res,
    void* __restrict__ Cp, int M, int N, int K, int lda, int ldc) {
    constexpr int AU = BM * 4;                 // 8-bf16 units for 32-wide K slab
    constexpr int BU = BN * 4;
    constexpr int RA = (AU + 255) / 256;
    constexpr int RB = (BU + 255) / 256;
    constexpr int FM = BM / 32, FN = BN / 32;  // frags per wave
    __shared__ __align__(16) __bf16 As[2][BM * LDP_];
    __shared__ __align__(16) __bf16 Bs[2][BN * LDP_];
    int tid = threadIdx.x;
    int ntx = gridDim.x;
    int nwg = ntx * gridDim.y;
    int bid = blockIdx.y * ntx + blockIdx.x;
    if ((nwg & 7) == 0) bid = (bid & 7) * (nwg >> 3) + (bid >> 3);
    int row0 = (bid / ntx) * BM, col0 = (bid % ntx) * BN;
    int wave = tid >> 6, lane = tid & 63;
    int wm = (wave >> 1) * (BM / 2), wn = (wave & 1) * (BN / 2);
    int fr = lane & 15, fk = lane >> 4;
    f32x4 acc[FM][FN] = {};
    uint4 aR[RA], bR[RB];

    auto loadT = [&](int k0) {
        #pragma unroll
        for (int i = 0; i < RA; ++i) {
            int idx = i * 256 + tid;
            if (AU % 256 == 0 || idx < AU) {
                int r = idx >> 2, c = (idx & 3) * 8;
                int gm = row0 + r;
                uint4 v = {0u, 0u, 0u, 0u};
                if (gm < M) v = *(const uint4*)(A + (size_t)gm * lda + k0 + c);
                aR[i] = v;
            }
        }
        #pragma unroll
        for (int i = 0; i < RB; ++i) {
            int idx = i * 256 + tid;
            if (BU % 256 == 0 || idx < BU) {
                int r = idx >> 2, c = (idx & 3) * 8;
                int gn = col0 + r;
                uint4 v = {0u, 0u, 0u, 0u};
                if (gn < N) v = *(const uint4*)(Bw + (size_t)gn * K + k0 + c);
                bR[i] = v;
            }
        }
    };
    auto writeT = [&](int buf) {
        #pragma unroll
        for (int i = 0; i < RA; ++i) {
            int idx = i * 256 + tid;
            if (AU % 256 == 0 || idx < AU) {
                int r = idx >> 2, c = (idx & 3) * 8;
                *(uint4*)&As[buf][r * LDP_ + c] = aR[i];
            }
        }
        #pragma unroll
        for (int i = 0; i < RB; ++i) {
            int idx = i * 256 + tid;
            if (BU % 256 == 0 || idx < BU) {
                int r = idx >> 2, c = (idx & 3) * 8;
                *(uint4*)&Bs[buf][r * LDP_ + c] = bR[i];
            }
        }
    };

    loadT(0);
    writeT(0);
    __syncthreads();
    int NK = K >> 5;
    for (int kt = 0; kt < NK; ++kt) {
        int cur = kt & 1;
        if (kt + 1 < NK) loadT((kt + 1) << 5);
        bf16x8 af[FM], bg[FN];
        #pragma unroll
        for (int mf = 0; mf < FM; ++mf)
            af[mf] = *(const bf16x8*)&As[cur][(wm + mf * 16 + fr) * LDP_ + fk * 8];
        #pragma unroll
        for (int nf = 0; nf < FN; ++nf)
            bg[nf] = *(const bf16x8*)&Bs[cur][(wn + nf * 16 + fr) * LDP_ + fk * 8];
        #pragma unroll
        for (int mf = 0; mf < FM; ++mf)
            #pragma unroll
            for (int nf = 0; nf < FN; ++nf)
                acc[mf][nf] = __builtin_amdgcn_mfma_f32_16x16x32_bf16(af[mf], bg[nf], acc[mf][nf], 0, 0, 0);
        if (kt + 1 < NK) {
            writeT(cur ^ 1);
            __syncthreads();
        }
    }
    #pragma unroll
    for (int mf = 0; mf < FM; ++mf) {
        #pragma unroll
        for (int nf = 0; nf < FN; ++nf) {
            int gn = col0 + wn + nf * 16 + fr;
            if (gn >= N) continue;
            float bb = bias ? bias[gn] : 0.f;
            #pragma unroll
            for (int e = 0; e < 4; ++e) {
                int gm = row0 + wm + mf * 16 + fk * 4 + e;
                if (gm >= M) continue;
                size_t idx = (size_t)gm * ldc + gn;
                float v = acc[mf][nf][e] + bb;
                if constexpr (BOUT) {
                    ((__bf16*)Cp)[idx] = (__bf16)v;
                } else {
                    if (res) v += res[idx];
                    ((float*)Cp)[idx] = v;
                }
            }
        }
    }
}

template <int BM, int BN, bool BOUT = false>
static inline void mgemm(const __bf16* A, const __bf16* Bw, const float* bias,
                         const float* res, void* C, int M, int N, int K,
                         int lda, int ldc, hipStream_t s) {
    dim3 g((N + BN - 1) / BN, (M + BM - 1) / BM);
    mgemm_k<BM, BN, BOUT><<<g, 256, 0, s>>>(A, Bw, bias, res, C, M, N, K, lda, ldc);
}

// ---------------- batched attention MFMA kernels ----------------
__global__ __launch_bounds__(256) void scores_k(
    const __bf16* __restrict__ qb, const __bf16* __restrict__ kbb,
    float* __restrict__ att) {
    int z = blockIdx.z, b = z >> 3, h = z & 7;
    const __bf16* Ab = qb + (size_t)b * N_ * DIM_ + h * HD_;
    const __bf16* Bb = kbb + (size_t)b * CTX_ * DIM_ + h * HD_;
    float* Cb = att + (size_t)z * N_ * CTX_;
    int row0 = blockIdx.y * 64, col0 = blockIdx.x * 64;
    __shared__ __align__(16) __bf16 As[64 * LDP_];
    __shared__ __align__(16) __bf16 Bs[64 * LDP_];
    int tid = threadIdx.x, wave = tid >> 6, lane = tid & 63;
    int wm = (wave >> 1) * 32, wn = (wave & 1) * 32;
    int fr = lane & 15, fk = lane >> 4;
    f32x4 acc[2][2] = {};
    int r = tid >> 2, c = (tid & 3) * 8;
    for (int k0 = 0; k0 < HD_; k0 += 32) {
        {
            uint4 v = {0u, 0u, 0u, 0u};
            if (row0 + r < N_) v = *(const uint4*)(Ab + (size_t)(row0 + r) * DIM_ + k0 + c);
            *(uint4*)&As[r * LDP_ + c] = v;
        }
        {
            uint4 v = {0u, 0u, 0u, 0u};
            if (col0 + r < CTX_) v = *(const uint4*)(Bb + (size_t)(col0 + r) * DIM_ + k0 + c);
            *(uint4*)&Bs[r * LDP_ + c] = v;
        }
        __syncthreads();
        bf16x8 af[2], bg[2];
        #pragma unroll
        for (int mf = 0; mf < 2; ++mf) af[mf] = *(const bf16x8*)&As[(wm + mf * 16 + fr) * LDP_ + fk * 8];
        #pragma unroll
        for (int nf = 0; nf < 2; ++nf) bg[nf] = *(const bf16x8*)&Bs[(wn + nf * 16 + fr) * LDP_ + fk * 8];
        #pragma unroll
        for (int mf = 0; mf < 2; ++mf)
            #pragma unroll
            for (int nf = 0; nf < 2; ++nf)
                acc[mf][nf] = __builtin_amdgcn_mfma_f32_16x16x32_bf16(af[mf], bg[nf], acc[mf][nf], 0, 0, 0);
        __syncthreads();
    }
    #pragma unroll
    for (int mf = 0; mf < 2; ++mf)
        #pragma unroll
        for (int nf = 0; nf < 2; ++nf) {
            int gn = col0 + wn + nf * 16 + fr;
            if (gn >= CTX_) continue;
            #pragma unroll
            for (int e = 0; e < 4; ++e) {
                int gm = row0 + wm + mf * 16 + fk * 4 + e;
                Cb[(size_t)gm * CTX_ + gn] = acc[mf][nf][e] * 0.125f;
            }
        }
}

__global__ __launch_bounds__(256) void pv_k(
    const __bf16* __restrict__ attb, const __bf16* __restrict__ vbb,
    __bf16* __restrict__ obb) {
    int z = blockIdx.z, b = z >> 3, h = z & 7;
    const __bf16* Ab = attb + (size_t)z * N_ * CTXP_;
    const __bf16* Vb = vbb + (size_t)b * CTX_ * DIM_ + h * HD_;
    __bf16* Cb = obb + (size_t)b * N_ * DIM_ + h * HD_;
    int row0 = blockIdx.y * 64;
    __shared__ __align__(16) __bf16 As[64 * LDP_];
    __shared__ __align__(16) __bf16 Bs[64 * LDP_];
    int tid = threadIdx.x, wave = tid >> 6, lane = tid & 63;
    int wm = (wave >> 1) * 32, wn = (wave & 1) * 32;
    int fr = lane & 15, fk = lane >> 4;
    f32x4 acc[2][2] = {};
    int r = tid >> 2, c = (tid & 3) * 8;
    int kr = tid >> 3, c2 = (tid & 7) * 8;
    for (int k0 = 0; k0 < CTXP_; k0 += 32) {
        {
            uint4 v = *(const uint4*)(Ab + (size_t)(row0 + r) * CTXP_ + k0 + c);
            *(uint4*)&As[r * LDP_ + c] = v;
        }
        {
            bf16x8 v = {};
            if (k0 + kr < CTX_) v = *(const bf16x8*)(Vb + (size_t)(k0 + kr) * DIM_ + c2);
            #pragma unroll
            for (int j = 0; j < 8; ++j) Bs[(c2 + j) * LDP_ + kr] = v[j];
        }
        __syncthreads();
        bf16x8 af[2], bg[2];
        #pragma unroll
        for (int mf = 0; mf < 2; ++mf) af[mf] = *(const bf16x8*)&As[(wm + mf * 16 + fr) * LDP_ + fk * 8];
        #pragma unroll
        for (int nf = 0; nf < 2; ++nf) bg[nf] = *(const bf16x8*)&Bs[(wn + nf * 16 + fr) * LDP_ + fk * 8];
        #pragma unroll
        for (int mf = 0; mf < 2; ++mf)
            #pragma unroll
            for (int nf = 0; nf < 2; ++nf)
                acc[mf][nf] = __builtin_amdgcn_mfma_f32_16x16x32_bf16(af[mf], bg[nf], acc[mf][nf], 0, 0, 0);
        __syncthreads();
    }
    #pragma unroll
    for (int mf = 0; mf < 2; ++mf)
        #pragma unroll
        for (int nf = 0; nf < 2; ++nf) {
            int gn = wn + nf * 16 + fr;
            #pragma unroll
            for (int e = 0; e < 4; ++e) {
                int gm = row0 + wm + mf * 16 + fk * 4 + e;
                Cb[(size_t)gm * DIM_ + gn] = (__bf16)acc[mf][nf][e];
            }
        }
}

// ---------------- generic fp32 GEMM (dt_proj only) ----------------
#define TM_ 64
#define TN_ 64
#define TK_ 16

__global__ __launch_bounds__(256) void gemm_k(
    const float* __restrict__ A, const float* __restrict__ B,
    const float* __restrict__ bias, float* C,
    int M, int N, int K, int lda, int ldb, int ldc) {
    __shared__ float As[TK_][TM_ + 4];
    __shared__ float Bs[TK_][TN_ + 4];
    int tid = threadIdx.x;
    int row0 = blockIdx.y * TM_;
    int col0 = blockIdx.x * TN_;
    int tm = (tid / 16) * 4, tn = (tid % 16) * 4;
    float acc[4][4] = {};
    int nk = (K + TK_ - 1) / TK_;
    for (int kt = 0; kt < nk; ++kt) {
        int k0 = kt * TK_;
        {
            int m = tid >> 2, kq = (tid & 3) * 4;
            int gm = row0 + m;
            float4 v = {0, 0, 0, 0};
            if (gm < M && k0 + kq + 3 < K) v = *(const float4*)(A + (size_t)gm * lda + k0 + kq);
            else if (gm < M) {
                float tmp[4] = {0, 0, 0, 0};
                for (int j = 0; j < 4; ++j) if (k0 + kq + j < K) tmp[j] = A[(size_t)gm * lda + k0 + kq + j];
                v = {tmp[0], tmp[1], tmp[2], tmp[3]};
            }
            As[kq + 0][m] = v.x; As[kq + 1][m] = v.y; As[kq + 2][m] = v.z; As[kq + 3][m] = v.w;
        }
        {
            int kk = tid >> 4, nq = (tid & 15) * 4;
            int gk = k0 + kk;
            float4 v = {0, 0, 0, 0};
            if (gk < K && col0 + nq + 3 < N) v = *(const float4*)(B + (size_t)gk * ldb + col0 + nq);
            Bs[kk][nq + 0] = v.x; Bs[kk][nq + 1] = v.y; Bs[kk][nq + 2] = v.z; Bs[kk][nq + 3] = v.w;
        }
        __syncthreads();
        #pragma unroll
        for (int kk = 0; kk < TK_; ++kk) {
            float4 a4 = *(const float4*)&As[kk][tm];
            float4 b4 = *(const float4*)&Bs[kk][tn];
            float a0[4] = {a4.x, a4.y, a4.z, a4.w};
            float b0[4] = {b4.x, b4.y, b4.z, b4.w};
            #pragma unroll
            for (int i = 0; i < 4; ++i)
                #pragma unroll
                for (int j = 0; j < 4; ++j)
                    acc[i][j] += a0[i] * b0[j];
        }
        __syncthreads();
    }
    for (int i = 0; i < 4; ++i) {
        int gm = row0 + tm + i;
        if (gm >= M) continue;
        for (int j = 0; j < 4; ++j) {
            int gn = col0 + tn + j;
            if (gn >= N) continue;
            float v = acc[i][j];
            if (bias) v += bias[gn];
            C[(size_t)gm * ldc + gn] = v;
        }
    }
}

// ---------------- host side ----------------

extern "C" void kernel_launch(void* const* d_in, const int* in_sizes, int n_in,
                              void* d_out, int out_size, void* d_ws, size_t ws_size,
                              hipStream_t stream) {
    const int*   text   = (const int*)d_in[0];
    const float* images = (const float*)d_in[1];
    const float* alphap = (const float*)d_in[2];
    const float* dgam   = (const float*)d_in[3];
    const float* dbeta  = (const float*)d_in[4];
    const float* imgW   = (const float*)d_in[5];
    const float* imgb   = (const float*)d_in[6];
    const float* g1W    = (const float*)d_in[7];
    const float* g1b    = (const float*)d_in[8];
    const float* g2W    = (const float*)d_in[9];
    const float* g2b    = (const float*)d_in[10];
    const float* temb   = (const float*)d_in[11];
    const float* pemb   = (const float*)d_in[12];
    const float* ln1g   = (const float*)d_in[13];
    const float* ln1b   = (const float*)d_in[14];
    const float* inW    = (const float*)d_in[15];
    const float* convW  = (const float*)d_in[16];
    const float* convb  = (const float*)d_in[17];
    const float* xpW    = (const float*)d_in[18];
    const float* dtW    = (const float*)d_in[19];
    const float* dtb    = (const float*)d_in[20];
    const float* Alog   = (const float*)d_in[21];
    const float* Dsk    = (const float*)d_in[22];
    const float* outW   = (const float*)d_in[23];
    const float* ln2g   = (const float*)d_in[24];
    const float* ln2b   = (const float*)d_in[25];
    const float* ainW   = (const float*)d_in[26];
    const float* ainb   = (const float*)d_in[27];
    const float* aoutW  = (const float*)d_in[28];
    const float* aoutb  = (const float*)d_in[29];
    const float* fng    = (const float*)d_in[30];
    const float* fnb    = (const float*)d_in[31];
    const float* lgW    = (const float*)d_in[32];
    const float* lgb    = (const float*)d_in[33];
    float* out = (float*)d_out;

    float* w = (float*)d_ws;
    float* imgd   = w; w += (size_t)B_ * CTX_ * IMGD_;   // bf16 dyt out (aliased)
    float* imgf   = w; w += (size_t)B_ * CTX_ * DIM_;
    float* pooled = w; w += B_ * DIM_;
    float* g1     = w; w += B_ * 128;
    float* gate   = w; w += B_ * DIM_;
    float* x      = w; w += (size_t)B_ * N_ * DIM_;
    float* xn     = w; w += (size_t)B_ * N_ * DIM_;      // bf16 ln out (aliased)
    float* xz     = w; w += (size_t)B_ * N_ * 2 * DIN_;
    float* xc     = w; w += (size_t)B_ * N_ * DIN_;
    float* dblb   = w; w += (size_t)B_ * N_ * 64;
    float* dtp    = w; w += (size_t)B_ * N_ * DIN_;
    float* psum   = w; w += (size_t)B_ * N_ * DIN_;
    float* chunkA = w; w += (size_t)NCHUNK_ * B_ * DIN_ * DST_;   // 2M fl
    float* chunkB = w; w += (size_t)NCHUNK_ * B_ * DIN_ * DST_;   // 2M fl
    float* att    = w; w += (size_t)B_ * HEADS_ * N_ * CTX_;
    // bf16 buffers
    __bf16* xcb   = (__bf16*)w; w += (size_t)B_ * N_ * DIN_ / 2;
    __bf16* imgfb = (__bf16*)w; w += (size_t)B_ * CTX_ * DIM_ / 2;
    __bf16* ybb   = (__bf16*)w; w += (size_t)B_ * N_ * DIN_ / 2;
    __bf16* qb    = (__bf16*)w; w += (size_t)B_ * N_ * DIM_ / 2;
    __bf16* kbb   = (__bf16*)w; w += (size_t)B_ * CTX_ * DIM_ / 2;
    __bf16* vbb   = (__bf16*)w; w += (size_t)B_ * CTX_ * DIM_ / 2;
    __bf16* obb   = (__bf16*)w; w += (size_t)B_ * N_ * DIM_ / 2;
    __bf16* attb  = (__bf16*)w; w += (size_t)B_ * HEADS_ * N_ * CTXP_ / 2;
    // bf16 weights
    __bf16* inpT  = (__bf16*)w; w += (size_t)DEPTH_ * 2 * DIN_ * DIM_ / 2;
    __bf16* outpT = (__bf16*)w; w += (size_t)DEPTH_ * DIM_ * DIN_ / 2;
    __bf16* ainB  = (__bf16*)w; w += (size_t)DEPTH_ * 3 * DIM_ * DIM_ / 2;
    __bf16* aoutB = (__bf16*)w; w += (size_t)DEPTH_ * DIM_ * DIM_ / 2;
    __bf16* imgWT = (__bf16*)w; w += (size_t)DIM_ * IMGD_ / 2;
    __bf16* xpWT  = (__bf16*)w; w += (size_t)DEPTH_ * 64 * DIN_ / 2;
    __bf16* lgT   = (__bf16*)att;   // logits weight aliases att (dead after layers)
    __bf16* imgdb = (__bf16*)imgd;
    __bf16* xnb   = (__bf16*)xn;

    // scan scratch alias
    float* ubuf   = att;   // u: 2M fl <= 3.21M; dead before scores written

    const int TOKENS = B_ * N_;
    const int IMGT   = B_ * CTX_;
    const int SCANT  = B_ * DIN_ * DST_ * NCHUNK_;   // 2M

    // ---- weight prep ----
    tconv_kernel<<<dim3(2 * DIN_ / 32, DIM_ / 32, DEPTH_), 256, 0, stream>>>(inW,  inpT,  DIM_, 2 * DIN_);
    tconv_kernel<<<dim3(DIM_ / 32, DIN_ / 32, DEPTH_),     256, 0, stream>>>(outW, outpT, DIN_, DIM_);
    tconv_kernel<<<dim3(DIM_ / 32, IMGD_ / 32, 1),         256, 0, stream>>>(imgW, imgWT, IMGD_, DIM_);
    tconv_kernel<<<dim3(64 / 32, DIN_ / 32, DEPTH_),       256, 0, stream>>>(xpW,  xpWT,  DIN_, 64);
    cvt_bf16_kernel<<<(DEPTH_ * 3 * DIM_ * DIM_ / 4 + 255) / 256, 256, 0, stream>>>(ainW,  ainB,  DEPTH_ * 3 * DIM_ * DIM_);
    cvt_bf16_kernel<<<(DEPTH_ * DIM_ * DIM_ / 4 + 255) / 256, 256, 0, stream>>>(aoutW, aoutB, DEPTH_ * DIM_ * DIM_);

    // ---- image path ----
    {
        int total = B_ * CTX_ * IMGD_;
        dyt_kernel<<<(total + 255) / 256, 256, 0, stream>>>(images, alphap, dgam, dbeta, imgdb, total);
        mgemm<32, 64>(imgdb, imgWT, imgb, nullptr, imgf, IMGT, DIM_, IMGD_, IMGD_, DIM_, stream);
        pool_kernel<<<(B_ * DIM_ + 255) / 256, 256, 0, stream>>>(imgf, pooled);
        gate1_kernel<<<(B_ * 128 + 255) / 256, 256, 0, stream>>>(pooled, g1W, g1b, g1);
        gate2_kernel<<<(B_ * DIM_ + 255) / 256, 256, 0, stream>>>(g1, g2W, g2b, gate);
        scale_kernel<<<(B_ * CTX_ * DIM_ + 255) / 256, 256, 0, stream>>>(imgf, gate, imgfb);
    }
    embed_kernel<<<(TOKENS * DIM_ + 255) / 256, 256, 0, stream>>>(text, temb, pemb, x);

    for (int l = 0; l < DEPTH_; ++l) {
        const __bf16* inpT_l  = inpT  + (size_t)l * 2 * DIN_ * DIM_;
        const __bf16* outpT_l = outpT + (size_t)l * DIM_ * DIN_;
        const __bf16* ainB_l  = ainB  + (size_t)l * 3 * DIM_ * DIM_;
        const __bf16* aoutB_l = aoutB + (size_t)l * DIM_ * DIM_;
        const __bf16* xpWT_l  = xpWT  + (size_t)l * 64 * DIN_;
        const float* cw    = convW + (size_t)l * DIN_ * 4;
        const float* cb    = convb + (size_t)l * DIN_;
        const float* dtw   = dtW  + (size_t)l * DTR_ * DIN_;
        const float* dtbi  = dtb  + (size_t)l * DIN_;
        const float* alog  = Alog + (size_t)l * DIN_ * DST_;
        const float* dsk   = Dsk  + (size_t)l * DIN_;
        const float* ab    = ainb + (size_t)l * 3 * DIM_;
        const float* aob   = aoutb + (size_t)l * DIM_;

        // mamba block
        ln_kernel<<<TOKENS / 4, 256, 0, stream>>>(x, ln1g + l * DIM_, ln1b + l * DIM_, xnb, TOKENS);
        mgemm<64, 128>(xnb, inpT_l, nullptr, nullptr, xz, TOKENS, 2 * DIN_, DIM_, DIM_, 2 * DIN_, stream);
        conv_silu_kernel<<<(TOKENS * DIN_ / 4 + 255) / 256, 256, 0, stream>>>(xz, cw, cb, xc, xcb);
        mgemm<32, 64>(xcb, xpWT_l, nullptr, nullptr, dblb, TOKENS, 64, DIN_, DIN_, 64, stream);
        gemm_k<<<dim3((DIN_ + TN_ - 1) / TN_, (TOKENS + TM_ - 1) / TM_), 256, 0, stream>>>(
            dblb, dtw, dtbi, dtp, TOKENS, DIN_, DTR_, 64, DIN_, DIN_);
        dt_prep_kernel<<<(TOKENS * DIN_ / 4 + 255) / 256, 256, 0, stream>>>(dtp, xc, ubuf);
        scan1_kernel<<<SCANT / 256, 256, 0, stream>>>(dtp, ubuf, dblb, alog, chunkA, chunkB);
        scan2_kernel<<<SCANT / 256, 256, 0, stream>>>(dtp, ubuf, dblb, alog, chunkA, chunkB, psum);
        yfin_kernel<<<(TOKENS * DIN_ / 4 + 255) / 256, 256, 0, stream>>>(psum, xc, xz, dsk, ybb);
        mgemm<32, 64>(ybb, outpT_l, nullptr, x, x, TOKENS, DIM_, DIN_, DIN_, DIM_, stream);

        // cross-attention block
        ln_kernel<<<TOKENS / 4, 256, 0, stream>>>(x, ln2g + l * DIM_, ln2b + l * DIM_, xnb, TOKENS);
        mgemm<32, 64, true>(xnb,   ainB_l,                           ab,            nullptr, qb,  TOKENS, DIM_, DIM_, DIM_, DIM_, stream);
        mgemm<32, 64, true>(imgfb, ainB_l + (size_t)DIM_ * DIM_,     ab + DIM_,     nullptr, kbb, IMGT,  DIM_, DIM_, DIM_, DIM_, stream);
        mgemm<32, 64, true>(imgfb, ainB_l + (size_t)2 * DIM_ * DIM_, ab + 2 * DIM_, nullptr, vbb, IMGT,  DIM_, DIM_, DIM_, DIM_, stream);
        scores_k<<<dim3(4, 4, B_ * HEADS_), 256, 0, stream>>>(qb, kbb, att);
        softmax_kernel<<<(B_ * HEADS_ * N_) / 4, 256, 0, stream>>>(att, attb, B_ * HEADS_ * N_);
        pv_k<<<dim3(1, 4, B_ * HEADS_), 256, 0, stream>>>(attb, vbb, obb);
        mgemm<32, 64>(obb, aoutB_l, aob, x, x, TOKENS, DIM_, DIM_, DIM_, DIM_, stream);
    }

    // final LN + logits
    tconv_kernel<<<dim3((10000 + 31) / 32, DIM_ / 32, 1), 256, 0, stream>>>(lgW, lgT, DIM_, 10000);
    ln_kernel<<<TOKENS / 4, 256, 0, stream>>>(x, fng, fnb, xnb, TOKENS);
    mgemm<128, 128>(xnb, lgT, lgb, nullptr, out, TOKENS, 10000, DIM_, DIM_, 10000, stream);
}

// Round 7
// 1490.033 us; speedup vs baseline: 3.3498x; 1.0013x over previous
//
#include <hip/hip_runtime.h>
#include <hip/hip_bf16.h>
#include <stdint.h>

#define B_    8
#define N_    256
#define CTX_  196
#define CTXP_ 224   // ctx padded to multiple of 32 for PV K-loop
#define CTXF_ 13    // score col frags (13*16 = 208 >= 196)
#define IMGD_ 1024
#define DIM_  512
#define DEPTH_ 6
#define DIN_  1024
#define DTR_  32
#define DST_  16
#define HEADS_ 8
#define HD_   64
#define NCHUNK_ 16
#define CLEN_   16   // N_/NCHUNK_

typedef __bf16 bf16x8 __attribute__((ext_vector_type(8)));
typedef __bf16 bf16x4 __attribute__((ext_vector_type(4)));
typedef float  f32x4  __attribute__((ext_vector_type(4)));

// 16-lane sum via DPP butterfly; all 16 lanes get total
__device__ __forceinline__ float dpp_red16(float v) {
    int y;
    y = __builtin_amdgcn_update_dpp(0, __float_as_int(v), 0xB1, 0xF, 0xF, true);
    v += __int_as_float(y);
    y = __builtin_amdgcn_update_dpp(0, __float_as_int(v), 0x4E, 0xF, 0xF, true);
    v += __int_as_float(y);
    y = __builtin_amdgcn_update_dpp(0, __float_as_int(v), 0x141, 0xF, 0xF, true);
    v += __int_as_float(y);
    y = __builtin_amdgcn_update_dpp(0, __float_as_int(v), 0x140, 0xF, 0xF, true);
    v += __int_as_float(y);
    return v;
}
__device__ __forceinline__ float dpp_max16(float v) {
    int y;
    y = __builtin_amdgcn_update_dpp(0, __float_as_int(v), 0xB1, 0xF, 0xF, true);
    v = fmaxf(v, __int_as_float(y));
    y = __builtin_amdgcn_update_dpp(0, __float_as_int(v), 0x4E, 0xF, 0xF, true);
    v = fmaxf(v, __int_as_float(y));
    y = __builtin_amdgcn_update_dpp(0, __float_as_int(v), 0x141, 0xF, 0xF, true);
    v = fmaxf(v, __int_as_float(y));
    y = __builtin_amdgcn_update_dpp(0, __float_as_int(v), 0x140, 0xF, 0xF, true);
    v = fmaxf(v, __int_as_float(y));
    return v;
}

// ---------------- elementwise / small kernels ----------------

__global__ void dyt_kernel(const float* __restrict__ img, const float* __restrict__ alpha_p,
                           const float* __restrict__ gamma, const float* __restrict__ beta,
                           __bf16* __restrict__ out, int total) {
    int i = blockIdx.x * 256 + threadIdx.x;
    if (i >= total) return;
    float a = alpha_p[0];
    int c = i & (IMGD_ - 1);
    out[i] = (__bf16)(gamma[c] * tanhf(a * img[i]) + beta[c]);
}

__global__ void pool_kernel(const float* __restrict__ imgf, float* __restrict__ pooled) {
    int i = blockIdx.x * 256 + threadIdx.x;
    if (i >= B_ * DIM_) return;
    int b = i >> 9, c = i & (DIM_ - 1);
    const float* p = imgf + (size_t)b * CTX_ * DIM_ + c;
    float s = 0.f;
    for (int t = 0; t < CTX_; ++t) s += p[t * DIM_];
    pooled[i] = s * (1.f / CTX_);
}

__global__ void gate1_kernel(const float* __restrict__ pooled, const float* __restrict__ W,
                             const float* __restrict__ bias, float* __restrict__ g1) {
    int i = blockIdx.x * 256 + threadIdx.x;
    if (i >= B_ * 128) return;
    int b = i >> 7, j = i & 127;
    const float* p = pooled + b * DIM_;
    float s = bias[j];
    for (int c = 0; c < DIM_; ++c) s += p[c] * W[c * 128 + j];
    g1[i] = 0.5f * s * (1.f + erff(s * 0.70710678118654752f));
}

__global__ void gate2_kernel(const float* __restrict__ g1, const float* __restrict__ W,
                             const float* __restrict__ bias, float* __restrict__ gate) {
    int i = blockIdx.x * 256 + threadIdx.x;
    if (i >= B_ * DIM_) return;
    int b = i >> 9, c = i & (DIM_ - 1);
    const float* p = g1 + b * 128;
    float s = bias[c];
    for (int j = 0; j < 128; ++j) s += p[j] * W[j * DIM_ + c];
    gate[i] = 1.f / (1.f + __expf(-s));
}

__global__ void scale_kernel(const float* __restrict__ imgf, const float* __restrict__ gate,
                             __bf16* __restrict__ imgfb) {
    int i = blockIdx.x * 256 + threadIdx.x;
    if (i >= B_ * CTX_ * DIM_) return;
    int c = i & (DIM_ - 1);
    int b = i / (CTX_ * DIM_);
    imgfb[i] = (__bf16)(imgf[i] * gate[b * DIM_ + c]);
}

__global__ void embed_kernel(const int* __restrict__ text, const float* __restrict__ temb,
                             const float* __restrict__ pemb, float* __restrict__ x) {
    int i = blockIdx.x * 256 + threadIdx.x;
    if (i >= B_ * N_ * DIM_) return;
    int c = i & (DIM_ - 1);
    int row = i >> 9;
    int n = row & (N_ - 1);
    int tok = text[row];
    x[i] = temb[(size_t)tok * DIM_ + c] + pemb[(size_t)n * DIM_ + c];
}

// wave-per-row layernorm, row = 512 floats, bf16 output
__global__ void ln_kernel(const float* __restrict__ x, const float* __restrict__ g,
                          const float* __restrict__ b, __bf16* __restrict__ o, int rows) {
    int row = blockIdx.x * 4 + (threadIdx.x >> 6);
    if (row >= rows) return;
    int lane = threadIdx.x & 63;
    const float* xr = x + (size_t)row * DIM_ + lane * 8;
    float4 v0 = ((const float4*)xr)[0];
    float4 v1 = ((const float4*)xr)[1];
    float r[8] = {v0.x, v0.y, v0.z, v0.w, v1.x, v1.y, v1.z, v1.w};
    float sum = 0.f, sq = 0.f;
    #pragma unroll
    for (int j = 0; j < 8; ++j) { sum += r[j]; sq += r[j] * r[j]; }
    #pragma unroll
    for (int m = 1; m < 64; m <<= 1) { sum += __shfl_xor(sum, m); sq += __shfl_xor(sq, m); }
    float mean = sum * (1.f / DIM_);
    float var  = sq * (1.f / DIM_) - mean * mean;
    float inv  = rsqrtf(fmaxf(var, 0.f) + 1e-5f);
    const float* gp = g + lane * 8;
    const float* bp = b + lane * 8;
    __bf16* op = o + (size_t)row * DIM_ + lane * 8;
    bf16x8 ov;
    #pragma unroll
    for (int j = 0; j < 8; ++j) ov[j] = (__bf16)((r[j] - mean) * inv * gp[j] + bp[j]);
    *(bf16x8*)op = ov;
}

// causal depthwise conv (4 taps) + SiLU; float4-vectorized over d
__global__ void conv_silu_kernel(const float* __restrict__ xz, const float* __restrict__ cw,
                                 const float* __restrict__ cb, float* __restrict__ xc,
                                 __bf16* __restrict__ xcb) {
    int idx = blockIdx.x * 256 + threadIdx.x;
    if (idx >= B_ * N_ * DIN_ / 4) return;
    int i4 = idx * 4;
    int d = i4 & (DIN_ - 1);
    int row = i4 >> 10;
    int n = row & (N_ - 1);
    int rowb = row - n;
    float4 acc = *(const float4*)(cb + d);
    #pragma unroll
    for (int k = 0; k < 4; ++k) {
        int m = n - 3 + k;
        if (m >= 0) {
            float4 v = *(const float4*)(xz + (size_t)(rowb + m) * (2 * DIN_) + d);
            acc.x += v.x * cw[(d + 0) * 4 + k];
            acc.y += v.y * cw[(d + 1) * 4 + k];
            acc.z += v.z * cw[(d + 2) * 4 + k];
            acc.w += v.w * cw[(d + 3) * 4 + k];
        }
    }
    float4 s;
    s.x = acc.x / (1.f + __expf(-acc.x));
    s.y = acc.y / (1.f + __expf(-acc.y));
    s.z = acc.z / (1.f + __expf(-acc.z));
    s.w = acc.w / (1.f + __expf(-acc.w));
    *(float4*)(xc + i4) = s;
    bf16x4 p = {(__bf16)s.x, (__bf16)s.y, (__bf16)s.z, (__bf16)s.w};
    *(bf16x4*)(xcb + i4) = p;
}

__global__ void cvt_bf16_kernel(const float* __restrict__ src, __bf16* __restrict__ dst, int count) {
    int i = (blockIdx.x * 256 + threadIdx.x) * 4;
    if (i >= count) return;
    float4 v = *(const float4*)(src + i);
    bf16x4 p = {(__bf16)v.x, (__bf16)v.y, (__bf16)v.z, (__bf16)v.w};
    *(bf16x4*)(dst + i) = p;
}

// ---------------- fused selective scan ----------------
// one block per (b,d): 256 threads = 16 s-lanes x 16 chunks of 16 steps.
// phase1: per-chunk affine summary -> LDS; compose prefix; phase2: replay + y out.
__global__ __launch_bounds__(256) void scanf_kernel(
    const float* __restrict__ dtp, const float* __restrict__ xc,
    const float* __restrict__ dbl, const float* __restrict__ xz,
    const float* __restrict__ A_log, const float* __restrict__ Dsk,
    __bf16* __restrict__ ybb) {
    __shared__ float sA[256], sB[256];
    int bd = blockIdx.x;
    int d = bd & (DIN_ - 1), b = bd >> 10;
    int tid = threadIdx.x, s = tid & 15, c = tid >> 4;
    float As = -__expf(A_log[(d << 4) | s]);
    int row0 = b * N_ + c * CLEN_;
    float a = 1.f, hb = 0.f;
    #pragma unroll 4
    for (int n = 0; n < CLEN_; ++n) {
        int row = row0 + n;
        float v = dtp[(size_t)row * DIN_ + d];
        float dt = fmaxf(v, 0.f) + __logf(1.f + __expf(-fabsf(v)));
        float uu = dt * xc[(size_t)row * DIN_ + d];
        float Bv = dbl[row * 64 + 32 + s];
        float dA = __expf(dt * As);
        hb = hb * dA + uu * Bv;
        a *= dA;
    }
    sA[tid] = a; sB[tid] = hb;
    __syncthreads();
    float h = 0.f;
    for (int j = 0; j < c; ++j)
        h = h * sA[j * 16 + s] + sB[j * 16 + s];
    float Dv = Dsk[d];
    #pragma unroll 4
    for (int n = 0; n < CLEN_; ++n) {
        int row = row0 + n;
        float v = dtp[(size_t)row * DIN_ + d];
        float dt = fmaxf(v, 0.f) + __logf(1.f + __expf(-fabsf(v)));
        float xcv = xc[(size_t)row * DIN_ + d];
        float uu = dt * xcv;
        float Bv = dbl[row * 64 + 32 + s];
        float Cv = dbl[row * 64 + 48 + s];
        float dA = __expf(dt * As);
        h = h * dA + uu * Bv;
        float p = dpp_red16(h * Cv);
        if (s == 0) {
            float zz = xz[(size_t)row * (2 * DIN_) + DIN_ + d];
            float y = (p + xcv * Dv) * (zz / (1.f + __expf(-zz)));
            ybb[(size_t)row * DIN_ + d] = (__bf16)y;
        }
    }
}

// ---------------- weight prep ----------------

__global__ void tconv_kernel(const float* __restrict__ src, __bf16* __restrict__ dst,
                             int K, int N) {
    __shared__ float tile[32][33];
    int n0 = blockIdx.x * 32, k0 = blockIdx.y * 32;
    src += (size_t)blockIdx.z * K * N;
    dst += (size_t)blockIdx.z * K * N;
    int tx = threadIdx.x & 31, ty = threadIdx.x >> 5;
    #pragma unroll
    for (int i = 0; i < 32; i += 8) {
        int k = k0 + ty + i, n = n0 + tx;
        tile[ty + i][tx] = (k < K && n < N) ? src[(size_t)k * N + n] : 0.f;
    }
    __syncthreads();
    #pragma unroll
    for (int i = 0; i < 32; i += 8) {
        int n = n0 + ty + i, k = k0 + tx;
        if (n < N && k < K) dst[(size_t)n * K + k] = (__bf16)tile[tx][ty + i];
    }
}

// V^T prep: vbT[(b*8+h)*64 + j][k] = kvb[(b*196+k)*1024 + 512 + h*64 + j], zero pad k>=196
__global__ void vtrans_kernel(const __bf16* __restrict__ kvb, __bf16* __restrict__ vbT) {
    int t = blockIdx.x * 256 + threadIdx.x;
    if (t >= B_ * HEADS_ * HD_ * (CTXP_ / 16)) return;
    int kc = t % (CTXP_ / 16);
    int r  = t / (CTXP_ / 16);
    int j = r & 63, h = (r >> 6) & 7, b = r >> 9;
    ushort tmp[16];
    #pragma unroll
    for (int i = 0; i < 16; ++i) {
        int k = kc * 16 + i;
        __bf16 v = (__bf16)0.f;
        if (k < CTX_) v = kvb[((size_t)(b * CTX_ + k)) * (2 * DIM_) + DIM_ + h * HD_ + j];
        tmp[i] = *(ushort*)&v;
    }
    *(uint4*)(vbT + (size_t)r * CTXP_ + kc * 16)     = *(uint4*)&tmp[0];
    *(uint4*)(vbT + (size_t)r * CTXP_ + kc * 16 + 8) = *(uint4*)&tmp[8];
}

// ---------------- bf16 MFMA GEMM (double-buffered, tile-templated) ----------------
#define LDP_ 40

template <int BM, int BN, bool BOUT>
__global__ __launch_bounds__(256) void mgemm_k(
    const __bf16* __restrict__ A, const __bf16* __restrict__ Bw,
    const float* __restrict__ bias, const float* __restrict__ res,
    void* __restrict__ Cp, int M, int N, int K, int lda, int ldc) {
    constexpr int AU = BM * 4;
    constexpr int BU = BN * 4;
    constexpr int RA = (AU + 255) / 256;
    constexpr int RB = (BU + 255) / 256;
    constexpr int FM = BM / 32, FN = BN / 32;
    __shared__ __align__(16) __bf16 As[2][BM * LDP_];
    __shared__ __align__(16) __bf16 Bs[2][BN * LDP_];
    int tid = threadIdx.x;
    int ntx = gridDim.x;
    int nwg = ntx * gridDim.y;
    int bid = blockIdx.y * ntx + blockIdx.x;
    if ((nwg & 7) == 0) bid = (bid & 7) * (nwg >> 3) + (bid >> 3);
    int row0 = (bid / ntx) * BM, col0 = (bid % ntx) * BN;
    int wave = tid >> 6, lane = tid & 63;
    int wm = (wave >> 1) * (BM / 2), wn = (wave & 1) * (BN / 2);
    int fr = lane & 15, fk = lane >> 4;
    f32x4 acc[FM][FN] = {};
    uint4 aR[RA], bR[RB];

    auto loadT = [&](int k0) {
        #pragma unroll
        for (int i = 0; i < RA; ++i) {
            int idx = i * 256 + tid;
            if (AU % 256 == 0 || idx < AU) {
                int r = idx >> 2, c = (idx & 3) * 8;
                int gm = row0 + r;
                uint4 v = {0u, 0u, 0u, 0u};
                if (gm < M) v = *(const uint4*)(A + (size_t)gm * lda + k0 + c);
                aR[i] = v;
            }
        }
        #pragma unroll
        for (int i = 0; i < RB; ++i) {
            int idx = i * 256 + tid;
            if (BU % 256 == 0 || idx < BU) {
                int r = idx >> 2, c = (idx & 3) * 8;
                int gn = col0 + r;
                uint4 v = {0u, 0u, 0u, 0u};
                if (gn < N) v = *(const uint4*)(Bw + (size_t)gn * K + k0 + c);
                bR[i] = v;
            }
        }
    };
    auto writeT = [&](int buf) {
        #pragma unroll
        for (int i = 0; i < RA; ++i) {
            int idx = i * 256 + tid;
            if (AU % 256 == 0 || idx < AU) {
                int r = idx >> 2, c = (idx & 3) * 8;
                *(uint4*)&As[buf][r * LDP_ + c] = aR[i];
            }
        }
        #pragma unroll
        for (int i = 0; i < RB; ++i) {
            int idx = i * 256 + tid;
            if (BU % 256 == 0 || idx < BU) {
                int r = idx >> 2, c = (idx & 3) * 8;
                *(uint4*)&Bs[buf][r * LDP_ + c] = bR[i];
            }
        }
    };

    loadT(0);
    writeT(0);
    __syncthreads();
    int NK = K >> 5;
    for (int kt = 0; kt < NK; ++kt) {
        int cur = kt & 1;
        if (kt + 1 < NK) loadT((kt + 1) << 5);
        bf16x8 af[FM], bg[FN];
        #pragma unroll
        for (int mf = 0; mf < FM; ++mf)
            af[mf] = *(const bf16x8*)&As[cur][(wm + mf * 16 + fr) * LDP_ + fk * 8];
        #pragma unroll
        for (int nf = 0; nf < FN; ++nf)
            bg[nf] = *(const bf16x8*)&Bs[cur][(wn + nf * 16 + fr) * LDP_ + fk * 8];
        #pragma unroll
        for (int mf = 0; mf < FM; ++mf)
            #pragma unroll
            for (int nf = 0; nf < FN; ++nf)
                acc[mf][nf] = __builtin_amdgcn_mfma_f32_16x16x32_bf16(af[mf], bg[nf], acc[mf][nf], 0, 0, 0);
        if (kt + 1 < NK) {
            writeT(cur ^ 1);
            __syncthreads();
        }
    }
    #pragma unroll
    for (int mf = 0; mf < FM; ++mf) {
        #pragma unroll
        for (int nf = 0; nf < FN; ++nf) {
            int gn = col0 + wn + nf * 16 + fr;
            if (gn >= N) continue;
            float bb = bias ? bias[gn] : 0.f;
            #pragma unroll
            for (int e = 0; e < 4; ++e) {
                int gm = row0 + wm + mf * 16 + fk * 4 + e;
                if (gm >= M) continue;
                size_t idx = (size_t)gm * ldc + gn;
                float v = acc[mf][nf][e] + bb;
                if constexpr (BOUT) {
                    ((__bf16*)Cp)[idx] = (__bf16)v;
                } else {
                    if (res) v += res[idx];
                    ((float*)Cp)[idx] = v;
                }
            }
        }
    }
}

template <int BM, int BN, bool BOUT = false>
static inline void mgemm(const __bf16* A, const __bf16* Bw, const float* bias,
                         const float* res, void* C, int M, int N, int K,
                         int lda, int ldc, hipStream_t s) {
    dim3 g((N + BN - 1) / BN, (M + BM - 1) / BM);
    mgemm_k<BM, BN, BOUT><<<g, 256, 0, s>>>(A, Bw, bias, res, C, M, N, K, lda, ldc);
}

// ---------------- fused attention ----------------
// block = 256 threads (4 waves), each block: one (b,h), 64 q-rows (blockIdx.y).
// K staged in LDS; Q frags direct from global; softmax in-register via DPP;
// P -> LDS bf16; PV with V^T direct from global.
#define KP_ 72    // K LDS row pad (bf16)
#define PP_ 232   // P LDS row pad (bf16)

__global__ __launch_bounds__(256) void attn_k(
    const __bf16* __restrict__ qb, const __bf16* __restrict__ kvb,
    const __bf16* __restrict__ vbT, __bf16* __restrict__ obb) {
    __shared__ __align__(16) __bf16 Ks[CTXP_ * KP_];
    __shared__ __align__(16) __bf16 Ps[64 * PP_];
    int z = blockIdx.z, b = z >> 3, h = z & 7;
    int tid = threadIdx.x, wave = tid >> 6, lane = tid & 63;
    int fr = lane & 15, fk = lane >> 4;
    int q0 = blockIdx.y * 64;
    // stage K (rows >= CTX_ zeroed)
    #pragma unroll
    for (int i = 0; i < 7; ++i) {
        int idx = i * 256 + tid;
        int r = idx >> 3, cu = (idx & 7) * 8;
        uint4 v = {0u, 0u, 0u, 0u};
        if (r < CTX_) v = *(const uint4*)(kvb + ((size_t)(b * CTX_ + r)) * (2 * DIM_) + h * HD_ + cu);
        *(uint4*)&Ks[r * KP_ + cu] = v;
    }
    // Q A-frags (global, L2-resident)
    bf16x8 aq[2];
    {
        int qrow = b * N_ + q0 + wave * 16 + fr;
        #pragma unroll
        for (int t = 0; t < 2; ++t)
            aq[t] = *(const bf16x8*)(qb + (size_t)qrow * DIM_ + h * HD_ + t * 32 + fk * 8);
    }
    __syncthreads();
    // scores: 13 col frags x 2 k-slabs
    f32x4 acc[CTXF_] = {};
    #pragma unroll
    for (int t = 0; t < 2; ++t)
        #pragma unroll
        for (int cb = 0; cb < CTXF_; ++cb) {
            bf16x8 bg = *(const bf16x8*)&Ks[(cb * 16 + fr) * KP_ + t * 32 + fk * 8];
            acc[cb] = __builtin_amdgcn_mfma_f32_16x16x32_bf16(aq[t], bg, acc[cb], 0, 0, 0);
        }
    // softmax per row (row = wave*16 + fk*4 + e); cols cb*16+fr
    #pragma unroll
    for (int e = 0; e < 4; ++e) {
        float m = -1e30f;
        #pragma unroll
        for (int cb = 0; cb < CTXF_; ++cb) {
            float sv = acc[cb][e] * 0.125f;
            if (cb * 16 + fr >= CTX_) sv = -1e30f;
            acc[cb][e] = sv;
            m = fmaxf(m, sv);
        }
        m = dpp_max16(m);
        float ssum = 0.f;
        #pragma unroll
        for (int cb = 0; cb < CTXF_; ++cb) {
            float p = __expf(acc[cb][e] - m);
            acc[cb][e] = p;
            ssum += p;
        }
        ssum = dpp_red16(ssum);
        float inv = 1.f / ssum;
        #pragma unroll
        for (int cb = 0; cb < CTXF_; ++cb)
            Ps[(wave * 16 + fk * 4 + e) * PP_ + cb * 16 + fr] = (__bf16)(acc[cb][e] * inv);
        Ps[(wave * 16 + fk * 4 + e) * PP_ + 208 + fr] = (__bf16)0.f;  // pad cols
    }
    __syncthreads();
    // PV: 7 k-slabs of 32; out 64 cols = 4 frags; V^T direct from global
    f32x4 acc2[4] = {};
    const __bf16* vB = vbT + (size_t)z * HD_ * CTXP_;
    #pragma unroll
    for (int sl = 0; sl < 7; ++sl) {
        bf16x8 ap = *(const bf16x8*)&Ps[(wave * 16 + fr) * PP_ + sl * 32 + fk * 8];
        #pragma unroll
        for (int nf = 0; nf < 4; ++nf) {
            bf16x8 bv = *(const bf16x8*)(vB + (size_t)(nf * 16 + fr) * CTXP_ + sl * 32 + fk * 8);
            acc2[nf] = __builtin_amdgcn_mfma_f32_16x16x32_bf16(ap, bv, acc2[nf], 0, 0, 0);
        }
    }
    #pragma unroll
    for (int nf = 0; nf < 4; ++nf)
        #pragma unroll
        for (int e = 0; e < 4; ++e) {
            int gm = b * N_ + q0 + wave * 16 + fk * 4 + e;
            obb[(size_t)gm * DIM_ + h * HD_ + nf * 16 + fr] = (__bf16)acc2[nf][e];
        }
}

// ---------------- generic fp32 GEMM (dt_proj only) ----------------
#define TM_ 64
#define TN_ 64
#define TK_ 16

__global__ __launch_bounds__(256) void gemm_k(
    const float* __restrict__ A, const float* __restrict__ B,
    const float* __restrict__ bias, float* C,
    int M, int N, int K, int lda, int ldb, int ldc) {
    __shared__ float As[TK_][TM_ + 4];
    __shared__ float Bs[TK_][TN_ + 4];
    int tid = threadIdx.x;
    int row0 = blockIdx.y * TM_;
    int col0 = blockIdx.x * TN_;
    int tm = (tid / 16) * 4, tn = (tid % 16) * 4;
    float acc[4][4] = {};
    int nk = (K + TK_ - 1) / TK_;
    for (int kt = 0; kt < nk; ++kt) {
        int k0 = kt * TK_;
        {
            int m = tid >> 2, kq = (tid & 3) * 4;
            int gm = row0 + m;
            float4 v = {0, 0, 0, 0};
            if (gm < M && k0 + kq + 3 < K) v = *(const float4*)(A + (size_t)gm * lda + k0 + kq);
            else if (gm < M) {
                float tmp[4] = {0, 0, 0, 0};
                for (int j = 0; j < 4; ++j) if (k0 + kq + j < K) tmp[j] = A[(size_t)gm * lda + k0 + kq + j];
                v = {tmp[0], tmp[1], tmp[2], tmp[3]};
            }
            As[kq + 0][m] = v.x; As[kq + 1][m] = v.y; As[kq + 2][m] = v.z; As[kq + 3][m] = v.w;
        }
        {
            int kk = tid >> 4, nq = (tid & 15) * 4;
            int gk = k0 + kk;
            float4 v = {0, 0, 0, 0};
            if (gk < K && col0 + nq + 3 < N) v = *(const float4*)(B + (size_t)gk * ldb + col0 + nq);
            Bs[kk][nq + 0] = v.x; Bs[kk][nq + 1] = v.y; Bs[kk][nq + 2] = v.z; Bs[kk][nq + 3] = v.w;
        }
        __syncthreads();
        #pragma unroll
        for (int kk = 0; kk < TK_; ++kk) {
            float4 a4 = *(const float4*)&As[kk][tm];
            float4 b4 = *(const float4*)&Bs[kk][tn];
            float a0[4] = {a4.x, a4.y, a4.z, a4.w};
            float b0[4] = {b4.x, b4.y, b4.z, b4.w};
            #pragma unroll
            for (int i = 0; i < 4; ++i)
                #pragma unroll
                for (int j = 0; j < 4; ++j)
                    acc[i][j] += a0[i] * b0[j];
        }
        __syncthreads();
    }
    for (int i = 0; i < 4; ++i) {
        int gm = row0 + tm + i;
        if (gm >= M) continue;
        for (int j = 0; j < 4; ++j) {
            int gn = col0 + tn + j;
            if (gn >= N) continue;
            float v = acc[i][j];
            if (bias) v += bias[gn];
            C[(size_t)gm * ldc + gn] = v;
        }
    }
}

// ---------------- host side ----------------

extern "C" void kernel_launch(void* const* d_in, const int* in_sizes, int n_in,
                              void* d_out, int out_size, void* d_ws, size_t ws_size,
                              hipStream_t stream) {
    const int*   text   = (const int*)d_in[0];
    const float* images = (const float*)d_in[1];
    const float* alphap = (const float*)d_in[2];
    const float* dgam   = (const float*)d_in[3];
    const float* dbeta  = (const float*)d_in[4];
    const float* imgW   = (const float*)d_in[5];
    const float* imgb   = (const float*)d_in[6];
    const float* g1W    = (const float*)d_in[7];
    const float* g1b    = (const float*)d_in[8];
    const float* g2W    = (const float*)d_in[9];
    const float* g2b    = (const float*)d_in[10];
    const float* temb   = (const float*)d_in[11];
    const float* pemb   = (const float*)d_in[12];
    const float* ln1g   = (const float*)d_in[13];
    const float* ln1b   = (const float*)d_in[14];
    const float* inW    = (const float*)d_in[15];
    const float* convW  = (const float*)d_in[16];
    const float* convb  = (const float*)d_in[17];
    const float* xpW    = (const float*)d_in[18];
    const float* dtW    = (const float*)d_in[19];
    const float* dtb    = (const float*)d_in[20];
    const float* Alog   = (const float*)d_in[21];
    const float* Dsk    = (const float*)d_in[22];
    const float* outW   = (const float*)d_in[23];
    const float* ln2g   = (const float*)d_in[24];
    const float* ln2b   = (const float*)d_in[25];
    const float* ainW   = (const float*)d_in[26];
    const float* ainb   = (const float*)d_in[27];
    const float* aoutW  = (const float*)d_in[28];
    const float* aoutb  = (const float*)d_in[29];
    const float* fng    = (const float*)d_in[30];
    const float* fnb    = (const float*)d_in[31];
    const float* lgW    = (const float*)d_in[32];
    const float* lgb    = (const float*)d_in[33];
    float* out = (float*)d_out;

    float* w = (float*)d_ws;
    float* imgd   = w; w += (size_t)B_ * CTX_ * IMGD_;   // bf16 dyt out (aliased)
    float* imgf   = w; w += (size_t)B_ * CTX_ * DIM_;
    float* pooled = w; w += B_ * DIM_;
    float* g1     = w; w += B_ * 128;
    float* gate   = w; w += B_ * DIM_;
    float* x      = w; w += (size_t)B_ * N_ * DIM_;
    float* xn     = w; w += (size_t)B_ * N_ * DIM_;      // bf16 ln out (aliased)
    float* xz     = w; w += (size_t)B_ * N_ * 2 * DIN_;
    float* xc     = w; w += (size_t)B_ * N_ * DIN_;
    float* dblb   = w; w += (size_t)B_ * N_ * 64;
    float* dtp    = w; w += (size_t)B_ * N_ * DIN_;
    // bf16 buffers
    __bf16* xcb   = (__bf16*)w; w += (size_t)B_ * N_ * DIN_ / 2;
    __bf16* imgfb = (__bf16*)w; w += (size_t)B_ * CTX_ * DIM_ / 2;
    __bf16* ybb   = (__bf16*)w; w += (size_t)B_ * N_ * DIN_ / 2;
    __bf16* qb    = (__bf16*)w; w += (size_t)B_ * N_ * DIM_ / 2;
    __bf16* kvb   = (__bf16*)w; w += (size_t)B_ * CTX_ * 2 * DIM_ / 2;
    __bf16* vbT   = (__bf16*)w; w += (size_t)B_ * HEADS_ * HD_ * CTXP_ / 2;
    __bf16* obb   = (__bf16*)w; w += (size_t)B_ * N_ * DIM_ / 2;
    __bf16* lgT   = (__bf16*)w; w += (size_t)10000 * DIM_ / 2;
    // bf16 weights
    __bf16* inpT  = (__bf16*)w; w += (size_t)DEPTH_ * 2 * DIN_ * DIM_ / 2;
    __bf16* outpT = (__bf16*)w; w += (size_t)DEPTH_ * DIM_ * DIN_ / 2;
    __bf16* ainB  = (__bf16*)w; w += (size_t)DEPTH_ * 3 * DIM_ * DIM_ / 2;
    __bf16* aoutB = (__bf16*)w; w += (size_t)DEPTH_ * DIM_ * DIM_ / 2;
    __bf16* imgWT = (__bf16*)w; w += (size_t)DIM_ * IMGD_ / 2;
    __bf16* xpWT  = (__bf16*)w; w += (size_t)DEPTH_ * 64 * DIN_ / 2;
    __bf16* imgdb = (__bf16*)imgd;
    __bf16* xnb   = (__bf16*)xn;

    const int TOKENS = B_ * N_;
    const int IMGT   = B_ * CTX_;

    // ---- weight prep ----
    tconv_kernel<<<dim3(2 * DIN_ / 32, DIM_ / 32, DEPTH_), 256, 0, stream>>>(inW,  inpT,  DIM_, 2 * DIN_);
    tconv_kernel<<<dim3(DIM_ / 32, DIN_ / 32, DEPTH_),     256, 0, stream>>>(outW, outpT, DIN_, DIM_);
    tconv_kernel<<<dim3(DIM_ / 32, IMGD_ / 32, 1),         256, 0, stream>>>(imgW, imgWT, IMGD_, DIM_);
    tconv_kernel<<<dim3(64 / 32, DIN_ / 32, DEPTH_),       256, 0, stream>>>(xpW,  xpWT,  DIN_, 64);
    tconv_kernel<<<dim3((10000 + 31) / 32, DIM_ / 32, 1),  256, 0, stream>>>(lgW, lgT, DIM_, 10000);
    cvt_bf16_kernel<<<(DEPTH_ * 3 * DIM_ * DIM_ / 4 + 255) / 256, 256, 0, stream>>>(ainW,  ainB,  DEPTH_ * 3 * DIM_ * DIM_);
    cvt_bf16_kernel<<<(DEPTH_ * DIM_ * DIM_ / 4 + 255) / 256, 256, 0, stream>>>(aoutW, aoutB, DEPTH_ * DIM_ * DIM_);

    // ---- image path ----
    {
        int total = B_ * CTX_ * IMGD_;
        dyt_kernel<<<(total + 255) / 256, 256, 0, stream>>>(images, alphap, dgam, dbeta, imgdb, total);
        mgemm<32, 64>(imgdb, imgWT, imgb, nullptr, imgf, IMGT, DIM_, IMGD_, IMGD_, DIM_, stream);
        pool_kernel<<<(B_ * DIM_ + 255) / 256, 256, 0, stream>>>(imgf, pooled);
        gate1_kernel<<<(B_ * 128 + 255) / 256, 256, 0, stream>>>(pooled, g1W, g1b, g1);
        gate2_kernel<<<(B_ * DIM_ + 255) / 256, 256, 0, stream>>>(g1, g2W, g2b, gate);
        scale_kernel<<<(B_ * CTX_ * DIM_ + 255) / 256, 256, 0, stream>>>(imgf, gate, imgfb);
    }
    embed_kernel<<<(TOKENS * DIM_ + 255) / 256, 256, 0, stream>>>(text, temb, pemb, x);

    for (int l = 0; l < DEPTH_; ++l) {
        const __bf16* inpT_l  = inpT  + (size_t)l * 2 * DIN_ * DIM_;
        const __bf16* outpT_l = outpT + (size_t)l * DIM_ * DIN_;
        const __bf16* ainB_l  = ainB  + (size_t)l * 3 * DIM_ * DIM_;
        const __bf16* aoutB_l = aoutB + (size_t)l * DIM_ * DIM_;
        const __bf16* xpWT_l  = xpWT  + (size_t)l * 64 * DIN_;
        const float* cw    = convW + (size_t)l * DIN_ * 4;
        const float* cb    = convb + (size_t)l * DIN_;
        const float* dtw   = dtW  + (size_t)l * DTR_ * DIN_;
        const float* dtbi  = dtb  + (size_t)l * DIN_;
        const float* alog  = Alog + (size_t)l * DIN_ * DST_;
        const float* dsk   = Dsk  + (size_t)l * DIN_;
        const float* ab    = ainb + (size_t)l * 3 * DIM_;
        const float* aob   = aoutb + (size_t)l * DIM_;

        // mamba block
        ln_kernel<<<TOKENS / 4, 256, 0, stream>>>(x, ln1g + l * DIM_, ln1b + l * DIM_, xnb, TOKENS);
        mgemm<64, 128>(xnb, inpT_l, nullptr, nullptr, xz, TOKENS, 2 * DIN_, DIM_, DIM_, 2 * DIN_, stream);
        conv_silu_kernel<<<(TOKENS * DIN_ / 4 + 255) / 256, 256, 0, stream>>>(xz, cw, cb, xc, xcb);
        mgemm<32, 64>(xcb, xpWT_l, nullptr, nullptr, dblb, TOKENS, 64, DIN_, DIN_, 64, stream);
        gemm_k<<<dim3((DIN_ + TN_ - 1) / TN_, (TOKENS + TM_ - 1) / TM_), 256, 0, stream>>>(
            dblb, dtw, dtbi, dtp, TOKENS, DIN_, DTR_, 64, DIN_, DIN_);
        scanf_kernel<<<B_ * DIN_, 256, 0, stream>>>(dtp, xc, dblb, xz, alog, dsk, ybb);
        mgemm<32, 64>(ybb, outpT_l, nullptr, x, x, TOKENS, DIM_, DIN_, DIN_, DIM_, stream);

        // cross-attention block
        ln_kernel<<<TOKENS / 4, 256, 0, stream>>>(x, ln2g + l * DIM_, ln2b + l * DIM_, xnb, TOKENS);
        mgemm<32, 64, true>(xnb, ainB_l, ab, nullptr, qb, TOKENS, DIM_, DIM_, DIM_, DIM_, stream);
        mgemm<32, 64, true>(imgfb, ainB_l + (size_t)DIM_ * DIM_, ab + DIM_, nullptr, kvb,
                            IMGT, 2 * DIM_, DIM_, DIM_, 2 * DIM_, stream);
        vtrans_kernel<<<(B_ * HEADS_ * HD_ * (CTXP_ / 16) + 255) / 256, 256, 0, stream>>>(kvb, vbT);
        attn_k<<<dim3(1, 4, B_ * HEADS_), 256, 0, stream>>>(qb, kvb, vbT, obb);
        mgemm<32, 64>(obb, aoutB_l, aob, x, x, TOKENS, DIM_, DIM_, DIM_, DIM_, stream);
    }

    // final LN + logits
    ln_kernel<<<TOKENS / 4, 256, 0, stream>>>(x, fng, fnb, xnb, TOKENS);
    mgemm<256, 128>(xnb, lgT, lgb, nullptr, out, TOKENS, 10000, DIM_, DIM_, 10000, stream);
}